// Round 4
// baseline (335.737 us; speedup 1.0000x reference)
//
#include <hip/hip_runtime.h>
#include <math.h>

#define NRES 256
#define CDIM 8
#define HNUM 12
#define CS   384

// ===========================================================================
// Kernel 1: unified projection GEMM  C[2048][1152] = s[2048][384] @ W + b
// virtual cols: [0,192) q | [192,576) kv | [576,720) qp-raw | [720,1152) kvp-raw
// Tiling: 16 rows x 128 cols; grid = 128 x 9 = 1152 blocks (4.5/CU).
// Wave owns 4 rows; lane owns 2 cols; acc[4][2]. LDS 24KB.
// ===========================================================================
__global__ __launch_bounds__(256) void proj_kernel(
    const float* __restrict__ s,
    const float* __restrict__ wq, const float* __restrict__ bq,
    const float* __restrict__ wkv, const float* __restrict__ bkv,
    const float* __restrict__ wqp, const float* __restrict__ bqp,
    const float* __restrict__ wkvp, const float* __restrict__ bkvp,
    float* __restrict__ qo, float* __restrict__ ko, float* __restrict__ vo,
    float* __restrict__ rawp)
{
    const int blk = blockIdx.x;
    const int rt = blk / 9, ct = blk - rt*9;
    const int r0 = rt * 16;
    const int tid = threadIdx.x;
    const int wave = tid >> 6, lane = tid & 63;

    __shared__ __align__(16) float s_sh[16*CS];   // 24 KB

    {
        const float4* sg = (const float4*)(s + (size_t)r0*CS);
        float4* sp = (float4*)s_sh;
        for (int t = tid; t < 16*CS/4; t += 256) sp[t] = sg[t];
    }

    float acc[4][2];
    const float* p0; const float* p1;
    int C0, C1, vc0, vc1;
    {
        const int c = ct*128 + lane;
        vc0 = c;
        const float* w; const float* b; int C, lc;
        if (c < 192)      { w = wq;   b = bq;   C = 192; lc = c; }
        else if (c < 576) { w = wkv;  b = bkv;  C = 384; lc = c - 192; }
        else if (c < 720) { w = wqp;  b = bqp;  C = 144; lc = c - 576; }
        else              { w = wkvp; b = bkvp; C = 432; lc = c - 720; }
        p0 = w + lc; C0 = C;
        const float bb = b[lc];
        #pragma unroll
        for (int r = 0; r < 4; ++r) acc[r][0] = bb;
    }
    {
        const int c = ct*128 + lane + 64;
        vc1 = c;
        const float* w; const float* b; int C, lc;
        if (c < 192)      { w = wq;   b = bq;   C = 192; lc = c; }
        else if (c < 576) { w = wkv;  b = bkv;  C = 384; lc = c - 192; }
        else if (c < 720) { w = wqp;  b = bqp;  C = 144; lc = c - 576; }
        else              { w = wkvp; b = bkvp; C = 432; lc = c - 720; }
        p1 = w + lc; C1 = C;
        const float bb = b[lc];
        #pragma unroll
        for (int r = 0; r < 4; ++r) acc[r][1] = bb;
    }
    __syncthreads();

    const float* srow = &s_sh[wave*4*CS];
    for (int d = 0; d < CS; d += 4) {
        const float w00 = p0[0], w01 = p0[C0], w02 = p0[2*C0], w03 = p0[3*C0];
        const float w10 = p1[0], w11 = p1[C1], w12 = p1[2*C1], w13 = p1[3*C1];
        p0 += 4*C0; p1 += 4*C1;
        #pragma unroll
        for (int r = 0; r < 4; ++r) {
            const float4 sv = *(const float4*)&srow[r*CS + d];
            acc[r][0] = fmaf(sv.x,w00,fmaf(sv.y,w01,fmaf(sv.z,w02,fmaf(sv.w,w03,acc[r][0]))));
            acc[r][1] = fmaf(sv.x,w10,fmaf(sv.y,w11,fmaf(sv.z,w12,fmaf(sv.w,w13,acc[r][1]))));
        }
    }

    #pragma unroll
    for (int n = 0; n < 2; ++n) {
        const int c = (n == 0) ? vc0 : vc1;
        #pragma unroll
        for (int r = 0; r < 4; ++r) {
            const int grow = r0 + wave*4 + r;
            const float val = acc[r][n];
            if (c < 192) {
                qo[(size_t)grow*192 + c] = val;
            } else if (c < 576) {
                const int lc = c - 192, h = lc >> 5, rm = lc & 31;
                if (rm < 16) ko[(size_t)grow*192 + h*16 + rm] = val;
                else         vo[(size_t)grow*192 + h*16 + rm - 16] = val;
            } else {
                rawp[(size_t)grow*576 + (c - 576)] = val;
            }
        }
    }
}

// ===========================================================================
// Kernel 1b: rigid transform of raw points -> q_pts / k_pts / v_pts
// ===========================================================================
__global__ __launch_bounds__(256) void pt_transform_kernel(
    const float* __restrict__ rawp, const float* __restrict__ rot,
    const float* __restrict__ trans,
    float* __restrict__ qpo, float* __restrict__ kpo, float* __restrict__ vpo)
{
    const int t = blockIdx.x*256 + threadIdx.x;
    const int row = t / 192;
    const int p = t - row*192;
    const float* R = rot + (size_t)row*9;
    const float* T = trans + (size_t)row*3;
    const float* base = rawp + (size_t)row*576;
    float x, y, z;
    if (p < 48) { x = base[p];       y = base[48+p];  z = base[96+p]; }
    else { const int pk = p-48; x = base[144+pk]; y = base[288+pk]; z = base[432+pk]; }
    const float px = R[0]*x + R[1]*y + R[2]*z + T[0];
    const float py = R[3]*x + R[4]*y + R[5]*z + T[1];
    const float pz = R[6]*x + R[7]*y + R[8]*z + T[2];
    if (p < 48) {
        float* o = qpo + (size_t)row*144 + p*3;
        o[0]=px; o[1]=py; o[2]=pz;
    } else {
        const int pk = p-48, h = pk/12, pp = pk - h*12;
        if (pp < 4) { float* o = kpo + (size_t)row*144 + (h*4+pp)*3;     o[0]=px; o[1]=py; o[2]=pz; }
        else        { float* o = vpo + (size_t)row*288 + (h*8+(pp-4))*3; o[0]=px; o[1]=py; o[2]=pz; }
    }
}

// ===========================================================================
// Kernel 2: s_g = mean over C, LayerNorm, g_q/g_k projections  (per n)
// ===========================================================================
__global__ __launch_bounds__(256) void gproj_kernel(
    const float* __restrict__ s, const float* __restrict__ g_gamma,
    const float* __restrict__ g_beta,
    const float* __restrict__ wgq, const float* __restrict__ bgq,
    const float* __restrict__ wgk, const float* __restrict__ bgk,
    float* __restrict__ gqo, float* __restrict__ gko)
{
    const int n = blockIdx.x;
    const int tid = threadIdx.x;
    __shared__ float sg[CS];
    __shared__ float red[256];

    for (int d = tid; d < CS; d += 256) {
        float acc = 0.f;
        for (int c = 0; c < CDIM; ++c) acc += s[((size_t)c*NRES+n)*CS + d];
        sg[d] = acc * (1.0f/CDIM);
    }
    __syncthreads();

    float lsum = 0.f;
    for (int d = tid; d < CS; d += 256) lsum += sg[d];
    red[tid] = lsum; __syncthreads();
    for (int st = 128; st > 0; st >>= 1) { if (tid < st) red[tid] += red[tid+st]; __syncthreads(); }
    const float mean = red[0] * (1.0f/CS);
    __syncthreads();

    float lvar = 0.f;
    for (int d = tid; d < CS; d += 256) { float df = sg[d]-mean; lvar += df*df; }
    red[tid] = lvar; __syncthreads();
    for (int st = 128; st > 0; st >>= 1) { if (tid < st) red[tid] += red[tid+st]; __syncthreads(); }
    const float var = red[0] * (1.0f/CS);
    __syncthreads();

    const float inv = rsqrtf(var + 1e-5f);
    for (int d = tid; d < CS; d += 256) sg[d] = (sg[d]-mean)*inv*g_gamma[d] + g_beta[d];
    __syncthreads();

    for (int t = tid; t < 192; t += 256) {
        float aq = bgq[t], ak = bgk[t];
        for (int d = 0; d < CS; ++d) {
            aq += sg[d]*wgq[d*192 + t];
            ak += sg[d]*wgk[d*192 + t];
        }
        gqo[n*192 + t] = aq;
        gko[n*192 + t] = ak;
    }
}

// ===========================================================================
// Kernel 3: attention logits + softmax. XOR-swizzled ksh/gksh: logical quad l
// of row j lives at physical slot (l+j)&3 -> ds_read_b128 hits 8 distinct
// bank-groups across lanes (conflict-free) with NO padding (LDS stays 52KB).
// ===========================================================================
__global__ __launch_bounds__(256) void attn_kernel(
    const float* __restrict__ q, const float* __restrict__ k,
    const float* __restrict__ q_pts, const float* __restrict__ k_pts,
    const float* __restrict__ g_q, const float* __restrict__ g_k,
    const float* __restrict__ trans, const float* __restrict__ mask,
    const float* __restrict__ head_weights, const float* __restrict__ wdist,
    const float* __restrict__ bdist, float* __restrict__ a_out)
{
    const int blk = blockIdx.x;
    const int iq = blk & 7;
    const int h  = (blk >> 3) % HNUM;
    const int c  = blk / (8*HNUM);
    const int i0 = iq * 32;
    const int tid = threadIdx.x;

    __shared__ __align__(16) float ksh[256*16];
    __shared__ __align__(16) float gksh[256*16];
    __shared__ __align__(16) float kpsh[256*12];
    __shared__ __align__(16) float qsh[32*16];
    __shared__ __align__(16) float gqsh[32*16];
    __shared__ __align__(16) float qpsh[32*12];
    __shared__ float tsh[256*3];
    __shared__ float msh[256];
    __shared__ float wdsh[12], bdsh[12];

    for (int t = tid; t < 4096; t += 256) {
        const int j = t >> 4, d = t & 15;
        const int qd = d >> 2, lo = d & 3;
        const int phys = j*16 + (((qd + j) & 3) << 2) + lo;   // XOR-swizzle
        ksh[phys]  = k[((size_t)c*NRES + j)*192 + h*16 + d];
        gksh[phys] = g_k[j*192 + h*16 + d];
    }
    for (int t = tid; t < 3072; t += 256) {
        const int j = t / 12, d = t - j*12;
        kpsh[t] = k_pts[((size_t)c*NRES + j)*144 + h*12 + d];
    }
    for (int t = tid; t < 512; t += 256) {
        const int i = t >> 4, d = t & 15;
        qsh[t]  = q[((size_t)c*NRES + i0 + i)*192 + h*16 + d];
        gqsh[t] = g_q[(i0 + i)*192 + h*16 + d];
    }
    for (int t = tid; t < 384; t += 256) {
        const int i = t / 12, d = t - i*12;
        qpsh[t] = q_pts[((size_t)c*NRES + i0 + i)*144 + h*12 + d];
    }
    for (int t = tid; t < 768; t += 256) tsh[t] = trans[(size_t)c*768 + t];
    if (tid < 256) msh[tid] = mask[c*NRES + tid];
    if (tid < 12) { wdsh[tid] = wdist[tid]; bdsh[tid] = bdist[tid]; }
    __syncthreads();

    const float s54   = 0.13608276348795434f;  // sqrt(1/54)
    const float scale = 0.14433756729740643f;  // sqrt(1/48)
    const float hwv = 0.5f * logf(1.0f + expf(head_weights[h])) * s54;

    const int wave = tid >> 6, lane = tid & 63;

    for (int rr = 0; rr < 8; ++rr) {
        const int il = wave*8 + rr;
        const int i  = i0 + il;
        float4 qv[4], gv[4];
        #pragma unroll
        for (int l = 0; l < 4; ++l) {
            qv[l] = *(const float4*)&qsh[il*16 + l*4];
            gv[l] = *(const float4*)&gqsh[il*16 + l*4];
        }
        const float4 a0 = *(const float4*)&qpsh[il*12 + 0];
        const float4 a1 = *(const float4*)&qpsh[il*12 + 4];
        const float4 a2 = *(const float4*)&qpsh[il*12 + 8];
        const float mi = msh[i];

        float lg[4];
        #pragma unroll
        for (int jj = 0; jj < 4; ++jj) {
            const int j = jj*64 + lane;
            float qk = 0.f, gd = 0.f;
            #pragma unroll
            for (int l = 0; l < 4; ++l) {
                const int slot = (l + j) & 3;
                const float4 kk = *(const float4*)&ksh[j*16 + slot*4];
                const float4 ge = *(const float4*)&gksh[j*16 + slot*4];
                qk += qv[l].x*kk.x + qv[l].y*kk.y + qv[l].z*kk.z + qv[l].w*kk.w;
                gd += gv[l].x*ge.x + gv[l].y*ge.y + gv[l].z*ge.z + gv[l].w*ge.w;
            }
            const float4 c0 = *(const float4*)&kpsh[j*12 + 0];
            const float4 c1 = *(const float4*)&kpsh[j*12 + 4];
            const float4 c2 = *(const float4*)&kpsh[j*12 + 8];
            float dx, dy, dz, pt;
            dx = a0.x - c0.x; dy = a0.y - c0.y; dz = a0.z - c0.z;
            pt  = dx*dx + dy*dy + dz*dz;
            dx = a0.w - c0.w; dy = a1.x - c1.x; dz = a1.y - c1.y;
            pt += dx*dx + dy*dy + dz*dz;
            dx = a1.z - c1.z; dy = a1.w - c1.w; dz = a2.x - c2.x;
            pt += dx*dx + dy*dy + dz*dz;
            dx = a2.y - c2.y; dy = a2.z - c2.z; dz = a2.w - c2.w;
            pt += dx*dx + dy*dy + dz*dz;

            const int f   = h*65536 + i*256 + j;
            const int ii  = f / 3072;
            const int rem = f - ii*3072;
            const int jjx = rem / 12;
            const int ho  = rem - jjx*12;
            const float ddx = tsh[ii*3+0] - tsh[jjx*3+0];
            const float ddy = tsh[ii*3+1] - tsh[jjx*3+1];
            const float ddz = tsh[ii*3+2] - tsh[jjx*3+2];
            const float dist = sqrtf(ddx*ddx + ddy*ddy + ddz*ddz);

            lg[jj] = scale*(qk + gd) - hwv*pt
                   + 100000.0f*(mi*msh[j] - 1.0f)
                   + dist*wdsh[ho] + bdsh[ho];
        }
        float mx = fmaxf(fmaxf(lg[0], lg[1]), fmaxf(lg[2], lg[3]));
        #pragma unroll
        for (int off = 32; off > 0; off >>= 1) mx = fmaxf(mx, __shfl_xor(mx, off));
        float e[4]; float ssum = 0.f;
        #pragma unroll
        for (int jj = 0; jj < 4; ++jj) { e[jj] = __expf(lg[jj] - mx); ssum += e[jj]; }
        #pragma unroll
        for (int off = 32; off > 0; off >>= 1) ssum += __shfl_xor(ssum, off);
        const float inv = 1.0f / ssum;
        float* dst = a_out + (((size_t)c*HNUM + h)*NRES + i)*NRES;
        #pragma unroll
        for (int jj = 0; jj < 4; ++jj) dst[jj*64 + lane] = e[jj]*inv;
    }
}

// ===========================================================================
// Kernel 4a: o = a@v, o_pt = a@v_pts, inverse rigid, norms -> feat buffer.
// a_sh transposed [rh=r*12+h][j] with stride 258 (bank-spread). Outer-product:
// thread = (r-pair g, col4 cq): 8 accs, inner j = 2 LDS + 1 float4 VMEM + 8 FMA.
// Unified 480-col space: [0,192)=o (16/head), [192,480)=o_pt raw (24/head).
// ===========================================================================
#define ASTR 258
__global__ __launch_bounds__(256) void out_feat_kernel(
    const float* __restrict__ a, const float* __restrict__ v,
    const float* __restrict__ v_pts, const float* __restrict__ rot,
    const float* __restrict__ trans, float* __restrict__ featbuf)
{
    const int blk = blockIdx.x;
    const int c  = blk >> 6;
    const int i0 = (blk & 63) * 4;
    const int tid = threadIdx.x;

    __shared__ float a_sh[48*ASTR];    // 49.5 KB, [r*12+h][j]
    __shared__ float feat_sh[4*576];   // 9 KB
    __shared__ float opt_sh[4*288];    // 4.5 KB

    for (int t = tid; t < 12288; t += 256) {
        const int j = t & 255, rh = t >> 8;       // rh = r*12 + hh
        const int hh = rh % 12, r = rh / 12;
        a_sh[rh*ASTR + j] = a[(((size_t)c*HNUM + hh)*NRES + (i0+r))*NRES + j];
    }
    __syncthreads();

    if (tid < 240) {
        const int g  = tid / 120;        // r-pair: rows {2g, 2g+1}
        const int cq = tid - g*120;      // col4 group
        int hh; const float* vbase; int vstride;
        if (cq < 48) { hh = cq >> 2; vbase = v + (size_t)c*NRES*192 + 4*cq; vstride = 192; }
        else { const int cp = (cq-48)*4; hh = cp/24;
               vbase = v_pts + (size_t)c*NRES*288 + cp; vstride = 288; }

        const int rh0 = (2*g)*12 + hh;
        const int rh1 = rh0 + 12;
        float4 acc0 = {0.f,0.f,0.f,0.f}, acc1 = {0.f,0.f,0.f,0.f};
        for (int j = 0; j < 256; ++j) {
            const float av0 = a_sh[rh0*ASTR + j];
            const float av1 = a_sh[rh1*ASTR + j];
            const float4 vv = *(const float4*)(vbase + (size_t)j*vstride);
            acc0.x = fmaf(av0, vv.x, acc0.x); acc0.y = fmaf(av0, vv.y, acc0.y);
            acc0.z = fmaf(av0, vv.z, acc0.z); acc0.w = fmaf(av0, vv.w, acc0.w);
            acc1.x = fmaf(av1, vv.x, acc1.x); acc1.y = fmaf(av1, vv.y, acc1.y);
            acc1.z = fmaf(av1, vv.z, acc1.z); acc1.w = fmaf(av1, vv.w, acc1.w);
        }
        if (cq < 48) {
            float* d0 = &feat_sh[(2*g)*576 + 4*cq];
            float* d1 = &feat_sh[(2*g+1)*576 + 4*cq];
            d0[0]=acc0.x; d0[1]=acc0.y; d0[2]=acc0.z; d0[3]=acc0.w;
            d1[0]=acc1.x; d1[1]=acc1.y; d1[2]=acc1.z; d1[3]=acc1.w;
        } else {
            const int cp = (cq-48)*4;
            float* d0 = &opt_sh[(2*g)*288 + cp];
            float* d1 = &opt_sh[(2*g+1)*288 + cp];
            d0[0]=acc0.x; d0[1]=acc0.y; d0[2]=acc0.z; d0[3]=acc0.w;
            d1[0]=acc1.x; d1[1]=acc1.y; d1[2]=acc1.z; d1[3]=acc1.w;
        }
    }
    __syncthreads();

    for (int t = tid; t < 384; t += 256) {
        const int r = t / 96, p = t - r*96;
        const int grow = c*NRES + i0 + r;
        const float x = opt_sh[r*288 + p*3+0] - trans[(size_t)grow*3+0];
        const float y = opt_sh[r*288 + p*3+1] - trans[(size_t)grow*3+1];
        const float z = opt_sh[r*288 + p*3+2] - trans[(size_t)grow*3+2];
        const float* R = rot + (size_t)grow*9;
        const float rx = R[0]*x + R[3]*y + R[6]*z;
        const float ry = R[1]*x + R[4]*y + R[7]*z;
        const float rz = R[2]*x + R[5]*y + R[8]*z;
        feat_sh[r*576 + 192 + p] = rx;
        feat_sh[r*576 + 288 + p] = ry;
        feat_sh[r*576 + 384 + p] = rz;
        feat_sh[r*576 + 480 + p] = sqrtf(rx*rx + ry*ry + rz*rz + 1e-8f);
    }
    __syncthreads();

    float* dst = featbuf + (size_t)(c*NRES + i0)*576;
    for (int t = tid; t < 2304; t += 256) dst[t] = feat_sh[t];
}

// ===========================================================================
// Kernel 4b: out0 = feat @ wout + bout  (2048x576 @ 576x384)
// ===========================================================================
__global__ __launch_bounds__(256) void out_gemm_kernel(
    const float* __restrict__ featbuf, const float* __restrict__ wout,
    const float* __restrict__ bout, float* __restrict__ out0)
{
    const int blk = blockIdx.x;
    const int rt = blk / 3, ct = blk - rt*3;
    const int r0 = rt * 16;
    const int tid = threadIdx.x;
    const int wave = tid >> 6, lane = tid & 63;

    __shared__ __align__(16) float fsh[16*576];   // 36 KB

    {
        const float4* fg = (const float4*)(featbuf + (size_t)r0*576);
        float4* fp = (float4*)fsh;
        for (int t = tid; t < 16*576/4; t += 256) fp[t] = fg[t];
    }

    const int c0 = ct*128 + lane;
    const int c1 = c0 + 64;
    float acc[4][2];
    {
        const float b0 = bout[c0], b1 = bout[c1];
        #pragma unroll
        for (int r = 0; r < 4; ++r) { acc[r][0] = b0; acc[r][1] = b1; }
    }
    __syncthreads();

    const float* p0 = wout + c0;
    const float* p1 = wout + c1;
    const float* frow = &fsh[wave*4*576];
    for (int d = 0; d < 576; d += 4) {
        const float w00 = p0[0], w01 = p0[384], w02 = p0[768], w03 = p0[1152];
        const float w10 = p1[0], w11 = p1[384], w12 = p1[768], w13 = p1[1152];
        p0 += 1536; p1 += 1536;
        #pragma unroll
        for (int r = 0; r < 4; ++r) {
            const float4 sv = *(const float4*)&frow[r*576 + d];
            acc[r][0] = fmaf(sv.x,w00,fmaf(sv.y,w01,fmaf(sv.z,w02,fmaf(sv.w,w03,acc[r][0]))));
            acc[r][1] = fmaf(sv.x,w10,fmaf(sv.y,w11,fmaf(sv.z,w12,fmaf(sv.w,w13,acc[r][1]))));
        }
    }

    #pragma unroll
    for (int r = 0; r < 4; ++r) {
        const int grow = r0 + wave*4 + r;
        out0[(size_t)grow*CS + c0] = acc[r][0];
        out0[(size_t)grow*CS + c1] = acc[r][1];
    }
}

// ===========================================================================
extern "C" void kernel_launch(void* const* d_in, const int* in_sizes, int n_in,
                              void* d_out, int out_size, void* d_ws, size_t ws_size,
                              hipStream_t stream)
{
    const float* s     = (const float*)d_in[0];
    const float* rot   = (const float*)d_in[2];
    const float* trans = (const float*)d_in[3];
    const float* mask  = (const float*)d_in[4];
    const float* wq    = (const float*)d_in[5];
    const float* bq    = (const float*)d_in[6];
    const float* wkv   = (const float*)d_in[7];
    const float* bkv   = (const float*)d_in[8];
    const float* g_gamma = (const float*)d_in[9];
    const float* g_beta  = (const float*)d_in[10];
    const float* wgq   = (const float*)d_in[11];
    const float* bgq   = (const float*)d_in[12];
    const float* wgk   = (const float*)d_in[13];
    const float* bgk   = (const float*)d_in[14];
    const float* wqp   = (const float*)d_in[15];
    const float* bqp   = (const float*)d_in[16];
    const float* wkvp  = (const float*)d_in[17];
    const float* bkvp  = (const float*)d_in[18];
    const float* head_weights = (const float*)d_in[19];
    const float* wdist = (const float*)d_in[20];
    const float* bdist = (const float*)d_in[21];
    const float* wout  = (const float*)d_in[22];
    const float* bout  = (const float*)d_in[23];

    float* ws      = (float*)d_ws;
    float* q_buf   = ws + 0;          // 393216
    float* qp_buf  = ws + 393216;     // 294912
    float* kp_buf  = ws + 688128;     // 294912
    float* gq_buf  = ws + 983040;     // 49152
    float* gk_buf  = ws + 1032192;    // 49152
    float* k_buf   = ws + 1081344;    // 393216
    float* v_buf   = ws + 1474560;    // 393216
    float* vp_buf  = ws + 1867776;    // 589824 (total 2457600)
    float* featbuf = ws + 0;          // 1179648, overlays buffers dead after attn

    float* out0  = (float*)d_out;       // 786432
    float* a_out = out0 + 786432;       // 6291456
    float* rawp  = a_out;               // raw point projections (dead before attn)

    proj_kernel<<<1152, 256, 0, stream>>>(s, wq, bq, wkv, bkv, wqp, bqp, wkvp, bkvp,
                                          q_buf, k_buf, v_buf, rawp);
    pt_transform_kernel<<<1536, 256, 0, stream>>>(rawp, rot, trans,
                                                  qp_buf, kp_buf, vp_buf);
    gproj_kernel<<<256, 256, 0, stream>>>(s, g_gamma, g_beta, wgq, bgq, wgk, bgk,
                                          gq_buf, gk_buf);
    attn_kernel<<<768, 256, 0, stream>>>(q_buf, k_buf, qp_buf, kp_buf, gq_buf, gk_buf,
                                         trans, mask, head_weights, wdist, bdist, a_out);
    out_feat_kernel<<<512, 256, 0, stream>>>(a_out, v_buf, vp_buf, rot, trans, featbuf);
    out_gemm_kernel<<<384, 256, 0, stream>>>(featbuf, wout, bout, out0);
}

// Round 5
// 312.890 us; speedup vs baseline: 1.0730x; 1.0730x over previous
//
#include <hip/hip_runtime.h>
#include <math.h>

#define NRES 256
#define CDIM 8
#define HNUM 12
#define CS   384

// ===========================================================================
// Kernel 0: bias init — proj outputs (q/k/v/rawp), g outputs, out0.
// Split-K GEMM partials accumulate on top via unsafeAtomicAdd.
// ===========================================================================
__global__ __launch_bounds__(256) void init_bias_kernel(
    const float* __restrict__ bq, const float* __restrict__ bkv,
    const float* __restrict__ bqp, const float* __restrict__ bkvp,
    const float* __restrict__ bgq, const float* __restrict__ bgk,
    const float* __restrict__ bout,
    float* __restrict__ qo, float* __restrict__ ko, float* __restrict__ vo,
    float* __restrict__ rawp, float* __restrict__ gqo, float* __restrict__ gko,
    float* __restrict__ out0)
{
    const int NPROJ = 2048*1152;
    const int NOUT  = 2048*384;
    const int NG    = 256*384;
    const int idx = blockIdx.x*256 + threadIdx.x;
    if (idx < NPROJ) {
        const int row = idx / 1152, vc = idx - row*1152;
        if (vc < 192) qo[(size_t)row*192 + vc] = bq[vc];
        else if (vc < 576) {
            const int lc = vc - 192, h = lc >> 5, rm = lc & 31;
            if (rm < 16) ko[(size_t)row*192 + h*16 + rm] = bkv[lc];
            else         vo[(size_t)row*192 + h*16 + rm - 16] = bkv[lc];
        } else if (vc < 720) rawp[(size_t)row*576 + vc - 576] = bqp[vc - 576];
        else                 rawp[(size_t)row*576 + vc - 576] = bkvp[vc - 720];
    } else if (idx < NPROJ + NOUT) {
        const int t = idx - NPROJ;
        out0[t] = bout[t % 384];
    } else if (idx < NPROJ + NOUT + NG) {
        const int t = idx - NPROJ - NOUT;
        const int n = t / 384, c = t - n*384;
        if (c < 192) gqo[(size_t)n*192 + c]       = bgq[c];
        else         gko[(size_t)n*192 + c - 192] = bgk[c - 192];
    }
}

// ===========================================================================
// Kernel 1: unified projection GEMM, SPLIT-K.
// C[2048][1152] += s[2048][k-half] @ W[k-half] (bias via init kernel)
// Block: 32 rows x 128 cols x 192 K; grid = 64 x 9 x 2 = 1152 (4.5/CU).
// Wave owns 8 rows (s-reads = LDS broadcast b128); lane owns 2 ADJACENT cols
// (weight loads = dwordx2, software-prefetched one 4k-group ahead).
// ===========================================================================
__global__ __launch_bounds__(256) void proj_kernel(
    const float* __restrict__ s,
    const float* __restrict__ wq, const float* __restrict__ wkv,
    const float* __restrict__ wqp, const float* __restrict__ wkvp,
    float* __restrict__ qo, float* __restrict__ ko, float* __restrict__ vo,
    float* __restrict__ rawp)
{
    const int blk = blockIdx.x;
    const int rt  = blk / 18;
    const int rem = blk - rt*18;
    const int ct  = rem >> 1;
    const int kh  = rem & 1;
    const int r0  = rt * 32;
    const int k0  = kh * 192;
    const int tid = threadIdx.x;
    const int wave = tid >> 6, lane = tid & 63;

    __shared__ __align__(16) float s_sh[32*192];   // 24 KB

    for (int t = tid; t < 32*48; t += 256) {
        const int r = t / 48, g = t - r*48;
        *(float4*)&s_sh[r*192 + g*4] =
            *(const float4*)&s[(size_t)(r0 + r)*CS + k0 + g*4];
    }

    const int c = ct*128 + lane*2;     // boundaries 192/576/720 are even
    const float* w; int C, lc;
    if (c < 192)      { w = wq;   C = 192; lc = c; }
    else if (c < 576) { w = wkv;  C = 384; lc = c - 192; }
    else if (c < 720) { w = wqp;  C = 144; lc = c - 576; }
    else              { w = wkvp; C = 432; lc = c - 720; }

    float acc[8][2];
    #pragma unroll
    for (int r = 0; r < 8; ++r) { acc[r][0] = 0.f; acc[r][1] = 0.f; }
    __syncthreads();

    const float* p = w + (size_t)k0*C + lc;
    float2 w0 = *(const float2*)p;
    float2 w1 = *(const float2*)(p + C);
    float2 w2 = *(const float2*)(p + 2*C);
    float2 w3 = *(const float2*)(p + 3*C);
    const float* srow = &s_sh[wave*8*192];

    for (int it = 0; it < 47; ++it) {
        const int d = it*4;
        const float* pn = p + 4*C;
        const float2 n0 = *(const float2*)pn;
        const float2 n1 = *(const float2*)(pn + C);
        const float2 n2 = *(const float2*)(pn + 2*C);
        const float2 n3 = *(const float2*)(pn + 3*C);
        #pragma unroll
        for (int r = 0; r < 8; ++r) {
            const float4 sv = *(const float4*)&srow[r*192 + d];
            acc[r][0] = fmaf(sv.x,w0.x,fmaf(sv.y,w1.x,fmaf(sv.z,w2.x,fmaf(sv.w,w3.x,acc[r][0]))));
            acc[r][1] = fmaf(sv.x,w0.y,fmaf(sv.y,w1.y,fmaf(sv.z,w2.y,fmaf(sv.w,w3.y,acc[r][1]))));
        }
        w0 = n0; w1 = n1; w2 = n2; w3 = n3;
        p = pn;
    }
    {   // last 4k group
        const int d = 47*4;
        #pragma unroll
        for (int r = 0; r < 8; ++r) {
            const float4 sv = *(const float4*)&srow[r*192 + d];
            acc[r][0] = fmaf(sv.x,w0.x,fmaf(sv.y,w1.x,fmaf(sv.z,w2.x,fmaf(sv.w,w3.x,acc[r][0]))));
            acc[r][1] = fmaf(sv.x,w0.y,fmaf(sv.y,w1.y,fmaf(sv.z,w2.y,fmaf(sv.w,w3.y,acc[r][1]))));
        }
    }

    #pragma unroll
    for (int n = 0; n < 2; ++n) {
        const int cc = c + n;
        #pragma unroll
        for (int r = 0; r < 8; ++r) {
            const int grow = r0 + wave*8 + r;
            const float val = acc[r][n];
            if (cc < 192) {
                unsafeAtomicAdd(&qo[(size_t)grow*192 + cc], val);
            } else if (cc < 576) {
                const int l2 = cc - 192, h = l2 >> 5, rm = l2 & 31;
                if (rm < 16) unsafeAtomicAdd(&ko[(size_t)grow*192 + h*16 + rm], val);
                else         unsafeAtomicAdd(&vo[(size_t)grow*192 + h*16 + rm - 16], val);
            } else {
                unsafeAtomicAdd(&rawp[(size_t)grow*576 + cc - 576], val);
            }
        }
    }
}

// ===========================================================================
// Kernel 1b: rigid transform of raw points -> q_pts / k_pts / v_pts
// ===========================================================================
__global__ __launch_bounds__(256) void pt_transform_kernel(
    const float* __restrict__ rawp, const float* __restrict__ rot,
    const float* __restrict__ trans,
    float* __restrict__ qpo, float* __restrict__ kpo, float* __restrict__ vpo)
{
    const int t = blockIdx.x*256 + threadIdx.x;
    const int row = t / 192;
    const int p = t - row*192;
    const float* R = rot + (size_t)row*9;
    const float* T = trans + (size_t)row*3;
    const float* base = rawp + (size_t)row*576;
    float x, y, z;
    if (p < 48) { x = base[p];       y = base[48+p];  z = base[96+p]; }
    else { const int pk = p-48; x = base[144+pk]; y = base[288+pk]; z = base[432+pk]; }
    const float px = R[0]*x + R[1]*y + R[2]*z + T[0];
    const float py = R[3]*x + R[4]*y + R[5]*z + T[1];
    const float pz = R[6]*x + R[7]*y + R[8]*z + T[2];
    if (p < 48) {
        float* o = qpo + (size_t)row*144 + p*3;
        o[0]=px; o[1]=py; o[2]=pz;
    } else {
        const int pk = p-48, h = pk/12, pp = pk - h*12;
        if (pp < 4) { float* o = kpo + (size_t)row*144 + (h*4+pp)*3;     o[0]=px; o[1]=py; o[2]=pz; }
        else        { float* o = vpo + (size_t)row*288 + (h*8+(pp-4))*3; o[0]=px; o[1]=py; o[2]=pz; }
    }
}

// ===========================================================================
// Kernel 2a: s_g = mean over C + LayerNorm -> sgn[256][384]
// ===========================================================================
__global__ __launch_bounds__(256) void ln_kernel(
    const float* __restrict__ s, const float* __restrict__ g_gamma,
    const float* __restrict__ g_beta, float* __restrict__ sgn)
{
    const int n = blockIdx.x;
    const int tid = threadIdx.x;
    __shared__ float sg[CS];
    __shared__ float red[256];

    for (int d = tid; d < CS; d += 256) {
        float acc = 0.f;
        for (int c = 0; c < CDIM; ++c) acc += s[((size_t)c*NRES+n)*CS + d];
        sg[d] = acc * (1.0f/CDIM);
    }
    __syncthreads();

    float lsum = 0.f;
    for (int d = tid; d < CS; d += 256) lsum += sg[d];
    red[tid] = lsum; __syncthreads();
    for (int st = 128; st > 0; st >>= 1) { if (tid < st) red[tid] += red[tid+st]; __syncthreads(); }
    const float mean = red[0] * (1.0f/CS);
    __syncthreads();

    float lvar = 0.f;
    for (int d = tid; d < CS; d += 256) { float df = sg[d]-mean; lvar += df*df; }
    red[tid] = lvar; __syncthreads();
    for (int st = 128; st > 0; st >>= 1) { if (tid < st) red[tid] += red[tid+st]; __syncthreads(); }
    const float var = red[0] * (1.0f/CS);
    __syncthreads();

    const float inv = rsqrtf(var + 1e-5f);
    for (int d = tid; d < CS; d += 256)
        sgn[(size_t)n*CS + d] = (sg[d]-mean)*inv*g_gamma[d] + g_beta[d];
}

// ===========================================================================
// Kernel 2b: g_q|g_k = sgn @ [wgq|wgk], SPLIT-K.
// Block: 16 rows x 128 cols x 192 K; grid = 16 x 3 x 2 = 96.
// ===========================================================================
__global__ __launch_bounds__(256) void ggemm_kernel(
    const float* __restrict__ sgn, const float* __restrict__ wgq,
    const float* __restrict__ wgk, float* __restrict__ gqo, float* __restrict__ gko)
{
    const int blk = blockIdx.x;
    const int rt  = blk / 6;
    const int rem = blk - rt*6;
    const int ct  = rem >> 1;
    const int kh  = rem & 1;
    const int r0  = rt * 16;
    const int k0  = kh * 192;
    const int tid = threadIdx.x;
    const int wave = tid >> 6, lane = tid & 63;

    __shared__ __align__(16) float s_sh[16*192];   // 12 KB

    for (int t = tid; t < 16*48; t += 256) {
        const int r = t / 48, g = t - r*48;
        *(float4*)&s_sh[r*192 + g*4] =
            *(const float4*)&sgn[(size_t)(r0 + r)*CS + k0 + g*4];
    }

    const int c = ct*128 + lane*2;     // virtual 0..383; boundary 192 even
    const float* w; int lc;
    if (c < 192) { w = wgq; lc = c; } else { w = wgk; lc = c - 192; }
    const int C = 192;

    float acc[4][2];
    #pragma unroll
    for (int r = 0; r < 4; ++r) { acc[r][0] = 0.f; acc[r][1] = 0.f; }
    __syncthreads();

    const float* p = w + (size_t)k0*C + lc;
    float2 w0 = *(const float2*)p;
    float2 w1 = *(const float2*)(p + C);
    float2 w2 = *(const float2*)(p + 2*C);
    float2 w3 = *(const float2*)(p + 3*C);
    const float* srow = &s_sh[wave*4*192];

    for (int it = 0; it < 47; ++it) {
        const int d = it*4;
        const float* pn = p + 4*C;
        const float2 n0 = *(const float2*)pn;
        const float2 n1 = *(const float2*)(pn + C);
        const float2 n2 = *(const float2*)(pn + 2*C);
        const float2 n3 = *(const float2*)(pn + 3*C);
        #pragma unroll
        for (int r = 0; r < 4; ++r) {
            const float4 sv = *(const float4*)&srow[r*192 + d];
            acc[r][0] = fmaf(sv.x,w0.x,fmaf(sv.y,w1.x,fmaf(sv.z,w2.x,fmaf(sv.w,w3.x,acc[r][0]))));
            acc[r][1] = fmaf(sv.x,w0.y,fmaf(sv.y,w1.y,fmaf(sv.z,w2.y,fmaf(sv.w,w3.y,acc[r][1]))));
        }
        w0 = n0; w1 = n1; w2 = n2; w3 = n3;
        p = pn;
    }
    {
        const int d = 47*4;
        #pragma unroll
        for (int r = 0; r < 4; ++r) {
            const float4 sv = *(const float4*)&srow[r*192 + d];
            acc[r][0] = fmaf(sv.x,w0.x,fmaf(sv.y,w1.x,fmaf(sv.z,w2.x,fmaf(sv.w,w3.x,acc[r][0]))));
            acc[r][1] = fmaf(sv.x,w0.y,fmaf(sv.y,w1.y,fmaf(sv.z,w2.y,fmaf(sv.w,w3.y,acc[r][1]))));
        }
    }

    #pragma unroll
    for (int n = 0; n < 2; ++n) {
        const int cc = c + n;
        #pragma unroll
        for (int r = 0; r < 4; ++r) {
            const int grow = r0 + wave*4 + r;
            if (cc < 192) unsafeAtomicAdd(&gqo[(size_t)grow*192 + cc], acc[r][n]);
            else          unsafeAtomicAdd(&gko[(size_t)grow*192 + cc - 192], acc[r][n]);
        }
    }
}

// ===========================================================================
// Kernel 3: attention logits + softmax (XOR-swizzled ksh/gksh).
// ===========================================================================
__global__ __launch_bounds__(256) void attn_kernel(
    const float* __restrict__ q, const float* __restrict__ k,
    const float* __restrict__ q_pts, const float* __restrict__ k_pts,
    const float* __restrict__ g_q, const float* __restrict__ g_k,
    const float* __restrict__ trans, const float* __restrict__ mask,
    const float* __restrict__ head_weights, const float* __restrict__ wdist,
    const float* __restrict__ bdist, float* __restrict__ a_out)
{
    const int blk = blockIdx.x;
    const int iq = blk & 7;
    const int h  = (blk >> 3) % HNUM;
    const int c  = blk / (8*HNUM);
    const int i0 = iq * 32;
    const int tid = threadIdx.x;

    __shared__ __align__(16) float ksh[256*16];
    __shared__ __align__(16) float gksh[256*16];
    __shared__ __align__(16) float kpsh[256*12];
    __shared__ __align__(16) float qsh[32*16];
    __shared__ __align__(16) float gqsh[32*16];
    __shared__ __align__(16) float qpsh[32*12];
    __shared__ float tsh[256*3];
    __shared__ float msh[256];
    __shared__ float wdsh[12], bdsh[12];

    for (int t = tid; t < 4096; t += 256) {
        const int j = t >> 4, d = t & 15;
        const int qd = d >> 2, lo = d & 3;
        const int phys = j*16 + (((qd + j) & 3) << 2) + lo;
        ksh[phys]  = k[((size_t)c*NRES + j)*192 + h*16 + d];
        gksh[phys] = g_k[j*192 + h*16 + d];
    }
    for (int t = tid; t < 3072; t += 256) {
        const int j = t / 12, d = t - j*12;
        kpsh[t] = k_pts[((size_t)c*NRES + j)*144 + h*12 + d];
    }
    for (int t = tid; t < 512; t += 256) {
        const int i = t >> 4, d = t & 15;
        qsh[t]  = q[((size_t)c*NRES + i0 + i)*192 + h*16 + d];
        gqsh[t] = g_q[(i0 + i)*192 + h*16 + d];
    }
    for (int t = tid; t < 384; t += 256) {
        const int i = t / 12, d = t - i*12;
        qpsh[t] = q_pts[((size_t)c*NRES + i0 + i)*144 + h*12 + d];
    }
    for (int t = tid; t < 768; t += 256) tsh[t] = trans[(size_t)c*768 + t];
    if (tid < 256) msh[tid] = mask[c*NRES + tid];
    if (tid < 12) { wdsh[tid] = wdist[tid]; bdsh[tid] = bdist[tid]; }
    __syncthreads();

    const float s54   = 0.13608276348795434f;
    const float scale = 0.14433756729740643f;
    const float hwv = 0.5f * logf(1.0f + expf(head_weights[h])) * s54;

    const int wave = tid >> 6, lane = tid & 63;

    for (int rr = 0; rr < 8; ++rr) {
        const int il = wave*8 + rr;
        const int i  = i0 + il;
        float4 qv[4], gv[4];
        #pragma unroll
        for (int l = 0; l < 4; ++l) {
            qv[l] = *(const float4*)&qsh[il*16 + l*4];
            gv[l] = *(const float4*)&gqsh[il*16 + l*4];
        }
        const float4 a0 = *(const float4*)&qpsh[il*12 + 0];
        const float4 a1 = *(const float4*)&qpsh[il*12 + 4];
        const float4 a2 = *(const float4*)&qpsh[il*12 + 8];
        const float mi = msh[i];

        float lg[4];
        #pragma unroll
        for (int jj = 0; jj < 4; ++jj) {
            const int j = jj*64 + lane;
            float qk = 0.f, gd = 0.f;
            #pragma unroll
            for (int l = 0; l < 4; ++l) {
                const int slot = (l + j) & 3;
                const float4 kk = *(const float4*)&ksh[j*16 + slot*4];
                const float4 ge = *(const float4*)&gksh[j*16 + slot*4];
                qk += qv[l].x*kk.x + qv[l].y*kk.y + qv[l].z*kk.z + qv[l].w*kk.w;
                gd += gv[l].x*ge.x + gv[l].y*ge.y + gv[l].z*ge.z + gv[l].w*ge.w;
            }
            const float4 c0 = *(const float4*)&kpsh[j*12 + 0];
            const float4 c1 = *(const float4*)&kpsh[j*12 + 4];
            const float4 c2 = *(const float4*)&kpsh[j*12 + 8];
            float dx, dy, dz, pt;
            dx = a0.x - c0.x; dy = a0.y - c0.y; dz = a0.z - c0.z;
            pt  = dx*dx + dy*dy + dz*dz;
            dx = a0.w - c0.w; dy = a1.x - c1.x; dz = a1.y - c1.y;
            pt += dx*dx + dy*dy + dz*dz;
            dx = a1.z - c1.z; dy = a1.w - c1.w; dz = a2.x - c2.x;
            pt += dx*dx + dy*dy + dz*dz;
            dx = a2.y - c2.y; dy = a2.z - c2.z; dz = a2.w - c2.w;
            pt += dx*dx + dy*dy + dz*dz;

            const int f   = h*65536 + i*256 + j;
            const int ii  = f / 3072;
            const int rem = f - ii*3072;
            const int jjx = rem / 12;
            const int ho  = rem - jjx*12;
            const float ddx = tsh[ii*3+0] - tsh[jjx*3+0];
            const float ddy = tsh[ii*3+1] - tsh[jjx*3+1];
            const float ddz = tsh[ii*3+2] - tsh[jjx*3+2];
            const float dist = sqrtf(ddx*ddx + ddy*ddy + ddz*ddz);

            lg[jj] = scale*(qk + gd) - hwv*pt
                   + 100000.0f*(mi*msh[j] - 1.0f)
                   + dist*wdsh[ho] + bdsh[ho];
        }
        float mx = fmaxf(fmaxf(lg[0], lg[1]), fmaxf(lg[2], lg[3]));
        #pragma unroll
        for (int off = 32; off > 0; off >>= 1) mx = fmaxf(mx, __shfl_xor(mx, off));
        float e[4]; float ssum = 0.f;
        #pragma unroll
        for (int jj = 0; jj < 4; ++jj) { e[jj] = __expf(lg[jj] - mx); ssum += e[jj]; }
        #pragma unroll
        for (int off = 32; off > 0; off >>= 1) ssum += __shfl_xor(ssum, off);
        const float inv = 1.0f / ssum;
        float* dst = a_out + (((size_t)c*HNUM + h)*NRES + i)*NRES;
        #pragma unroll
        for (int jj = 0; jj < 4; ++jj) dst[jj*64 + lane] = e[jj]*inv;
    }
}

// ===========================================================================
// Kernel 4a: o = a@v, o_pt = a@v_pts, inverse rigid, norms -> feat buffer.
// ===========================================================================
#define ASTR 258
__global__ __launch_bounds__(256) void out_feat_kernel(
    const float* __restrict__ a, const float* __restrict__ v,
    const float* __restrict__ v_pts, const float* __restrict__ rot,
    const float* __restrict__ trans, float* __restrict__ featbuf)
{
    const int blk = blockIdx.x;
    const int c  = blk >> 6;
    const int i0 = (blk & 63) * 4;
    const int tid = threadIdx.x;

    __shared__ float a_sh[48*ASTR];
    __shared__ float feat_sh[4*576];
    __shared__ float opt_sh[4*288];

    for (int t = tid; t < 12288; t += 256) {
        const int j = t & 255, rh = t >> 8;
        const int hh = rh % 12, r = rh / 12;
        a_sh[rh*ASTR + j] = a[(((size_t)c*HNUM + hh)*NRES + (i0+r))*NRES + j];
    }
    __syncthreads();

    if (tid < 240) {
        const int g  = tid / 120;
        const int cq = tid - g*120;
        int hh; const float* vbase; int vstride;
        if (cq < 48) { hh = cq >> 2; vbase = v + (size_t)c*NRES*192 + 4*cq; vstride = 192; }
        else { const int cp = (cq-48)*4; hh = cp/24;
               vbase = v_pts + (size_t)c*NRES*288 + cp; vstride = 288; }

        const int rh0 = (2*g)*12 + hh;
        const int rh1 = rh0 + 12;
        float4 acc0 = {0.f,0.f,0.f,0.f}, acc1 = {0.f,0.f,0.f,0.f};
        for (int j = 0; j < 256; ++j) {
            const float av0 = a_sh[rh0*ASTR + j];
            const float av1 = a_sh[rh1*ASTR + j];
            const float4 vv = *(const float4*)(vbase + (size_t)j*vstride);
            acc0.x = fmaf(av0, vv.x, acc0.x); acc0.y = fmaf(av0, vv.y, acc0.y);
            acc0.z = fmaf(av0, vv.z, acc0.z); acc0.w = fmaf(av0, vv.w, acc0.w);
            acc1.x = fmaf(av1, vv.x, acc1.x); acc1.y = fmaf(av1, vv.y, acc1.y);
            acc1.z = fmaf(av1, vv.z, acc1.z); acc1.w = fmaf(av1, vv.w, acc1.w);
        }
        if (cq < 48) {
            float* d0 = &feat_sh[(2*g)*576 + 4*cq];
            float* d1 = &feat_sh[(2*g+1)*576 + 4*cq];
            d0[0]=acc0.x; d0[1]=acc0.y; d0[2]=acc0.z; d0[3]=acc0.w;
            d1[0]=acc1.x; d1[1]=acc1.y; d1[2]=acc1.z; d1[3]=acc1.w;
        } else {
            const int cp = (cq-48)*4;
            float* d0 = &opt_sh[(2*g)*288 + cp];
            float* d1 = &opt_sh[(2*g+1)*288 + cp];
            d0[0]=acc0.x; d0[1]=acc0.y; d0[2]=acc0.z; d0[3]=acc0.w;
            d1[0]=acc1.x; d1[1]=acc1.y; d1[2]=acc1.z; d1[3]=acc1.w;
        }
    }
    __syncthreads();

    for (int t = tid; t < 384; t += 256) {
        const int r = t / 96, p = t - r*96;
        const int grow = c*NRES + i0 + r;
        const float x = opt_sh[r*288 + p*3+0] - trans[(size_t)grow*3+0];
        const float y = opt_sh[r*288 + p*3+1] - trans[(size_t)grow*3+1];
        const float z = opt_sh[r*288 + p*3+2] - trans[(size_t)grow*3+2];
        const float* R = rot + (size_t)grow*9;
        const float rx = R[0]*x + R[3]*y + R[6]*z;
        const float ry = R[1]*x + R[4]*y + R[7]*z;
        const float rz = R[2]*x + R[5]*y + R[8]*z;
        feat_sh[r*576 + 192 + p] = rx;
        feat_sh[r*576 + 288 + p] = ry;
        feat_sh[r*576 + 384 + p] = rz;
        feat_sh[r*576 + 480 + p] = sqrtf(rx*rx + ry*ry + rz*rz + 1e-8f);
    }
    __syncthreads();

    float* dst = featbuf + (size_t)(c*NRES + i0)*576;
    for (int t = tid; t < 2304; t += 256) dst[t] = feat_sh[t];
}

// ===========================================================================
// Kernel 4b: out0 += feat @ wout, SPLIT-K (bias via init kernel).
// Block: 16 rows x 128 cols x 288 K; grid = 128 x 3 x 2 = 768 (3/CU).
// ===========================================================================
__global__ __launch_bounds__(256) void out_gemm_kernel(
    const float* __restrict__ featbuf, const float* __restrict__ wout,
    float* __restrict__ out0)
{
    const int blk = blockIdx.x;
    const int rt  = blk / 6;
    const int rem = blk - rt*6;
    const int ct  = rem >> 1;
    const int kh  = rem & 1;
    const int r0  = rt * 16;
    const int k0  = kh * 288;
    const int tid = threadIdx.x;
    const int wave = tid >> 6, lane = tid & 63;

    __shared__ __align__(16) float fsh[16*288];   // 18 KB

    for (int t = tid; t < 16*72; t += 256) {
        const int r = t / 72, g = t - r*72;
        *(float4*)&fsh[r*288 + g*4] =
            *(const float4*)&featbuf[(size_t)(r0 + r)*576 + k0 + g*4];
    }

    const int c = ct*128 + lane*2;
    const int C = 384;

    float acc[4][2];
    #pragma unroll
    for (int r = 0; r < 4; ++r) { acc[r][0] = 0.f; acc[r][1] = 0.f; }
    __syncthreads();

    const float* p = wout + (size_t)k0*C + c;
    float2 w0 = *(const float2*)p;
    float2 w1 = *(const float2*)(p + C);
    float2 w2 = *(const float2*)(p + 2*C);
    float2 w3 = *(const float2*)(p + 3*C);
    const float* frow = &fsh[wave*4*288];

    for (int it = 0; it < 71; ++it) {
        const int d = it*4;
        const float* pn = p + 4*C;
        const float2 n0 = *(const float2*)pn;
        const float2 n1 = *(const float2*)(pn + C);
        const float2 n2 = *(const float2*)(pn + 2*C);
        const float2 n3 = *(const float2*)(pn + 3*C);
        #pragma unroll
        for (int r = 0; r < 4; ++r) {
            const float4 sv = *(const float4*)&frow[r*288 + d];
            acc[r][0] = fmaf(sv.x,w0.x,fmaf(sv.y,w1.x,fmaf(sv.z,w2.x,fmaf(sv.w,w3.x,acc[r][0]))));
            acc[r][1] = fmaf(sv.x,w0.y,fmaf(sv.y,w1.y,fmaf(sv.z,w2.y,fmaf(sv.w,w3.y,acc[r][1]))));
        }
        w0 = n0; w1 = n1; w2 = n2; w3 = n3;
        p = pn;
    }
    {
        const int d = 71*4;
        #pragma unroll
        for (int r = 0; r < 4; ++r) {
            const float4 sv = *(const float4*)&frow[r*288 + d];
            acc[r][0] = fmaf(sv.x,w0.x,fmaf(sv.y,w1.x,fmaf(sv.z,w2.x,fmaf(sv.w,w3.x,acc[r][0]))));
            acc[r][1] = fmaf(sv.x,w0.y,fmaf(sv.y,w1.y,fmaf(sv.z,w2.y,fmaf(sv.w,w3.y,acc[r][1]))));
        }
    }

    #pragma unroll
    for (int r = 0; r < 4; ++r) {
        const int grow = r0 + wave*4 + r;
        unsafeAtomicAdd(&out0[(size_t)grow*CS + c],     acc[r][0]);
        unsafeAtomicAdd(&out0[(size_t)grow*CS + c + 1], acc[r][1]);
    }
}

// ===========================================================================
extern "C" void kernel_launch(void* const* d_in, const int* in_sizes, int n_in,
                              void* d_out, int out_size, void* d_ws, size_t ws_size,
                              hipStream_t stream)
{
    const float* s     = (const float*)d_in[0];
    const float* rot   = (const float*)d_in[2];
    const float* trans = (const float*)d_in[3];
    const float* mask  = (const float*)d_in[4];
    const float* wq    = (const float*)d_in[5];
    const float* bq    = (const float*)d_in[6];
    const float* wkv   = (const float*)d_in[7];
    const float* bkv   = (const float*)d_in[8];
    const float* g_gamma = (const float*)d_in[9];
    const float* g_beta  = (const float*)d_in[10];
    const float* wgq   = (const float*)d_in[11];
    const float* bgq   = (const float*)d_in[12];
    const float* wgk   = (const float*)d_in[13];
    const float* bgk   = (const float*)d_in[14];
    const float* wqp   = (const float*)d_in[15];
    const float* bqp   = (const float*)d_in[16];
    const float* wkvp  = (const float*)d_in[17];
    const float* bkvp  = (const float*)d_in[18];
    const float* head_weights = (const float*)d_in[19];
    const float* wdist = (const float*)d_in[20];
    const float* bdist = (const float*)d_in[21];
    const float* wout  = (const float*)d_in[22];
    const float* bout  = (const float*)d_in[23];

    float* ws      = (float*)d_ws;
    float* q_buf   = ws + 0;          // 393216
    float* qp_buf  = ws + 393216;     // 294912
    float* kp_buf  = ws + 688128;     // 294912
    float* gq_buf  = ws + 983040;     // 49152
    float* gk_buf  = ws + 1032192;    // 49152
    float* k_buf   = ws + 1081344;    // 393216
    float* v_buf   = ws + 1474560;    // 393216
    float* vp_buf  = ws + 1867776;    // 589824 (total 2457600)
    float* featbuf = ws + 0;          // overlays buffers dead after attn
    float* sgn_buf = ws + 1867776;    // 98304, overlays vp region; dead
                                      // before pt_transform writes vp

    float* out0  = (float*)d_out;       // 786432
    float* a_out = out0 + 786432;       // 6291456
    float* rawp  = a_out;               // raw point projections (dead before attn)

    init_bias_kernel<<<12672, 256, 0, stream>>>(bq, bkv, bqp, bkvp, bgq, bgk, bout,
                                                q_buf, k_buf, v_buf, rawp,
                                                gq_buf, gk_buf, out0);
    ln_kernel<<<256, 256, 0, stream>>>(s, g_gamma, g_beta, sgn_buf);
    proj_kernel<<<1152, 256, 0, stream>>>(s, wq, wkv, wqp, wkvp,
                                          q_buf, k_buf, v_buf, rawp);
    ggemm_kernel<<<96, 256, 0, stream>>>(sgn_buf, wgq, wgk, gq_buf, gk_buf);
    pt_transform_kernel<<<1536, 256, 0, stream>>>(rawp, rot, trans,
                                                  qp_buf, kp_buf, vp_buf);
    attn_kernel<<<768, 256, 0, stream>>>(q_buf, k_buf, qp_buf, kp_buf, gq_buf, gk_buf,
                                         trans, mask, head_weights, wdist, bdist, a_out);
    out_feat_kernel<<<512, 256, 0, stream>>>(a_out, v_buf, vp_buf, rot, trans, featbuf);
    out_gemm_kernel<<<768, 256, 0, stream>>>(featbuf, wout, out0);
}

// Round 6
// 272.096 us; speedup vs baseline: 1.2339x; 1.1499x over previous
//
#include <hip/hip_runtime.h>
#include <math.h>

#define NRES 256
#define CDIM 8
#define HNUM 12
#define CS   384

typedef __attribute__((ext_vector_type(8))) short bf16x8;
typedef __attribute__((ext_vector_type(4))) float f32x4;
typedef unsigned short ushort_t;

static __device__ __forceinline__ unsigned short f2bf(float x) {
    unsigned int u = __float_as_uint(x);
    unsigned int r = (u + 0x7fffu + ((u >> 16) & 1u)) >> 16;
    return (unsigned short)r;
}

// ===========================================================================
// Kernel 0: conversions + bias packing + out0 bias init.
//  R0: s -> s_bf (row-major bf16)
//  R1: WT[vc][k] bf16 (vc in unified 1152 space), read-coalesced over vc
//  R2: WTg[vc][k] bf16 (384 space: [0,192)=wgq, [192,384)=wgk)
//  R3: pbias[1152], R4: gbias[384], R5: out0 = bout
// ===========================================================================
__global__ __launch_bounds__(256) void convert_kernel(
    const float* __restrict__ s,
    const float* __restrict__ wq, const float* __restrict__ bq,
    const float* __restrict__ wkv, const float* __restrict__ bkv,
    const float* __restrict__ wqp, const float* __restrict__ bqp,
    const float* __restrict__ wkvp, const float* __restrict__ bkvp,
    const float* __restrict__ wgq, const float* __restrict__ bgq,
    const float* __restrict__ wgk, const float* __restrict__ bgk,
    const float* __restrict__ bout,
    ushort_t* __restrict__ s_bf, ushort_t* __restrict__ wt_bf,
    ushort_t* __restrict__ wtg_bf, float* __restrict__ pbias,
    float* __restrict__ gbias, float* __restrict__ out0)
{
    const int idx = blockIdx.x*256 + threadIdx.x;
    const int NS   = 2048*384;            // 786432
    const int NWT  = 384*1152;            // 442368
    const int NWTG = 384*384;             // 147456
    if (idx < NS) {
        s_bf[idx] = f2bf(s[idx]);
    } else if (idx < NS + NWT) {
        const int t = idx - NS;
        const int k = t / 1152, vc = t - k*1152;
        const float* w; int C, lc;
        if (vc < 192)      { w = wq;   C = 192; lc = vc; }
        else if (vc < 576) { w = wkv;  C = 384; lc = vc - 192; }
        else if (vc < 720) { w = wqp;  C = 144; lc = vc - 576; }
        else               { w = wkvp; C = 432; lc = vc - 720; }
        wt_bf[(size_t)vc*384 + k] = f2bf(w[(size_t)k*C + lc]);
    } else if (idx < NS + NWT + NWTG) {
        const int t = idx - NS - NWT;
        const int k = t / 384, vc = t - k*384;
        const float val = (vc < 192) ? wgq[(size_t)k*192 + vc]
                                     : wgk[(size_t)k*192 + vc - 192];
        wtg_bf[(size_t)vc*384 + k] = f2bf(val);
    } else if (idx < NS + NWT + NWTG + 1152) {
        const int i = idx - NS - NWT - NWTG;
        float b;
        if (i < 192)      b = bq[i];
        else if (i < 576) b = bkv[i - 192];
        else if (i < 720) b = bqp[i - 576];
        else              b = bkvp[i - 720];
        pbias[i] = b;
    } else if (idx < NS + NWT + NWTG + 1152 + 384) {
        const int i = idx - NS - NWT - NWTG - 1152;
        gbias[i] = (i < 192) ? bgq[i] : bgk[i - 192];
    } else if (idx < NS + NWT + NWTG + 1536 + 2048*384) {
        const int t = idx - NS - NWT - NWTG - 1536;
        out0[t] = bout[t % 384];
    }
}

// ===========================================================================
// Kernel 1: unified projection GEMM via MFMA bf16.
// C[2048][1152] = s_bf[2048][384] @ WT^T + pbias, K in one pass (no split-K).
// Block: 64 rows x 64 cols, 4 waves 2x2; wave = 32x32 via 2x2 16x16x32 mfma.
// Grid = 32 x 18 = 576. No LDS.
// ===========================================================================
__global__ __launch_bounds__(256) void proj_mfma_kernel(
    const ushort_t* __restrict__ s_bf, const ushort_t* __restrict__ wt_bf,
    const float* __restrict__ pbias,
    float* __restrict__ qo, float* __restrict__ ko, float* __restrict__ vo,
    float* __restrict__ rawp)
{
    const int blk = blockIdx.x;
    const int rt = blk / 18, ct = blk - rt*18;
    const int r0 = rt * 64, c0 = ct * 64;
    const int tid = threadIdx.x;
    const int wave = tid >> 6, lane = tid & 63;
    const int wrow = wave >> 1, wcol = wave & 1;
    const int m0 = r0 + wrow*32, n0 = c0 + wcol*32;
    const int qd = lane >> 4, lr = lane & 15;

    f32x4 acc00 = {0,0,0,0}, acc01 = {0,0,0,0}, acc10 = {0,0,0,0}, acc11 = {0,0,0,0};

    const ushort_t* a0p = s_bf  + (size_t)(m0 + lr)*384 + qd*8;
    const ushort_t* a1p = a0p + 16*384;
    const ushort_t* b0p = wt_bf + (size_t)(n0 + lr)*384 + qd*8;
    const ushort_t* b1p = b0p + 16*384;

    #pragma unroll
    for (int kk = 0; kk < 384; kk += 32) {
        const bf16x8 a0 = *(const bf16x8*)(a0p + kk);
        const bf16x8 a1 = *(const bf16x8*)(a1p + kk);
        const bf16x8 b0 = *(const bf16x8*)(b0p + kk);
        const bf16x8 b1 = *(const bf16x8*)(b1p + kk);
        acc00 = __builtin_amdgcn_mfma_f32_16x16x32_bf16(a0, b0, acc00, 0, 0, 0);
        acc01 = __builtin_amdgcn_mfma_f32_16x16x32_bf16(a0, b1, acc01, 0, 0, 0);
        acc10 = __builtin_amdgcn_mfma_f32_16x16x32_bf16(a1, b0, acc10, 0, 0, 0);
        acc11 = __builtin_amdgcn_mfma_f32_16x16x32_bf16(a1, b1, acc11, 0, 0, 0);
    }

    #pragma unroll
    for (int mt = 0; mt < 2; ++mt) {
        #pragma unroll
        for (int nt = 0; nt < 2; ++nt) {
            const f32x4 av = (mt==0) ? (nt==0 ? acc00 : acc01)
                                     : (nt==0 ? acc10 : acc11);
            const int col = n0 + nt*16 + lr;
            const float bb = pbias[col];
            #pragma unroll
            for (int reg = 0; reg < 4; ++reg) {
                const int row = m0 + mt*16 + qd*4 + reg;
                const float val = av[reg] + bb;
                if (col < 192) {
                    qo[(size_t)row*192 + col] = val;
                } else if (col < 576) {
                    const int lc = col - 192, h = lc >> 5, rm = lc & 31;
                    if (rm < 16) ko[(size_t)row*192 + h*16 + rm] = val;
                    else         vo[(size_t)row*192 + h*16 + rm - 16] = val;
                } else {
                    rawp[(size_t)row*576 + col - 576] = val;
                }
            }
        }
    }
}

// ===========================================================================
// Kernel 1b: rigid transform of raw points -> q_pts / k_pts / v_pts
// ===========================================================================
__global__ __launch_bounds__(256) void pt_transform_kernel(
    const float* __restrict__ rawp, const float* __restrict__ rot,
    const float* __restrict__ trans,
    float* __restrict__ qpo, float* __restrict__ kpo, float* __restrict__ vpo)
{
    const int t = blockIdx.x*256 + threadIdx.x;
    const int row = t / 192;
    const int p = t - row*192;
    const float* R = rot + (size_t)row*9;
    const float* T = trans + (size_t)row*3;
    const float* base = rawp + (size_t)row*576;
    float x, y, z;
    if (p < 48) { x = base[p];       y = base[48+p];  z = base[96+p]; }
    else { const int pk = p-48; x = base[144+pk]; y = base[288+pk]; z = base[432+pk]; }
    const float px = R[0]*x + R[1]*y + R[2]*z + T[0];
    const float py = R[3]*x + R[4]*y + R[5]*z + T[1];
    const float pz = R[6]*x + R[7]*y + R[8]*z + T[2];
    if (p < 48) {
        float* o = qpo + (size_t)row*144 + p*3;
        o[0]=px; o[1]=py; o[2]=pz;
    } else {
        const int pk = p-48, h = pk/12, pp = pk - h*12;
        if (pp < 4) { float* o = kpo + (size_t)row*144 + (h*4+pp)*3;     o[0]=px; o[1]=py; o[2]=pz; }
        else        { float* o = vpo + (size_t)row*288 + (h*8+(pp-4))*3; o[0]=px; o[1]=py; o[2]=pz; }
    }
}

// ===========================================================================
// Kernel 2a: s_g = mean over C + LayerNorm -> sgn_bf (bf16)
// ===========================================================================
__global__ __launch_bounds__(256) void ln_kernel(
    const float* __restrict__ s, const float* __restrict__ g_gamma,
    const float* __restrict__ g_beta, ushort_t* __restrict__ sgn_bf)
{
    const int n = blockIdx.x;
    const int tid = threadIdx.x;
    __shared__ float sg[CS];
    __shared__ float red[256];

    for (int d = tid; d < CS; d += 256) {
        float acc = 0.f;
        for (int c = 0; c < CDIM; ++c) acc += s[((size_t)c*NRES+n)*CS + d];
        sg[d] = acc * (1.0f/CDIM);
    }
    __syncthreads();

    float lsum = 0.f;
    for (int d = tid; d < CS; d += 256) lsum += sg[d];
    red[tid] = lsum; __syncthreads();
    for (int st = 128; st > 0; st >>= 1) { if (tid < st) red[tid] += red[tid+st]; __syncthreads(); }
    const float mean = red[0] * (1.0f/CS);
    __syncthreads();

    float lvar = 0.f;
    for (int d = tid; d < CS; d += 256) { float df = sg[d]-mean; lvar += df*df; }
    red[tid] = lvar; __syncthreads();
    for (int st = 128; st > 0; st >>= 1) { if (tid < st) red[tid] += red[tid+st]; __syncthreads(); }
    const float var = red[0] * (1.0f/CS);
    __syncthreads();

    const float inv = rsqrtf(var + 1e-5f);
    for (int d = tid; d < CS; d += 256)
        sgn_bf[(size_t)n*CS + d] = f2bf((sg[d]-mean)*inv*g_gamma[d] + g_beta[d]);
}

// ===========================================================================
// Kernel 2b: g_q|g_k = sgn @ [wgq|wgk] via MFMA bf16. 256x384 @ 384x384.
// Grid = 4 x 6 = 24 blocks, same wave structure as proj_mfma.
// ===========================================================================
__global__ __launch_bounds__(256) void ggemm_mfma_kernel(
    const ushort_t* __restrict__ sgn_bf, const ushort_t* __restrict__ wtg_bf,
    const float* __restrict__ gbias,
    float* __restrict__ gqo, float* __restrict__ gko)
{
    const int blk = blockIdx.x;
    const int rt = blk / 6, ct = blk - rt*6;
    const int r0 = rt * 64, c0 = ct * 64;
    const int tid = threadIdx.x;
    const int wave = tid >> 6, lane = tid & 63;
    const int wrow = wave >> 1, wcol = wave & 1;
    const int m0 = r0 + wrow*32, n0 = c0 + wcol*32;
    const int qd = lane >> 4, lr = lane & 15;

    f32x4 acc00 = {0,0,0,0}, acc01 = {0,0,0,0}, acc10 = {0,0,0,0}, acc11 = {0,0,0,0};

    const ushort_t* a0p = sgn_bf + (size_t)(m0 + lr)*384 + qd*8;
    const ushort_t* a1p = a0p + 16*384;
    const ushort_t* b0p = wtg_bf + (size_t)(n0 + lr)*384 + qd*8;
    const ushort_t* b1p = b0p + 16*384;

    #pragma unroll
    for (int kk = 0; kk < 384; kk += 32) {
        const bf16x8 a0 = *(const bf16x8*)(a0p + kk);
        const bf16x8 a1 = *(const bf16x8*)(a1p + kk);
        const bf16x8 b0 = *(const bf16x8*)(b0p + kk);
        const bf16x8 b1 = *(const bf16x8*)(b1p + kk);
        acc00 = __builtin_amdgcn_mfma_f32_16x16x32_bf16(a0, b0, acc00, 0, 0, 0);
        acc01 = __builtin_amdgcn_mfma_f32_16x16x32_bf16(a0, b1, acc01, 0, 0, 0);
        acc10 = __builtin_amdgcn_mfma_f32_16x16x32_bf16(a1, b0, acc10, 0, 0, 0);
        acc11 = __builtin_amdgcn_mfma_f32_16x16x32_bf16(a1, b1, acc11, 0, 0, 0);
    }

    #pragma unroll
    for (int mt = 0; mt < 2; ++mt) {
        #pragma unroll
        for (int nt = 0; nt < 2; ++nt) {
            const f32x4 av = (mt==0) ? (nt==0 ? acc00 : acc01)
                                     : (nt==0 ? acc10 : acc11);
            const int col = n0 + nt*16 + lr;
            const float bb = gbias[col];
            #pragma unroll
            for (int reg = 0; reg < 4; ++reg) {
                const int row = m0 + mt*16 + qd*4 + reg;
                const float val = av[reg] + bb;
                if (col < 192) gqo[(size_t)row*192 + col]       = val;
                else           gko[(size_t)row*192 + col - 192] = val;
            }
        }
    }
}

// ===========================================================================
// Kernel 3: attention logits + softmax (XOR-swizzled ksh/gksh). fp32.
// ===========================================================================
__global__ __launch_bounds__(256) void attn_kernel(
    const float* __restrict__ q, const float* __restrict__ k,
    const float* __restrict__ q_pts, const float* __restrict__ k_pts,
    const float* __restrict__ g_q, const float* __restrict__ g_k,
    const float* __restrict__ trans, const float* __restrict__ mask,
    const float* __restrict__ head_weights, const float* __restrict__ wdist,
    const float* __restrict__ bdist, float* __restrict__ a_out)
{
    const int blk = blockIdx.x;
    const int iq = blk & 7;
    const int h  = (blk >> 3) % HNUM;
    const int c  = blk / (8*HNUM);
    const int i0 = iq * 32;
    const int tid = threadIdx.x;

    __shared__ __align__(16) float ksh[256*16];
    __shared__ __align__(16) float gksh[256*16];
    __shared__ __align__(16) float kpsh[256*12];
    __shared__ __align__(16) float qsh[32*16];
    __shared__ __align__(16) float gqsh[32*16];
    __shared__ __align__(16) float qpsh[32*12];
    __shared__ float tsh[256*3];
    __shared__ float msh[256];
    __shared__ float wdsh[12], bdsh[12];

    for (int t = tid; t < 4096; t += 256) {
        const int j = t >> 4, d = t & 15;
        const int qd = d >> 2, lo = d & 3;
        const int phys = j*16 + (((qd + j) & 3) << 2) + lo;
        ksh[phys]  = k[((size_t)c*NRES + j)*192 + h*16 + d];
        gksh[phys] = g_k[j*192 + h*16 + d];
    }
    for (int t = tid; t < 3072; t += 256) {
        const int j = t / 12, d = t - j*12;
        kpsh[t] = k_pts[((size_t)c*NRES + j)*144 + h*12 + d];
    }
    for (int t = tid; t < 512; t += 256) {
        const int i = t >> 4, d = t & 15;
        qsh[t]  = q[((size_t)c*NRES + i0 + i)*192 + h*16 + d];
        gqsh[t] = g_q[(i0 + i)*192 + h*16 + d];
    }
    for (int t = tid; t < 384; t += 256) {
        const int i = t / 12, d = t - i*12;
        qpsh[t] = q_pts[((size_t)c*NRES + i0 + i)*144 + h*12 + d];
    }
    for (int t = tid; t < 768; t += 256) tsh[t] = trans[(size_t)c*768 + t];
    if (tid < 256) msh[tid] = mask[c*NRES + tid];
    if (tid < 12) { wdsh[tid] = wdist[tid]; bdsh[tid] = bdist[tid]; }
    __syncthreads();

    const float s54   = 0.13608276348795434f;
    const float scale = 0.14433756729740643f;
    const float hwv = 0.5f * logf(1.0f + expf(head_weights[h])) * s54;

    const int wave = tid >> 6, lane = tid & 63;

    for (int rr = 0; rr < 8; ++rr) {
        const int il = wave*8 + rr;
        const int i  = i0 + il;
        float4 qv[4], gv[4];
        #pragma unroll
        for (int l = 0; l < 4; ++l) {
            qv[l] = *(const float4*)&qsh[il*16 + l*4];
            gv[l] = *(const float4*)&gqsh[il*16 + l*4];
        }
        const float4 a0 = *(const float4*)&qpsh[il*12 + 0];
        const float4 a1 = *(const float4*)&qpsh[il*12 + 4];
        const float4 a2 = *(const float4*)&qpsh[il*12 + 8];
        const float mi = msh[i];

        float lg[4];
        #pragma unroll
        for (int jj = 0; jj < 4; ++jj) {
            const int j = jj*64 + lane;
            float qk = 0.f, gd = 0.f;
            #pragma unroll
            for (int l = 0; l < 4; ++l) {
                const int slot = (l + j) & 3;
                const float4 kk = *(const float4*)&ksh[j*16 + slot*4];
                const float4 ge = *(const float4*)&gksh[j*16 + slot*4];
                qk += qv[l].x*kk.x + qv[l].y*kk.y + qv[l].z*kk.z + qv[l].w*kk.w;
                gd += gv[l].x*ge.x + gv[l].y*ge.y + gv[l].z*ge.z + gv[l].w*ge.w;
            }
            const float4 c0 = *(const float4*)&kpsh[j*12 + 0];
            const float4 c1 = *(const float4*)&kpsh[j*12 + 4];
            const float4 c2 = *(const float4*)&kpsh[j*12 + 8];
            float dx, dy, dz, pt;
            dx = a0.x - c0.x; dy = a0.y - c0.y; dz = a0.z - c0.z;
            pt  = dx*dx + dy*dy + dz*dz;
            dx = a0.w - c0.w; dy = a1.x - c1.x; dz = a1.y - c1.y;
            pt += dx*dx + dy*dy + dz*dz;
            dx = a1.z - c1.z; dy = a1.w - c1.w; dz = a2.x - c2.x;
            pt += dx*dx + dy*dy + dz*dz;
            dx = a2.y - c2.y; dy = a2.z - c2.z; dz = a2.w - c2.w;
            pt += dx*dx + dy*dy + dz*dz;

            const int f   = h*65536 + i*256 + j;
            const int ii  = f / 3072;
            const int rem = f - ii*3072;
            const int jjx = rem / 12;
            const int ho  = rem - jjx*12;
            const float ddx = tsh[ii*3+0] - tsh[jjx*3+0];
            const float ddy = tsh[ii*3+1] - tsh[jjx*3+1];
            const float ddz = tsh[ii*3+2] - tsh[jjx*3+2];
            const float dist = sqrtf(ddx*ddx + ddy*ddy + ddz*ddz);

            lg[jj] = scale*(qk + gd) - hwv*pt
                   + 100000.0f*(mi*msh[j] - 1.0f)
                   + dist*wdsh[ho] + bdsh[ho];
        }
        float mx = fmaxf(fmaxf(lg[0], lg[1]), fmaxf(lg[2], lg[3]));
        #pragma unroll
        for (int off = 32; off > 0; off >>= 1) mx = fmaxf(mx, __shfl_xor(mx, off));
        float e[4]; float ssum = 0.f;
        #pragma unroll
        for (int jj = 0; jj < 4; ++jj) { e[jj] = __expf(lg[jj] - mx); ssum += e[jj]; }
        #pragma unroll
        for (int off = 32; off > 0; off >>= 1) ssum += __shfl_xor(ssum, off);
        const float inv = 1.0f / ssum;
        float* dst = a_out + (((size_t)c*HNUM + h)*NRES + i)*NRES;
        #pragma unroll
        for (int jj = 0; jj < 4; ++jj) dst[jj*64 + lane] = e[jj]*inv;
    }
}

// ===========================================================================
// Kernel 4a: o = a@v, o_pt = a@v_pts, inverse rigid, norms -> feat buffer.
// ===========================================================================
#define ASTR 258
__global__ __launch_bounds__(256) void out_feat_kernel(
    const float* __restrict__ a, const float* __restrict__ v,
    const float* __restrict__ v_pts, const float* __restrict__ rot,
    const float* __restrict__ trans, float* __restrict__ featbuf)
{
    const int blk = blockIdx.x;
    const int c  = blk >> 6;
    const int i0 = (blk & 63) * 4;
    const int tid = threadIdx.x;

    __shared__ float a_sh[48*ASTR];
    __shared__ float feat_sh[4*576];
    __shared__ float opt_sh[4*288];

    for (int t = tid; t < 12288; t += 256) {
        const int j = t & 255, rh = t >> 8;
        const int hh = rh % 12, r = rh / 12;
        a_sh[rh*ASTR + j] = a[(((size_t)c*HNUM + hh)*NRES + (i0+r))*NRES + j];
    }
    __syncthreads();

    if (tid < 240) {
        const int g  = tid / 120;
        const int cq = tid - g*120;
        int hh; const float* vbase; int vstride;
        if (cq < 48) { hh = cq >> 2; vbase = v + (size_t)c*NRES*192 + 4*cq; vstride = 192; }
        else { const int cp = (cq-48)*4; hh = cp/24;
               vbase = v_pts + (size_t)c*NRES*288 + cp; vstride = 288; }

        const int rh0 = (2*g)*12 + hh;
        const int rh1 = rh0 + 12;
        float4 acc0 = {0.f,0.f,0.f,0.f}, acc1 = {0.f,0.f,0.f,0.f};
        for (int j = 0; j < 256; ++j) {
            const float av0 = a_sh[rh0*ASTR + j];
            const float av1 = a_sh[rh1*ASTR + j];
            const float4 vv = *(const float4*)(vbase + (size_t)j*vstride);
            acc0.x = fmaf(av0, vv.x, acc0.x); acc0.y = fmaf(av0, vv.y, acc0.y);
            acc0.z = fmaf(av0, vv.z, acc0.z); acc0.w = fmaf(av0, vv.w, acc0.w);
            acc1.x = fmaf(av1, vv.x, acc1.x); acc1.y = fmaf(av1, vv.y, acc1.y);
            acc1.z = fmaf(av1, vv.z, acc1.z); acc1.w = fmaf(av1, vv.w, acc1.w);
        }
        if (cq < 48) {
            float* d0 = &feat_sh[(2*g)*576 + 4*cq];
            float* d1 = &feat_sh[(2*g+1)*576 + 4*cq];
            d0[0]=acc0.x; d0[1]=acc0.y; d0[2]=acc0.z; d0[3]=acc0.w;
            d1[0]=acc1.x; d1[1]=acc1.y; d1[2]=acc1.z; d1[3]=acc1.w;
        } else {
            const int cp = (cq-48)*4;
            float* d0 = &opt_sh[(2*g)*288 + cp];
            float* d1 = &opt_sh[(2*g+1)*288 + cp];
            d0[0]=acc0.x; d0[1]=acc0.y; d0[2]=acc0.z; d0[3]=acc0.w;
            d1[0]=acc1.x; d1[1]=acc1.y; d1[2]=acc1.z; d1[3]=acc1.w;
        }
    }
    __syncthreads();

    for (int t = tid; t < 384; t += 256) {
        const int r = t / 96, p = t - r*96;
        const int grow = c*NRES + i0 + r;
        const float x = opt_sh[r*288 + p*3+0] - trans[(size_t)grow*3+0];
        const float y = opt_sh[r*288 + p*3+1] - trans[(size_t)grow*3+1];
        const float z = opt_sh[r*288 + p*3+2] - trans[(size_t)grow*3+2];
        const float* R = rot + (size_t)grow*9;
        const float rx = R[0]*x + R[3]*y + R[6]*z;
        const float ry = R[1]*x + R[4]*y + R[7]*z;
        const float rz = R[2]*x + R[5]*y + R[8]*z;
        feat_sh[r*576 + 192 + p] = rx;
        feat_sh[r*576 + 288 + p] = ry;
        feat_sh[r*576 + 384 + p] = rz;
        feat_sh[r*576 + 480 + p] = sqrtf(rx*rx + ry*ry + rz*rz + 1e-8f);
    }
    __syncthreads();

    float* dst = featbuf + (size_t)(c*NRES + i0)*576;
    for (int t = tid; t < 2304; t += 256) dst[t] = feat_sh[t];
}

// ===========================================================================
// Kernel 4b: out0 += feat @ wout, fp32 SPLIT-K (bias via convert kernel).
// ===========================================================================
__global__ __launch_bounds__(256) void out_gemm_kernel(
    const float* __restrict__ featbuf, const float* __restrict__ wout,
    float* __restrict__ out0)
{
    const int blk = blockIdx.x;
    const int rt  = blk / 6;
    const int rem = blk - rt*6;
    const int ct  = rem >> 1;
    const int kh  = rem & 1;
    const int r0  = rt * 16;
    const int k0  = kh * 288;
    const int tid = threadIdx.x;
    const int wave = tid >> 6, lane = tid & 63;

    __shared__ __align__(16) float fsh[16*288];

    for (int t = tid; t < 16*72; t += 256) {
        const int r = t / 72, g = t - r*72;
        *(float4*)&fsh[r*288 + g*4] =
            *(const float4*)&featbuf[(size_t)(r0 + r)*576 + k0 + g*4];
    }

    const int c = ct*128 + lane*2;
    const int C = 384;

    float acc[4][2];
    #pragma unroll
    for (int r = 0; r < 4; ++r) { acc[r][0] = 0.f; acc[r][1] = 0.f; }
    __syncthreads();

    const float* p = wout + (size_t)k0*C + c;
    float2 w0 = *(const float2*)p;
    float2 w1 = *(const float2*)(p + C);
    float2 w2 = *(const float2*)(p + 2*C);
    float2 w3 = *(const float2*)(p + 3*C);
    const float* frow = &fsh[wave*4*288];

    for (int it = 0; it < 71; ++it) {
        const int d = it*4;
        const float* pn = p + 4*C;
        const float2 n0 = *(const float2*)pn;
        const float2 n1 = *(const float2*)(pn + C);
        const float2 n2 = *(const float2*)(pn + 2*C);
        const float2 n3 = *(const float2*)(pn + 3*C);
        #pragma unroll
        for (int r = 0; r < 4; ++r) {
            const float4 sv = *(const float4*)&frow[r*288 + d];
            acc[r][0] = fmaf(sv.x,w0.x,fmaf(sv.y,w1.x,fmaf(sv.z,w2.x,fmaf(sv.w,w3.x,acc[r][0]))));
            acc[r][1] = fmaf(sv.x,w0.y,fmaf(sv.y,w1.y,fmaf(sv.z,w2.y,fmaf(sv.w,w3.y,acc[r][1]))));
        }
        w0 = n0; w1 = n1; w2 = n2; w3 = n3;
        p = pn;
    }
    {
        const int d = 71*4;
        #pragma unroll
        for (int r = 0; r < 4; ++r) {
            const float4 sv = *(const float4*)&frow[r*288 + d];
            acc[r][0] = fmaf(sv.x,w0.x,fmaf(sv.y,w1.x,fmaf(sv.z,w2.x,fmaf(sv.w,w3.x,acc[r][0]))));
            acc[r][1] = fmaf(sv.x,w0.y,fmaf(sv.y,w1.y,fmaf(sv.z,w2.y,fmaf(sv.w,w3.y,acc[r][1]))));
        }
    }

    #pragma unroll
    for (int r = 0; r < 4; ++r) {
        const int grow = r0 + wave*4 + r;
        unsafeAtomicAdd(&out0[(size_t)grow*CS + c],     acc[r][0]);
        unsafeAtomicAdd(&out0[(size_t)grow*CS + c + 1], acc[r][1]);
    }
}

// ===========================================================================
extern "C" void kernel_launch(void* const* d_in, const int* in_sizes, int n_in,
                              void* d_out, int out_size, void* d_ws, size_t ws_size,
                              hipStream_t stream)
{
    const float* s     = (const float*)d_in[0];
    const float* rot   = (const float*)d_in[2];
    const float* trans = (const float*)d_in[3];
    const float* mask  = (const float*)d_in[4];
    const float* wq    = (const float*)d_in[5];
    const float* bq    = (const float*)d_in[6];
    const float* wkv   = (const float*)d_in[7];
    const float* bkv   = (const float*)d_in[8];
    const float* g_gamma = (const float*)d_in[9];
    const float* g_beta  = (const float*)d_in[10];
    const float* wgq   = (const float*)d_in[11];
    const float* bgq   = (const float*)d_in[12];
    const float* wgk   = (const float*)d_in[13];
    const float* bgk   = (const float*)d_in[14];
    const float* wqp   = (const float*)d_in[15];
    const float* bqp   = (const float*)d_in[16];
    const float* wkvp  = (const float*)d_in[17];
    const float* bkvp  = (const float*)d_in[18];
    const float* head_weights = (const float*)d_in[19];
    const float* wdist = (const float*)d_in[20];
    const float* bdist = (const float*)d_in[21];
    const float* wout  = (const float*)d_in[22];
    const float* bout  = (const float*)d_in[23];

    float* ws      = (float*)d_ws;
    float* q_buf   = ws + 0;          // 393216
    float* qp_buf  = ws + 393216;     // 294912
    float* kp_buf  = ws + 688128;     // 294912
    float* gq_buf  = ws + 983040;     // 49152
    float* gk_buf  = ws + 1032192;    // 49152
    float* k_buf   = ws + 1081344;    // 393216
    float* v_buf   = ws + 1474560;    // 393216
    float* vp_buf  = ws + 1867776;    // 589824 (total 2457600)
    float* featbuf = ws + 0;          // overlays buffers dead after attn
    ushort_t* sgn_bf = (ushort_t*)(ws + 1867776); // 98304 bf16, overlays vp
                                                  // region; dead before
                                                  // pt_transform writes vp

    float* out0  = (float*)d_out;       // 786432
    float* a_out = out0 + 786432;       // 6291456
    // overlays inside a_out (all dead before attn writes):
    float*    rawp   = a_out;                              // 1179648 floats
    ushort_t* s_bf   = (ushort_t*)(a_out + 1179648);       // 786432 bf16
    ushort_t* wt_bf  = (ushort_t*)(a_out + 1572864);       // 442368 bf16
    ushort_t* wtg_bf = (ushort_t*)(a_out + 1794048);       // 147456 bf16
    float*    pbias  = a_out + 1867776;                    // 1152
    float*    gbias  = a_out + 1868928;                    // 384

    convert_kernel<<<8454, 256, 0, stream>>>(s, wq, bq, wkv, bkv, wqp, bqp,
                                             wkvp, bkvp, wgq, bgq, wgk, bgk, bout,
                                             s_bf, wt_bf, wtg_bf, pbias, gbias, out0);
    ln_kernel<<<256, 256, 0, stream>>>(s, g_gamma, g_beta, sgn_bf);
    proj_mfma_kernel<<<576, 256, 0, stream>>>(s_bf, wt_bf, pbias,
                                              q_buf, k_buf, v_buf, rawp);
    ggemm_mfma_kernel<<<24, 256, 0, stream>>>(sgn_bf, wtg_bf, gbias,
                                              gq_buf, gk_buf);
    pt_transform_kernel<<<1536, 256, 0, stream>>>(rawp, rot, trans,
                                                  qp_buf, kp_buf, vp_buf);
    attn_kernel<<<768, 256, 0, stream>>>(q_buf, k_buf, qp_buf, kp_buf, gq_buf, gk_buf,
                                         trans, mask, head_weights, wdist, bdist, a_out);
    out_feat_kernel<<<512, 256, 0, stream>>>(a_out, v_buf, vp_buf, rot, trans, featbuf);
    out_gemm_kernel<<<768, 256, 0, stream>>>(featbuf, wout, out0);
}

// Round 7
// 248.308 us; speedup vs baseline: 1.3521x; 1.0958x over previous
//
#include <hip/hip_runtime.h>
#include <math.h>

#define NRES 256
#define CDIM 8
#define HNUM 12
#define CS   384

typedef __attribute__((ext_vector_type(8))) short bf16x8;
typedef __attribute__((ext_vector_type(4))) float f32x4;
typedef unsigned short ushort_t;

static __device__ __forceinline__ unsigned short f2bf(float x) {
    unsigned int u = __float_as_uint(x);
    unsigned int r = (u + 0x7fffu + ((u >> 16) & 1u)) >> 16;
    return (unsigned short)r;
}
static __device__ __forceinline__ float bf2f(unsigned short h) {
    return __uint_as_float(((unsigned int)h) << 16);
}

// ===========================================================================
// Kernel 0: conversions + bias packing + out0 bias init.
// ===========================================================================
__global__ __launch_bounds__(256) void convert_kernel(
    const float* __restrict__ s,
    const float* __restrict__ wq, const float* __restrict__ bq,
    const float* __restrict__ wkv, const float* __restrict__ bkv,
    const float* __restrict__ wqp, const float* __restrict__ bqp,
    const float* __restrict__ wkvp, const float* __restrict__ bkvp,
    const float* __restrict__ wgq, const float* __restrict__ bgq,
    const float* __restrict__ wgk, const float* __restrict__ bgk,
    const float* __restrict__ bout,
    ushort_t* __restrict__ s_bf, ushort_t* __restrict__ wt_bf,
    ushort_t* __restrict__ wtg_bf, float* __restrict__ pbias,
    float* __restrict__ gbias, float* __restrict__ out0)
{
    const int idx = blockIdx.x*256 + threadIdx.x;
    const int NS   = 2048*384;
    const int NWT  = 384*1152;
    const int NWTG = 384*384;
    if (idx < NS) {
        s_bf[idx] = f2bf(s[idx]);
    } else if (idx < NS + NWT) {
        const int t = idx - NS;
        const int k = t / 1152, vc = t - k*1152;
        const float* w; int C, lc;
        if (vc < 192)      { w = wq;   C = 192; lc = vc; }
        else if (vc < 576) { w = wkv;  C = 384; lc = vc - 192; }
        else if (vc < 720) { w = wqp;  C = 144; lc = vc - 576; }
        else               { w = wkvp; C = 432; lc = vc - 720; }
        wt_bf[(size_t)vc*384 + k] = f2bf(w[(size_t)k*C + lc]);
    } else if (idx < NS + NWT + NWTG) {
        const int t = idx - NS - NWT;
        const int k = t / 384, vc = t - k*384;
        const float val = (vc < 192) ? wgq[(size_t)k*192 + vc]
                                     : wgk[(size_t)k*192 + vc - 192];
        wtg_bf[(size_t)vc*384 + k] = f2bf(val);
    } else if (idx < NS + NWT + NWTG + 1152) {
        const int i = idx - NS - NWT - NWTG;
        float b;
        if (i < 192)      b = bq[i];
        else if (i < 576) b = bkv[i - 192];
        else if (i < 720) b = bqp[i - 576];
        else              b = bkvp[i - 720];
        pbias[i] = b;
    } else if (idx < NS + NWT + NWTG + 1152 + 384) {
        const int i = idx - NS - NWT - NWTG - 1152;
        gbias[i] = (i < 192) ? bgq[i] : bgk[i - 192];
    } else if (idx < NS + NWT + NWTG + 1536 + 2048*384) {
        const int t = idx - NS - NWT - NWTG - 1536;
        out0[t] = bout[t % 384];
    }
}

// ===========================================================================
// Kernel 1: unified projection GEMM via MFMA bf16.
// ===========================================================================
__global__ __launch_bounds__(256) void proj_mfma_kernel(
    const ushort_t* __restrict__ s_bf, const ushort_t* __restrict__ wt_bf,
    const float* __restrict__ pbias,
    float* __restrict__ qo, float* __restrict__ ko, float* __restrict__ vo,
    float* __restrict__ rawp)
{
    const int blk = blockIdx.x;
    const int rt = blk / 18, ct = blk - rt*18;
    const int r0 = rt * 64, c0 = ct * 64;
    const int tid = threadIdx.x;
    const int wave = tid >> 6, lane = tid & 63;
    const int wrow = wave >> 1, wcol = wave & 1;
    const int m0 = r0 + wrow*32, n0 = c0 + wcol*32;
    const int qd = lane >> 4, lr = lane & 15;

    f32x4 acc00 = {0,0,0,0}, acc01 = {0,0,0,0}, acc10 = {0,0,0,0}, acc11 = {0,0,0,0};

    const ushort_t* a0p = s_bf  + (size_t)(m0 + lr)*384 + qd*8;
    const ushort_t* a1p = a0p + 16*384;
    const ushort_t* b0p = wt_bf + (size_t)(n0 + lr)*384 + qd*8;
    const ushort_t* b1p = b0p + 16*384;

    #pragma unroll
    for (int kk = 0; kk < 384; kk += 32) {
        const bf16x8 a0 = *(const bf16x8*)(a0p + kk);
        const bf16x8 a1 = *(const bf16x8*)(a1p + kk);
        const bf16x8 b0 = *(const bf16x8*)(b0p + kk);
        const bf16x8 b1 = *(const bf16x8*)(b1p + kk);
        acc00 = __builtin_amdgcn_mfma_f32_16x16x32_bf16(a0, b0, acc00, 0, 0, 0);
        acc01 = __builtin_amdgcn_mfma_f32_16x16x32_bf16(a0, b1, acc01, 0, 0, 0);
        acc10 = __builtin_amdgcn_mfma_f32_16x16x32_bf16(a1, b0, acc10, 0, 0, 0);
        acc11 = __builtin_amdgcn_mfma_f32_16x16x32_bf16(a1, b1, acc11, 0, 0, 0);
    }

    #pragma unroll
    for (int mt = 0; mt < 2; ++mt) {
        #pragma unroll
        for (int nt = 0; nt < 2; ++nt) {
            const f32x4 av = (mt==0) ? (nt==0 ? acc00 : acc01)
                                     : (nt==0 ? acc10 : acc11);
            const int col = n0 + nt*16 + lr;
            const float bb = pbias[col];
            #pragma unroll
            for (int reg = 0; reg < 4; ++reg) {
                const int row = m0 + mt*16 + qd*4 + reg;
                const float val = av[reg] + bb;
                if (col < 192) {
                    qo[(size_t)row*192 + col] = val;
                } else if (col < 576) {
                    const int lc = col - 192, h = lc >> 5, rm = lc & 31;
                    if (rm < 16) ko[(size_t)row*192 + h*16 + rm] = val;
                    else         vo[(size_t)row*192 + h*16 + rm - 16] = val;
                } else {
                    rawp[(size_t)row*576 + col - 576] = val;
                }
            }
        }
    }
}

// ===========================================================================
// Kernel 1b: rigid transform of raw points -> q_pts / k_pts / v_pts
// ===========================================================================
__global__ __launch_bounds__(256) void pt_transform_kernel(
    const float* __restrict__ rawp, const float* __restrict__ rot,
    const float* __restrict__ trans,
    float* __restrict__ qpo, float* __restrict__ kpo, float* __restrict__ vpo)
{
    const int t = blockIdx.x*256 + threadIdx.x;
    const int row = t / 192;
    const int p = t - row*192;
    const float* R = rot + (size_t)row*9;
    const float* T = trans + (size_t)row*3;
    const float* base = rawp + (size_t)row*576;
    float x, y, z;
    if (p < 48) { x = base[p];       y = base[48+p];  z = base[96+p]; }
    else { const int pk = p-48; x = base[144+pk]; y = base[288+pk]; z = base[432+pk]; }
    const float px = R[0]*x + R[1]*y + R[2]*z + T[0];
    const float py = R[3]*x + R[4]*y + R[5]*z + T[1];
    const float pz = R[6]*x + R[7]*y + R[8]*z + T[2];
    if (p < 48) {
        float* o = qpo + (size_t)row*144 + p*3;
        o[0]=px; o[1]=py; o[2]=pz;
    } else {
        const int pk = p-48, h = pk/12, pp = pk - h*12;
        if (pp < 4) { float* o = kpo + (size_t)row*144 + (h*4+pp)*3;     o[0]=px; o[1]=py; o[2]=pz; }
        else        { float* o = vpo + (size_t)row*288 + (h*8+(pp-4))*3; o[0]=px; o[1]=py; o[2]=pz; }
    }
}

// ===========================================================================
// Kernel 2a: s_g = mean over C + LayerNorm -> sgn_bf (bf16)
// ===========================================================================
__global__ __launch_bounds__(256) void ln_kernel(
    const float* __restrict__ s, const float* __restrict__ g_gamma,
    const float* __restrict__ g_beta, ushort_t* __restrict__ sgn_bf)
{
    const int n = blockIdx.x;
    const int tid = threadIdx.x;
    __shared__ float sg[CS];
    __shared__ float red[256];

    for (int d = tid; d < CS; d += 256) {
        float acc = 0.f;
        for (int c = 0; c < CDIM; ++c) acc += s[((size_t)c*NRES+n)*CS + d];
        sg[d] = acc * (1.0f/CDIM);
    }
    __syncthreads();

    float lsum = 0.f;
    for (int d = tid; d < CS; d += 256) lsum += sg[d];
    red[tid] = lsum; __syncthreads();
    for (int st = 128; st > 0; st >>= 1) { if (tid < st) red[tid] += red[tid+st]; __syncthreads(); }
    const float mean = red[0] * (1.0f/CS);
    __syncthreads();

    float lvar = 0.f;
    for (int d = tid; d < CS; d += 256) { float df = sg[d]-mean; lvar += df*df; }
    red[tid] = lvar; __syncthreads();
    for (int st = 128; st > 0; st >>= 1) { if (tid < st) red[tid] += red[tid+st]; __syncthreads(); }
    const float var = red[0] * (1.0f/CS);
    __syncthreads();

    const float inv = rsqrtf(var + 1e-5f);
    for (int d = tid; d < CS; d += 256)
        sgn_bf[(size_t)n*CS + d] = f2bf((sg[d]-mean)*inv*g_gamma[d] + g_beta[d]);
}

// ===========================================================================
// Kernel 2b: g_q|g_k = sgn @ [wgq|wgk] via MFMA bf16.
// ===========================================================================
__global__ __launch_bounds__(256) void ggemm_mfma_kernel(
    const ushort_t* __restrict__ sgn_bf, const ushort_t* __restrict__ wtg_bf,
    const float* __restrict__ gbias,
    float* __restrict__ gqo, float* __restrict__ gko)
{
    const int blk = blockIdx.x;
    const int rt = blk / 6, ct = blk - rt*6;
    const int r0 = rt * 64, c0 = ct * 64;
    const int tid = threadIdx.x;
    const int wave = tid >> 6, lane = tid & 63;
    const int wrow = wave >> 1, wcol = wave & 1;
    const int m0 = r0 + wrow*32, n0 = c0 + wcol*32;
    const int qd = lane >> 4, lr = lane & 15;

    f32x4 acc00 = {0,0,0,0}, acc01 = {0,0,0,0}, acc10 = {0,0,0,0}, acc11 = {0,0,0,0};

    const ushort_t* a0p = sgn_bf + (size_t)(m0 + lr)*384 + qd*8;
    const ushort_t* a1p = a0p + 16*384;
    const ushort_t* b0p = wtg_bf + (size_t)(n0 + lr)*384 + qd*8;
    const ushort_t* b1p = b0p + 16*384;

    #pragma unroll
    for (int kk = 0; kk < 384; kk += 32) {
        const bf16x8 a0 = *(const bf16x8*)(a0p + kk);
        const bf16x8 a1 = *(const bf16x8*)(a1p + kk);
        const bf16x8 b0 = *(const bf16x8*)(b0p + kk);
        const bf16x8 b1 = *(const bf16x8*)(b1p + kk);
        acc00 = __builtin_amdgcn_mfma_f32_16x16x32_bf16(a0, b0, acc00, 0, 0, 0);
        acc01 = __builtin_amdgcn_mfma_f32_16x16x32_bf16(a0, b1, acc01, 0, 0, 0);
        acc10 = __builtin_amdgcn_mfma_f32_16x16x32_bf16(a1, b0, acc10, 0, 0, 0);
        acc11 = __builtin_amdgcn_mfma_f32_16x16x32_bf16(a1, b1, acc11, 0, 0, 0);
    }

    #pragma unroll
    for (int mt = 0; mt < 2; ++mt) {
        #pragma unroll
        for (int nt = 0; nt < 2; ++nt) {
            const f32x4 av = (mt==0) ? (nt==0 ? acc00 : acc01)
                                     : (nt==0 ? acc10 : acc11);
            const int col = n0 + nt*16 + lr;
            const float bb = gbias[col];
            #pragma unroll
            for (int reg = 0; reg < 4; ++reg) {
                const int row = m0 + mt*16 + qd*4 + reg;
                const float val = av[reg] + bb;
                if (col < 192) gqo[(size_t)row*192 + col]       = val;
                else           gko[(size_t)row*192 + col - 192] = val;
            }
        }
    }
}

// ===========================================================================
// Kernel 3: attention via MFMA.
// logit = scale*(q.k + gq.gk) - hwv*|qp-kp|^2 + mask + db
//       = A_i . B_j - hwv*|qp'|^2 - hwv*|kp'|^2 + mask + db
// A=[scale*q(16), scale*gq(16), sh*qp_hi(12), sh*qp_hi(12), sh*qp_lo(12), 0..]
// B=[k(16),       gk(16),       sh*kp_hi(12), sh*kp_lo(12), sh*kp_hi(12), 0..]
// sh = sqrt(2*hwv); qp' = qp - centroid(trans_c) (translation-invariant).
// Block = (c, h, i-half of 128) -> 192 blocks, 4 waves (32 rows each).
// ===========================================================================
__global__ __launch_bounds__(256) void attn_mfma_kernel(
    const float* __restrict__ q, const float* __restrict__ k,
    const float* __restrict__ q_pts, const float* __restrict__ k_pts,
    const float* __restrict__ g_q, const float* __restrict__ g_k,
    const float* __restrict__ trans, const float* __restrict__ mask,
    const float* __restrict__ head_weights, const float* __restrict__ wdist,
    const float* __restrict__ bdist, float* __restrict__ a_out)
{
    const int blk  = blockIdx.x;
    const int half = blk & 1;
    const int ch   = blk >> 1;
    const int h    = ch % HNUM;
    const int c    = ch / HNUM;
    const int i0   = half * 128;
    const int tid  = threadIdx.x;

    __shared__ ushort_t Bsh[256*96];     // 48 KB
    __shared__ ushort_t Ash[128*96];     // 24 KB
    __shared__ float dsh[12*256];        // 12 KB dist LUT
    __shared__ float tsh[768];
    __shared__ float msh[256];
    __shared__ float kn_sh[256];
    __shared__ float qn_sh[128];
    __shared__ float wdsh[12], bdsh[12];
    __shared__ float cpart[96];
    __shared__ float censh[3];

    // --- stage trans / mask / dist params ---
    for (int t = tid; t < 768; t += 256) tsh[t] = trans[(size_t)c*768 + t];
    msh[tid] = mask[c*NRES + tid];
    if (tid < 12) { wdsh[tid] = wdist[tid]; bdsh[tid] = bdist[tid]; }
    __syncthreads();

    // --- centroid of trans_c ---
    if (tid < 96) {
        const int coord = tid % 3, chunk = tid / 3;
        float sv = 0.f;
        for (int e = 0; e < 8; ++e) sv += tsh[(chunk*8+e)*3 + coord];
        cpart[tid] = sv;
    }
    __syncthreads();
    if (tid < 3) {
        float sv = 0.f;
        for (int e = 0; e < 32; ++e) sv += cpart[e*3 + tid];
        censh[tid] = sv * (1.0f/256.0f);
    }
    __syncthreads();

    const float s54   = 0.13608276348795434f;  // sqrt(1/54)
    const float scale = 0.14433756729740643f;  // sqrt(1/48)
    const float hwv = 0.5f * logf(1.0f + expf(head_weights[h])) * s54;
    const float sh  = sqrtf(2.0f * hwv);
    const float cx = censh[0], cy = censh[1], cz = censh[2];

    // --- build B rows (all 256 threads, one j each) ---
    {
        const int j = tid;
        const float* kr  = k    + ((size_t)c*NRES + j)*192 + h*16;
        const float* gkr = g_k  + (size_t)j*192 + h*16;
        const float* kpr = k_pts+ ((size_t)c*NRES + j)*144 + h*12;
        ushort_t* br = &Bsh[j*96];
        #pragma unroll
        for (int e = 0; e < 16; ++e) br[e]    = f2bf(kr[e]);
        #pragma unroll
        for (int e = 0; e < 16; ++e) br[16+e] = f2bf(gkr[e]);
        float kn = 0.f;
        #pragma unroll
        for (int e = 0; e < 12; ++e) {
            const float cen = (e%3==0) ? cx : ((e%3==1) ? cy : cz);
            const float kp = kpr[e] - cen;
            kn += kp*kp;
            const float sp = sh * kp;
            const ushort_t hi = f2bf(sp);
            br[32+e] = hi;
            br[44+e] = f2bf(sp - bf2f(hi));
            br[56+e] = hi;
        }
        #pragma unroll
        for (int e = 68; e < 96; ++e) br[e] = 0;
        kn_sh[j] = hwv * kn;
    }

    // --- build A rows (threads 0..127, one i each) ---
    if (tid < 128) {
        const int il = i0 + tid;
        const float* qr  = q    + ((size_t)c*NRES + il)*192 + h*16;
        const float* gqr = g_q  + (size_t)il*192 + h*16;
        const float* qpr = q_pts+ ((size_t)c*NRES + il)*144 + h*12;
        ushort_t* ar = &Ash[tid*96];
        #pragma unroll
        for (int e = 0; e < 16; ++e) ar[e]    = f2bf(scale*qr[e]);
        #pragma unroll
        for (int e = 0; e < 16; ++e) ar[16+e] = f2bf(scale*gqr[e]);
        float qn = 0.f;
        #pragma unroll
        for (int e = 0; e < 12; ++e) {
            const float cen = (e%3==0) ? cx : ((e%3==1) ? cy : cz);
            const float qp = qpr[e] - cen;
            qn += qp*qp;
            const float sp = sh * qp;
            const ushort_t hi = f2bf(sp);
            ar[32+e] = hi;
            ar[44+e] = hi;
            ar[56+e] = f2bf(sp - bf2f(hi));
        }
        #pragma unroll
        for (int e = 68; e < 96; ++e) ar[e] = 0;
        qn_sh[tid] = hwv * qn;
    }

    // --- dist LUT: ii range for this (h, i-half) is <= 12 values ---
    const int Fmin = h*65536 + i0*256;
    const int iibase = Fmin / 3072;
    const int NI = (Fmin + 127*256 + 255)/3072 - iibase + 1;
    for (int idx = tid; idx < NI*256; idx += 256) {
        const int e = idx >> 8, jj = idx & 255;
        const int ia = iibase + e;
        const float dx = tsh[ia*3+0] - tsh[jj*3+0];
        const float dy = tsh[ia*3+1] - tsh[jj*3+1];
        const float dz = tsh[ia*3+2] - tsh[jj*3+2];
        dsh[idx] = sqrtf(dx*dx + dy*dy + dz*dz);
    }
    __syncthreads();

    // --- main: per wave 32 rows = 2 groups of 16 ---
    const int wave = tid >> 6, lane = tid & 63;
    const int qd = lane >> 4, lr = lane & 15;

    for (int g = 0; g < 2; ++g) {
        const int m0 = wave*32 + g*16;   // local row base in Ash
        const ushort_t* ap = &Ash[(m0 + lr)*96 + qd*8];
        const bf16x8 af0 = *(const bf16x8*)(ap);
        const bf16x8 af1 = *(const bf16x8*)(ap + 32);
        const bf16x8 af2 = *(const bf16x8*)(ap + 64);

        f32x4 acc[16];
        #pragma unroll
        for (int t = 0; t < 16; ++t) {
            const ushort_t* bp = &Bsh[(t*16 + lr)*96 + qd*8];
            f32x4 a = {0.f,0.f,0.f,0.f};
            a = __builtin_amdgcn_mfma_f32_16x16x32_bf16(af0, *(const bf16x8*)(bp),      a, 0, 0, 0);
            a = __builtin_amdgcn_mfma_f32_16x16x32_bf16(af1, *(const bf16x8*)(bp + 32), a, 0, 0, 0);
            a = __builtin_amdgcn_mfma_f32_16x16x32_bf16(af2, *(const bf16x8*)(bp + 64), a, 0, 0, 0);
            acc[t] = a;
        }

        // epilogue: bias terms + softmax over j
        const int ibase = m0 + qd*4;          // local (0..127)
        float qn_r[4], mb_r[4];
        int F0_[4];
        #pragma unroll
        for (int r = 0; r < 4; ++r) {
            const int il = i0 + ibase + r;     // chain-local i (0..255)
            qn_r[r] = qn_sh[ibase + r];
            mb_r[r] = 100000.0f * msh[il];
            F0_[r]  = h*65536 + il*256;
        }

        float mx[4] = {-1e30f,-1e30f,-1e30f,-1e30f};
        #pragma unroll
        for (int t = 0; t < 16; ++t) {
            const int j = t*16 + lr;
            const float knj = kn_sh[j];
            const float mj  = msh[j];
            #pragma unroll
            for (int r = 0; r < 4; ++r) {
                const unsigned int f = (unsigned int)(F0_[r] + j);
                const unsigned int p = f / 12u;
                const int ho = (int)(f - p*12u);
                const int ii = (int)(p >> 8);
                const int jj = (int)(p & 255u);
                const float dist = dsh[(ii - iibase)*256 + jj];
                const float db = dist*wdsh[ho] + bdsh[ho];
                const float lv = acc[t][r] - qn_r[r] - knj
                               + (mb_r[r]*mj - 100000.0f) + db;
                acc[t][r] = lv;
                mx[r] = fmaxf(mx[r], lv);
            }
        }
        #pragma unroll
        for (int r = 0; r < 4; ++r) {
            #pragma unroll
            for (int off = 1; off < 16; off <<= 1)
                mx[r] = fmaxf(mx[r], __shfl_xor(mx[r], off));
        }
        float sm[4] = {0.f,0.f,0.f,0.f};
        #pragma unroll
        for (int t = 0; t < 16; ++t) {
            #pragma unroll
            for (int r = 0; r < 4; ++r) {
                const float e = __expf(acc[t][r] - mx[r]);
                acc[t][r] = e;
                sm[r] += e;
            }
        }
        #pragma unroll
        for (int r = 0; r < 4; ++r) {
            #pragma unroll
            for (int off = 1; off < 16; off <<= 1)
                sm[r] += __shfl_xor(sm[r], off);
            sm[r] = 1.0f / sm[r];
        }
        float* dst = a_out + ((size_t)ch*NRES + (i0 + ibase))*NRES;
        #pragma unroll
        for (int t = 0; t < 16; ++t) {
            #pragma unroll
            for (int r = 0; r < 4; ++r)
                dst[(size_t)r*NRES + t*16 + lr] = acc[t][r]*sm[r];
        }
    }
}

// ===========================================================================
// Kernel 4a: o = a@v, o_pt = a@v_pts, inverse rigid, norms -> feat buffer.
// ===========================================================================
#define ASTR 258
__global__ __launch_bounds__(256) void out_feat_kernel(
    const float* __restrict__ a, const float* __restrict__ v,
    const float* __restrict__ v_pts, const float* __restrict__ rot,
    const float* __restrict__ trans, float* __restrict__ featbuf)
{
    const int blk = blockIdx.x;
    const int c  = blk >> 6;
    const int i0 = (blk & 63) * 4;
    const int tid = threadIdx.x;

    __shared__ float a_sh[48*ASTR];
    __shared__ float feat_sh[4*576];
    __shared__ float opt_sh[4*288];

    for (int t = tid; t < 12288; t += 256) {
        const int j = t & 255, rh = t >> 8;
        const int hh = rh % 12, r = rh / 12;
        a_sh[rh*ASTR + j] = a[(((size_t)c*HNUM + hh)*NRES + (i0+r))*NRES + j];
    }
    __syncthreads();

    if (tid < 240) {
        const int g  = tid / 120;
        const int cq = tid - g*120;
        int hh; const float* vbase; int vstride;
        if (cq < 48) { hh = cq >> 2; vbase = v + (size_t)c*NRES*192 + 4*cq; vstride = 192; }
        else { const int cp = (cq-48)*4; hh = cp/24;
               vbase = v_pts + (size_t)c*NRES*288 + cp; vstride = 288; }

        const int rh0 = (2*g)*12 + hh;
        const int rh1 = rh0 + 12;
        float4 acc0 = {0.f,0.f,0.f,0.f}, acc1 = {0.f,0.f,0.f,0.f};
        for (int j = 0; j < 256; ++j) {
            const float av0 = a_sh[rh0*ASTR + j];
            const float av1 = a_sh[rh1*ASTR + j];
            const float4 vv = *(const float4*)(vbase + (size_t)j*vstride);
            acc0.x = fmaf(av0, vv.x, acc0.x); acc0.y = fmaf(av0, vv.y, acc0.y);
            acc0.z = fmaf(av0, vv.z, acc0.z); acc0.w = fmaf(av0, vv.w, acc0.w);
            acc1.x = fmaf(av1, vv.x, acc1.x); acc1.y = fmaf(av1, vv.y, acc1.y);
            acc1.z = fmaf(av1, vv.z, acc1.z); acc1.w = fmaf(av1, vv.w, acc1.w);
        }
        if (cq < 48) {
            float* d0 = &feat_sh[(2*g)*576 + 4*cq];
            float* d1 = &feat_sh[(2*g+1)*576 + 4*cq];
            d0[0]=acc0.x; d0[1]=acc0.y; d0[2]=acc0.z; d0[3]=acc0.w;
            d1[0]=acc1.x; d1[1]=acc1.y; d1[2]=acc1.z; d1[3]=acc1.w;
        } else {
            const int cp = (cq-48)*4;
            float* d0 = &opt_sh[(2*g)*288 + cp];
            float* d1 = &opt_sh[(2*g+1)*288 + cp];
            d0[0]=acc0.x; d0[1]=acc0.y; d0[2]=acc0.z; d0[3]=acc0.w;
            d1[0]=acc1.x; d1[1]=acc1.y; d1[2]=acc1.z; d1[3]=acc1.w;
        }
    }
    __syncthreads();

    for (int t = tid; t < 384; t += 256) {
        const int r = t / 96, p = t - r*96;
        const int grow = c*NRES + i0 + r;
        const float x = opt_sh[r*288 + p*3+0] - trans[(size_t)grow*3+0];
        const float y = opt_sh[r*288 + p*3+1] - trans[(size_t)grow*3+1];
        const float z = opt_sh[r*288 + p*3+2] - trans[(size_t)grow*3+2];
        const float* R = rot + (size_t)grow*9;
        const float rx = R[0]*x + R[3]*y + R[6]*z;
        const float ry = R[1]*x + R[4]*y + R[7]*z;
        const float rz = R[2]*x + R[5]*y + R[8]*z;
        feat_sh[r*576 + 192 + p] = rx;
        feat_sh[r*576 + 288 + p] = ry;
        feat_sh[r*576 + 384 + p] = rz;
        feat_sh[r*576 + 480 + p] = sqrtf(rx*rx + ry*ry + rz*rz + 1e-8f);
    }
    __syncthreads();

    float* dst = featbuf + (size_t)(c*NRES + i0)*576;
    for (int t = tid; t < 2304; t += 256) dst[t] = feat_sh[t];
}

// ===========================================================================
// Kernel 4b: out0 += feat @ wout, fp32 SPLIT-K (bias via convert kernel).
// ===========================================================================
__global__ __launch_bounds__(256) void out_gemm_kernel(
    const float* __restrict__ featbuf, const float* __restrict__ wout,
    float* __restrict__ out0)
{
    const int blk = blockIdx.x;
    const int rt  = blk / 6;
    const int rem = blk - rt*6;
    const int ct  = rem >> 1;
    const int kh  = rem & 1;
    const int r0  = rt * 16;
    const int k0  = kh * 288;
    const int tid = threadIdx.x;
    const int wave = tid >> 6, lane = tid & 63;

    __shared__ __align__(16) float fsh[16*288];

    for (int t = tid; t < 16*72; t += 256) {
        const int r = t / 72, g = t - r*72;
        *(float4*)&fsh[r*288 + g*4] =
            *(const float4*)&featbuf[(size_t)(r0 + r)*576 + k0 + g*4];
    }

    const int c = ct*128 + lane*2;
    const int C = 384;

    float acc[4][2];
    #pragma unroll
    for (int r = 0; r < 4; ++r) { acc[r][0] = 0.f; acc[r][1] = 0.f; }
    __syncthreads();

    const float* p = wout + (size_t)k0*C + c;
    float2 w0 = *(const float2*)p;
    float2 w1 = *(const float2*)(p + C);
    float2 w2 = *(const float2*)(p + 2*C);
    float2 w3 = *(const float2*)(p + 3*C);
    const float* frow = &fsh[wave*4*288];

    for (int it = 0; it < 71; ++it) {
        const int d = it*4;
        const float* pn = p + 4*C;
        const float2 n0 = *(const float2*)pn;
        const float2 n1 = *(const float2*)(pn + C);
        const float2 n2 = *(const float2*)(pn + 2*C);
        const float2 n3 = *(const float2*)(pn + 3*C);
        #pragma unroll
        for (int r = 0; r < 4; ++r) {
            const float4 sv = *(const float4*)&frow[r*288 + d];
            acc[r][0] = fmaf(sv.x,w0.x,fmaf(sv.y,w1.x,fmaf(sv.z,w2.x,fmaf(sv.w,w3.x,acc[r][0]))));
            acc[r][1] = fmaf(sv.x,w0.y,fmaf(sv.y,w1.y,fmaf(sv.z,w2.y,fmaf(sv.w,w3.y,acc[r][1]))));
        }
        w0 = n0; w1 = n1; w2 = n2; w3 = n3;
        p = pn;
    }
    {
        const int d = 71*4;
        #pragma unroll
        for (int r = 0; r < 4; ++r) {
            const float4 sv = *(const float4*)&frow[r*288 + d];
            acc[r][0] = fmaf(sv.x,w0.x,fmaf(sv.y,w1.x,fmaf(sv.z,w2.x,fmaf(sv.w,w3.x,acc[r][0]))));
            acc[r][1] = fmaf(sv.x,w0.y,fmaf(sv.y,w1.y,fmaf(sv.z,w2.y,fmaf(sv.w,w3.y,acc[r][1]))));
        }
    }

    #pragma unroll
    for (int r = 0; r < 4; ++r) {
        const int grow = r0 + wave*4 + r;
        unsafeAtomicAdd(&out0[(size_t)grow*CS + c],     acc[r][0]);
        unsafeAtomicAdd(&out0[(size_t)grow*CS + c + 1], acc[r][1]);
    }
}

// ===========================================================================
extern "C" void kernel_launch(void* const* d_in, const int* in_sizes, int n_in,
                              void* d_out, int out_size, void* d_ws, size_t ws_size,
                              hipStream_t stream)
{
    const float* s     = (const float*)d_in[0];
    const float* rot   = (const float*)d_in[2];
    const float* trans = (const float*)d_in[3];
    const float* mask  = (const float*)d_in[4];
    const float* wq    = (const float*)d_in[5];
    const float* bq    = (const float*)d_in[6];
    const float* wkv   = (const float*)d_in[7];
    const float* bkv   = (const float*)d_in[8];
    const float* g_gamma = (const float*)d_in[9];
    const float* g_beta  = (const float*)d_in[10];
    const float* wgq   = (const float*)d_in[11];
    const float* bgq   = (const float*)d_in[12];
    const float* wgk   = (const float*)d_in[13];
    const float* bgk   = (const float*)d_in[14];
    const float* wqp   = (const float*)d_in[15];
    const float* bqp   = (const float*)d_in[16];
    const float* wkvp  = (const float*)d_in[17];
    const float* bkvp  = (const float*)d_in[18];
    const float* head_weights = (const float*)d_in[19];
    const float* wdist = (const float*)d_in[20];
    const float* bdist = (const float*)d_in[21];
    const float* wout  = (const float*)d_in[22];
    const float* bout  = (const float*)d_in[23];

    float* ws      = (float*)d_ws;
    float* q_buf   = ws + 0;          // 393216
    float* qp_buf  = ws + 393216;     // 294912
    float* kp_buf  = ws + 688128;     // 294912
    float* gq_buf  = ws + 983040;     // 49152
    float* gk_buf  = ws + 1032192;    // 49152
    float* k_buf   = ws + 1081344;    // 393216
    float* v_buf   = ws + 1474560;    // 393216
    float* vp_buf  = ws + 1867776;    // 589824 (total 2457600)
    float* featbuf = ws + 0;          // overlays buffers dead after attn
    ushort_t* sgn_bf = (ushort_t*)(ws + 1867776); // overlays vp region; dead
                                                  // before pt_transform

    float* out0  = (float*)d_out;       // 786432
    float* a_out = out0 + 786432;       // 6291456
    // overlays inside a_out (all dead before attn writes):
    float*    rawp   = a_out;                              // 1179648 floats
    ushort_t* s_bf   = (ushort_t*)(a_out + 1179648);       // 786432 bf16
    ushort_t* wt_bf  = (ushort_t*)(a_out + 1572864);       // 442368 bf16
    ushort_t* wtg_bf = (ushort_t*)(a_out + 1794048);       // 147456 bf16
    float*    pbias  = a_out + 1867776;                    // 1152
    float*    gbias  = a_out + 1868928;                    // 384

    convert_kernel<<<8454, 256, 0, stream>>>(s, wq, bq, wkv, bkv, wqp, bqp,
                                             wkvp, bkvp, wgq, bgq, wgk, bgk, bout,
                                             s_bf, wt_bf, wtg_bf, pbias, gbias, out0);
    ln_kernel<<<256, 256, 0, stream>>>(s, g_gamma, g_beta, sgn_bf);
    proj_mfma_kernel<<<576, 256, 0, stream>>>(s_bf, wt_bf, pbias,
                                              q_buf, k_buf, v_buf, rawp);
    ggemm_mfma_kernel<<<24, 256, 0, stream>>>(sgn_bf, wtg_bf, gbias,
                                              gq_buf, gk_buf);
    pt_transform_kernel<<<1536, 256, 0, stream>>>(rawp, rot, trans,
                                                  qp_buf, kp_buf, vp_buf);
    attn_mfma_kernel<<<192, 256, 0, stream>>>(q_buf, k_buf, qp_buf, kp_buf,
                                              gq_buf, gk_buf, trans, mask,
                                              head_weights, wdist, bdist, a_out);
    out_feat_kernel<<<512, 256, 0, stream>>>(a_out, v_buf, vp_buf, rot, trans, featbuf);
    out_gemm_kernel<<<768, 256, 0, stream>>>(featbuf, wout, out0);
}

// Round 8
// 219.349 us; speedup vs baseline: 1.5306x; 1.1320x over previous
//
#include <hip/hip_runtime.h>
#include <math.h>

#define NRES 256
#define CDIM 8
#define HNUM 12
#define CS   384

typedef __attribute__((ext_vector_type(8))) short bf16x8;
typedef __attribute__((ext_vector_type(4))) float f32x4;
typedef unsigned short ushort_t;

static __device__ __forceinline__ unsigned short f2bf(float x) {
    unsigned int u = __float_as_uint(x);
    unsigned int r = (u + 0x7fffu + ((u >> 16) & 1u)) >> 16;
    return (unsigned short)r;
}
static __device__ __forceinline__ float bf2f(unsigned short h) {
    return __uint_as_float(((unsigned int)h) << 16);
}

// ===========================================================================
// Kernel 0: conversions + bias packing. (out0 now written directly by
// out_gemm_mfma — no init needed.)  Adds wout -> transposed hi/lo bf16.
// ===========================================================================
__global__ __launch_bounds__(256) void convert_kernel(
    const float* __restrict__ s,
    const float* __restrict__ wq, const float* __restrict__ bq,
    const float* __restrict__ wkv, const float* __restrict__ bkv,
    const float* __restrict__ wqp, const float* __restrict__ bqp,
    const float* __restrict__ wkvp, const float* __restrict__ bkvp,
    const float* __restrict__ wgq, const float* __restrict__ bgq,
    const float* __restrict__ wgk, const float* __restrict__ bgk,
    const float* __restrict__ wout,
    ushort_t* __restrict__ s_bf, ushort_t* __restrict__ wt_bf,
    ushort_t* __restrict__ wtg_bf, float* __restrict__ pbias,
    float* __restrict__ gbias,
    ushort_t* __restrict__ wo_hi, ushort_t* __restrict__ wo_lo)
{
    const int idx = blockIdx.x*256 + threadIdx.x;
    const int NS   = 2048*384;
    const int NWT  = 384*1152;
    const int NWTG = 384*384;
    const int NWO  = 576*384;
    if (idx < NS) {
        s_bf[idx] = f2bf(s[idx]);
    } else if (idx < NS + NWT) {
        const int t = idx - NS;
        const int k = t / 1152, vc = t - k*1152;
        const float* w; int C, lc;
        if (vc < 192)      { w = wq;   C = 192; lc = vc; }
        else if (vc < 576) { w = wkv;  C = 384; lc = vc - 192; }
        else if (vc < 720) { w = wqp;  C = 144; lc = vc - 576; }
        else               { w = wkvp; C = 432; lc = vc - 720; }
        wt_bf[(size_t)vc*384 + k] = f2bf(w[(size_t)k*C + lc]);
    } else if (idx < NS + NWT + NWTG) {
        const int t = idx - NS - NWT;
        const int k = t / 384, vc = t - k*384;
        const float val = (vc < 192) ? wgq[(size_t)k*192 + vc]
                                     : wgk[(size_t)k*192 + vc - 192];
        wtg_bf[(size_t)vc*384 + k] = f2bf(val);
    } else if (idx < NS + NWT + NWTG + 1152) {
        const int i = idx - NS - NWT - NWTG;
        float b;
        if (i < 192)      b = bq[i];
        else if (i < 576) b = bkv[i - 192];
        else if (i < 720) b = bqp[i - 576];
        else              b = bkvp[i - 720];
        pbias[i] = b;
    } else if (idx < NS + NWT + NWTG + 1152 + 384) {
        const int i = idx - NS - NWT - NWTG - 1152;
        gbias[i] = (i < 192) ? bgq[i] : bgk[i - 192];
    } else if (idx < NS + NWT + NWTG + 1536 + NWO) {
        const int t = idx - NS - NWT - NWTG - 1536;
        const int k = t / 384, n = t - k*384;
        const float wv = wout[t];
        const ushort_t hi = f2bf(wv);
        wo_hi[(size_t)n*576 + k] = hi;
        wo_lo[(size_t)n*576 + k] = f2bf(wv - bf2f(hi));
    }
}

// ===========================================================================
// Kernel 1: unified projection GEMM via MFMA bf16.
// ===========================================================================
__global__ __launch_bounds__(256) void proj_mfma_kernel(
    const ushort_t* __restrict__ s_bf, const ushort_t* __restrict__ wt_bf,
    const float* __restrict__ pbias,
    float* __restrict__ qo, float* __restrict__ ko, float* __restrict__ vo,
    float* __restrict__ rawp)
{
    const int blk = blockIdx.x;
    const int rt = blk / 18, ct = blk - rt*18;
    const int r0 = rt * 64, c0 = ct * 64;
    const int tid = threadIdx.x;
    const int wave = tid >> 6, lane = tid & 63;
    const int wrow = wave >> 1, wcol = wave & 1;
    const int m0 = r0 + wrow*32, n0 = c0 + wcol*32;
    const int qd = lane >> 4, lr = lane & 15;

    f32x4 acc00 = {0,0,0,0}, acc01 = {0,0,0,0}, acc10 = {0,0,0,0}, acc11 = {0,0,0,0};

    const ushort_t* a0p = s_bf  + (size_t)(m0 + lr)*384 + qd*8;
    const ushort_t* a1p = a0p + 16*384;
    const ushort_t* b0p = wt_bf + (size_t)(n0 + lr)*384 + qd*8;
    const ushort_t* b1p = b0p + 16*384;

    #pragma unroll
    for (int kk = 0; kk < 384; kk += 32) {
        const bf16x8 a0 = *(const bf16x8*)(a0p + kk);
        const bf16x8 a1 = *(const bf16x8*)(a1p + kk);
        const bf16x8 b0 = *(const bf16x8*)(b0p + kk);
        const bf16x8 b1 = *(const bf16x8*)(b1p + kk);
        acc00 = __builtin_amdgcn_mfma_f32_16x16x32_bf16(a0, b0, acc00, 0, 0, 0);
        acc01 = __builtin_amdgcn_mfma_f32_16x16x32_bf16(a0, b1, acc01, 0, 0, 0);
        acc10 = __builtin_amdgcn_mfma_f32_16x16x32_bf16(a1, b0, acc10, 0, 0, 0);
        acc11 = __builtin_amdgcn_mfma_f32_16x16x32_bf16(a1, b1, acc11, 0, 0, 0);
    }

    #pragma unroll
    for (int mt = 0; mt < 2; ++mt) {
        #pragma unroll
        for (int nt = 0; nt < 2; ++nt) {
            const f32x4 av = (mt==0) ? (nt==0 ? acc00 : acc01)
                                     : (nt==0 ? acc10 : acc11);
            const int col = n0 + nt*16 + lr;
            const float bb = pbias[col];
            #pragma unroll
            for (int reg = 0; reg < 4; ++reg) {
                const int row = m0 + mt*16 + qd*4 + reg;
                const float val = av[reg] + bb;
                if (col < 192) {
                    qo[(size_t)row*192 + col] = val;
                } else if (col < 576) {
                    const int lc = col - 192, h = lc >> 5, rm = lc & 31;
                    if (rm < 16) ko[(size_t)row*192 + h*16 + rm] = val;
                    else         vo[(size_t)row*192 + h*16 + rm - 16] = val;
                } else {
                    rawp[(size_t)row*576 + col - 576] = val;
                }
            }
        }
    }
}

// ===========================================================================
// Kernel 1b: rigid transform of raw points -> q_pts / k_pts / v_pts
// ===========================================================================
__global__ __launch_bounds__(256) void pt_transform_kernel(
    const float* __restrict__ rawp, const float* __restrict__ rot,
    const float* __restrict__ trans,
    float* __restrict__ qpo, float* __restrict__ kpo, float* __restrict__ vpo)
{
    const int t = blockIdx.x*256 + threadIdx.x;
    const int row = t / 192;
    const int p = t - row*192;
    const float* R = rot + (size_t)row*9;
    const float* T = trans + (size_t)row*3;
    const float* base = rawp + (size_t)row*576;
    float x, y, z;
    if (p < 48) { x = base[p];       y = base[48+p];  z = base[96+p]; }
    else { const int pk = p-48; x = base[144+pk]; y = base[288+pk]; z = base[432+pk]; }
    const float px = R[0]*x + R[1]*y + R[2]*z + T[0];
    const float py = R[3]*x + R[4]*y + R[5]*z + T[1];
    const float pz = R[6]*x + R[7]*y + R[8]*z + T[2];
    if (p < 48) {
        float* o = qpo + (size_t)row*144 + p*3;
        o[0]=px; o[1]=py; o[2]=pz;
    } else {
        const int pk = p-48, h = pk/12, pp = pk - h*12;
        if (pp < 4) { float* o = kpo + (size_t)row*144 + (h*4+pp)*3;     o[0]=px; o[1]=py; o[2]=pz; }
        else        { float* o = vpo + (size_t)row*288 + (h*8+(pp-4))*3; o[0]=px; o[1]=py; o[2]=pz; }
    }
}

// ===========================================================================
// Kernel 2a: s_g = mean over C + LayerNorm -> sgn_bf (bf16)
// ===========================================================================
__global__ __launch_bounds__(256) void ln_kernel(
    const float* __restrict__ s, const float* __restrict__ g_gamma,
    const float* __restrict__ g_beta, ushort_t* __restrict__ sgn_bf)
{
    const int n = blockIdx.x;
    const int tid = threadIdx.x;
    __shared__ float sg[CS];
    __shared__ float red[256];

    for (int d = tid; d < CS; d += 256) {
        float acc = 0.f;
        for (int c = 0; c < CDIM; ++c) acc += s[((size_t)c*NRES+n)*CS + d];
        sg[d] = acc * (1.0f/CDIM);
    }
    __syncthreads();

    float lsum = 0.f;
    for (int d = tid; d < CS; d += 256) lsum += sg[d];
    red[tid] = lsum; __syncthreads();
    for (int st = 128; st > 0; st >>= 1) { if (tid < st) red[tid] += red[tid+st]; __syncthreads(); }
    const float mean = red[0] * (1.0f/CS);
    __syncthreads();

    float lvar = 0.f;
    for (int d = tid; d < CS; d += 256) { float df = sg[d]-mean; lvar += df*df; }
    red[tid] = lvar; __syncthreads();
    for (int st = 128; st > 0; st >>= 1) { if (tid < st) red[tid] += red[tid+st]; __syncthreads(); }
    const float var = red[0] * (1.0f/CS);
    __syncthreads();

    const float inv = rsqrtf(var + 1e-5f);
    for (int d = tid; d < CS; d += 256)
        sgn_bf[(size_t)n*CS + d] = f2bf((sg[d]-mean)*inv*g_gamma[d] + g_beta[d]);
}

// ===========================================================================
// Kernel 2b: g_q|g_k = sgn @ [wgq|wgk] via MFMA bf16.
// ===========================================================================
__global__ __launch_bounds__(256) void ggemm_mfma_kernel(
    const ushort_t* __restrict__ sgn_bf, const ushort_t* __restrict__ wtg_bf,
    const float* __restrict__ gbias,
    float* __restrict__ gqo, float* __restrict__ gko)
{
    const int blk = blockIdx.x;
    const int rt = blk / 6, ct = blk - rt*6;
    const int r0 = rt * 64, c0 = ct * 64;
    const int tid = threadIdx.x;
    const int wave = tid >> 6, lane = tid & 63;
    const int wrow = wave >> 1, wcol = wave & 1;
    const int m0 = r0 + wrow*32, n0 = c0 + wcol*32;
    const int qd = lane >> 4, lr = lane & 15;

    f32x4 acc00 = {0,0,0,0}, acc01 = {0,0,0,0}, acc10 = {0,0,0,0}, acc11 = {0,0,0,0};

    const ushort_t* a0p = sgn_bf + (size_t)(m0 + lr)*384 + qd*8;
    const ushort_t* a1p = a0p + 16*384;
    const ushort_t* b0p = wtg_bf + (size_t)(n0 + lr)*384 + qd*8;
    const ushort_t* b1p = b0p + 16*384;

    #pragma unroll
    for (int kk = 0; kk < 384; kk += 32) {
        const bf16x8 a0 = *(const bf16x8*)(a0p + kk);
        const bf16x8 a1 = *(const bf16x8*)(a1p + kk);
        const bf16x8 b0 = *(const bf16x8*)(b0p + kk);
        const bf16x8 b1 = *(const bf16x8*)(b1p + kk);
        acc00 = __builtin_amdgcn_mfma_f32_16x16x32_bf16(a0, b0, acc00, 0, 0, 0);
        acc01 = __builtin_amdgcn_mfma_f32_16x16x32_bf16(a0, b1, acc01, 0, 0, 0);
        acc10 = __builtin_amdgcn_mfma_f32_16x16x32_bf16(a1, b0, acc10, 0, 0, 0);
        acc11 = __builtin_amdgcn_mfma_f32_16x16x32_bf16(a1, b1, acc11, 0, 0, 0);
    }

    #pragma unroll
    for (int mt = 0; mt < 2; ++mt) {
        #pragma unroll
        for (int nt = 0; nt < 2; ++nt) {
            const f32x4 av = (mt==0) ? (nt==0 ? acc00 : acc01)
                                     : (nt==0 ? acc10 : acc11);
            const int col = n0 + nt*16 + lr;
            const float bb = gbias[col];
            #pragma unroll
            for (int reg = 0; reg < 4; ++reg) {
                const int row = m0 + mt*16 + qd*4 + reg;
                const float val = av[reg] + bb;
                if (col < 192) gqo[(size_t)row*192 + col]       = val;
                else           gko[(size_t)row*192 + col - 192] = val;
            }
        }
    }
}

// ===========================================================================
// Kernel 3: attention via MFMA (unchanged from round 7).
// ===========================================================================
__global__ __launch_bounds__(256) void attn_mfma_kernel(
    const float* __restrict__ q, const float* __restrict__ k,
    const float* __restrict__ q_pts, const float* __restrict__ k_pts,
    const float* __restrict__ g_q, const float* __restrict__ g_k,
    const float* __restrict__ trans, const float* __restrict__ mask,
    const float* __restrict__ head_weights, const float* __restrict__ wdist,
    const float* __restrict__ bdist, float* __restrict__ a_out)
{
    const int blk  = blockIdx.x;
    const int half = blk & 1;
    const int ch   = blk >> 1;
    const int h    = ch % HNUM;
    const int c    = ch / HNUM;
    const int i0   = half * 128;
    const int tid  = threadIdx.x;

    __shared__ ushort_t Bsh[256*96];
    __shared__ ushort_t Ash[128*96];
    __shared__ float dsh[12*256];
    __shared__ float tsh[768];
    __shared__ float msh[256];
    __shared__ float kn_sh[256];
    __shared__ float qn_sh[128];
    __shared__ float wdsh[12], bdsh[12];
    __shared__ float cpart[96];
    __shared__ float censh[3];

    for (int t = tid; t < 768; t += 256) tsh[t] = trans[(size_t)c*768 + t];
    msh[tid] = mask[c*NRES + tid];
    if (tid < 12) { wdsh[tid] = wdist[tid]; bdsh[tid] = bdist[tid]; }
    __syncthreads();

    if (tid < 96) {
        const int coord = tid % 3, chunk = tid / 3;
        float sv = 0.f;
        for (int e = 0; e < 8; ++e) sv += tsh[(chunk*8+e)*3 + coord];
        cpart[tid] = sv;
    }
    __syncthreads();
    if (tid < 3) {
        float sv = 0.f;
        for (int e = 0; e < 32; ++e) sv += cpart[e*3 + tid];
        censh[tid] = sv * (1.0f/256.0f);
    }
    __syncthreads();

    const float s54   = 0.13608276348795434f;
    const float scale = 0.14433756729740643f;
    const float hwv = 0.5f * logf(1.0f + expf(head_weights[h])) * s54;
    const float sh  = sqrtf(2.0f * hwv);
    const float cx = censh[0], cy = censh[1], cz = censh[2];

    {
        const int j = tid;
        const float* kr  = k    + ((size_t)c*NRES + j)*192 + h*16;
        const float* gkr = g_k  + (size_t)j*192 + h*16;
        const float* kpr = k_pts+ ((size_t)c*NRES + j)*144 + h*12;
        ushort_t* br = &Bsh[j*96];
        #pragma unroll
        for (int e = 0; e < 16; ++e) br[e]    = f2bf(kr[e]);
        #pragma unroll
        for (int e = 0; e < 16; ++e) br[16+e] = f2bf(gkr[e]);
        float kn = 0.f;
        #pragma unroll
        for (int e = 0; e < 12; ++e) {
            const float cen = (e%3==0) ? cx : ((e%3==1) ? cy : cz);
            const float kp = kpr[e] - cen;
            kn += kp*kp;
            const float sp = sh * kp;
            const ushort_t hi = f2bf(sp);
            br[32+e] = hi;
            br[44+e] = f2bf(sp - bf2f(hi));
            br[56+e] = hi;
        }
        #pragma unroll
        for (int e = 68; e < 96; ++e) br[e] = 0;
        kn_sh[j] = hwv * kn;
    }

    if (tid < 128) {
        const int il = i0 + tid;
        const float* qr  = q    + ((size_t)c*NRES + il)*192 + h*16;
        const float* gqr = g_q  + (size_t)il*192 + h*16;
        const float* qpr = q_pts+ ((size_t)c*NRES + il)*144 + h*12;
        ushort_t* ar = &Ash[tid*96];
        #pragma unroll
        for (int e = 0; e < 16; ++e) ar[e]    = f2bf(scale*qr[e]);
        #pragma unroll
        for (int e = 0; e < 16; ++e) ar[16+e] = f2bf(scale*gqr[e]);
        float qn = 0.f;
        #pragma unroll
        for (int e = 0; e < 12; ++e) {
            const float cen = (e%3==0) ? cx : ((e%3==1) ? cy : cz);
            const float qp = qpr[e] - cen;
            qn += qp*qp;
            const float sp = sh * qp;
            const ushort_t hi = f2bf(sp);
            ar[32+e] = hi;
            ar[44+e] = hi;
            ar[56+e] = f2bf(sp - bf2f(hi));
        }
        #pragma unroll
        for (int e = 68; e < 96; ++e) ar[e] = 0;
        qn_sh[tid] = hwv * qn;
    }

    const int Fmin = h*65536 + i0*256;
    const int iibase = Fmin / 3072;
    const int NI = (Fmin + 127*256 + 255)/3072 - iibase + 1;
    for (int idx = tid; idx < NI*256; idx += 256) {
        const int e = idx >> 8, jj = idx & 255;
        const int ia = iibase + e;
        const float dx = tsh[ia*3+0] - tsh[jj*3+0];
        const float dy = tsh[ia*3+1] - tsh[jj*3+1];
        const float dz = tsh[ia*3+2] - tsh[jj*3+2];
        dsh[idx] = sqrtf(dx*dx + dy*dy + dz*dz);
    }
    __syncthreads();

    const int wave = tid >> 6, lane = tid & 63;
    const int qd = lane >> 4, lr = lane & 15;

    for (int g = 0; g < 2; ++g) {
        const int m0 = wave*32 + g*16;
        const ushort_t* ap = &Ash[(m0 + lr)*96 + qd*8];
        const bf16x8 af0 = *(const bf16x8*)(ap);
        const bf16x8 af1 = *(const bf16x8*)(ap + 32);
        const bf16x8 af2 = *(const bf16x8*)(ap + 64);

        f32x4 acc[16];
        #pragma unroll
        for (int t = 0; t < 16; ++t) {
            const ushort_t* bp = &Bsh[(t*16 + lr)*96 + qd*8];
            f32x4 a = {0.f,0.f,0.f,0.f};
            a = __builtin_amdgcn_mfma_f32_16x16x32_bf16(af0, *(const bf16x8*)(bp),      a, 0, 0, 0);
            a = __builtin_amdgcn_mfma_f32_16x16x32_bf16(af1, *(const bf16x8*)(bp + 32), a, 0, 0, 0);
            a = __builtin_amdgcn_mfma_f32_16x16x32_bf16(af2, *(const bf16x8*)(bp + 64), a, 0, 0, 0);
            acc[t] = a;
        }

        const int ibase = m0 + qd*4;
        float qn_r[4], mb_r[4];
        int F0_[4];
        #pragma unroll
        for (int r = 0; r < 4; ++r) {
            const int il = i0 + ibase + r;
            qn_r[r] = qn_sh[ibase + r];
            mb_r[r] = 100000.0f * msh[il];
            F0_[r]  = h*65536 + il*256;
        }

        float mx[4] = {-1e30f,-1e30f,-1e30f,-1e30f};
        #pragma unroll
        for (int t = 0; t < 16; ++t) {
            const int j = t*16 + lr;
            const float knj = kn_sh[j];
            const float mj  = msh[j];
            #pragma unroll
            for (int r = 0; r < 4; ++r) {
                const unsigned int f = (unsigned int)(F0_[r] + j);
                const unsigned int p = f / 12u;
                const int ho = (int)(f - p*12u);
                const int ii = (int)(p >> 8);
                const int jj = (int)(p & 255u);
                const float dist = dsh[(ii - iibase)*256 + jj];
                const float db = dist*wdsh[ho] + bdsh[ho];
                const float lv = acc[t][r] - qn_r[r] - knj
                               + (mb_r[r]*mj - 100000.0f) + db;
                acc[t][r] = lv;
                mx[r] = fmaxf(mx[r], lv);
            }
        }
        #pragma unroll
        for (int r = 0; r < 4; ++r) {
            #pragma unroll
            for (int off = 1; off < 16; off <<= 1)
                mx[r] = fmaxf(mx[r], __shfl_xor(mx[r], off));
        }
        float sm[4] = {0.f,0.f,0.f,0.f};
        #pragma unroll
        for (int t = 0; t < 16; ++t) {
            #pragma unroll
            for (int r = 0; r < 4; ++r) {
                const float e = __expf(acc[t][r] - mx[r]);
                acc[t][r] = e;
                sm[r] += e;
            }
        }
        #pragma unroll
        for (int r = 0; r < 4; ++r) {
            #pragma unroll
            for (int off = 1; off < 16; off <<= 1)
                sm[r] += __shfl_xor(sm[r], off);
            sm[r] = 1.0f / sm[r];
        }
        float* dst = a_out + ((size_t)ch*NRES + (i0 + ibase))*NRES;
        #pragma unroll
        for (int t = 0; t < 16; ++t) {
            #pragma unroll
            for (int r = 0; r < 4; ++r)
                dst[(size_t)r*NRES + t*16 + lr] = acc[t][r]*sm[r];
        }
    }
}

// ===========================================================================
// Kernel 4a: o / o_pt via MFMA. Block = (c, h, i-quarter of 64) -> 384 blocks.
// B(LDS) = [v(16) | vp'_hi(24) | vp'_lo(24)] bf16, vp' = v_pts - centroid.
// A = a rows as hi+lo bf16 (both accumulated into same fp32 acc).
// Epilogue: exact fp32 inverse-rigid + norms; emits feat as hi/lo bf16.
// feat layout per row: [o(192) | x(96) | y(96) | z(96) | norm(96)].
// ===========================================================================
#define ASTRB 264
__global__ __launch_bounds__(256) void out_feat_mfma_kernel(
    const float* __restrict__ a, const float* __restrict__ v,
    const float* __restrict__ v_pts, const float* __restrict__ rot,
    const float* __restrict__ trans,
    ushort_t* __restrict__ feat_hi, ushort_t* __restrict__ feat_lo)
{
    const int blk = blockIdx.x;
    const int qtr = blk & 3;
    const int ch  = blk >> 2;
    const int h   = ch % HNUM;
    const int c   = ch / HNUM;
    const int i0  = qtr * 64;
    const int tid = threadIdx.x;

    __shared__ ushort_t Bt[64*ASTRB];   // 33 KB  [col][k=j]
    __shared__ float opt[64*25];        // 6.25 KB o_pt accum (fp32)
    __shared__ float osh[64*17];        // 4.25 KB o accum
    __shared__ float cpart[96];
    __shared__ float censh[3];

    // centroid of trans chain c
    if (tid < 96) {
        const int coord = tid % 3, chunk = tid / 3;
        float sv = 0.f;
        for (int e = 0; e < 8; ++e)
            sv += trans[((size_t)c*NRES + chunk*8 + e)*3 + coord];
        cpart[tid] = sv;
    }
    __syncthreads();
    if (tid < 3) {
        float sv = 0.f;
        for (int e = 0; e < 32; ++e) sv += cpart[e*3 + tid];
        censh[tid] = sv * (1.0f/256.0f);
    }
    __syncthreads();
    const float cx = censh[0], cy = censh[1], cz = censh[2];
    const float cen3[3] = {cx, cy, cz};

    // stage B: thread j builds column j of all 64 rows
    {
        const int j = tid;
        const float4* vr = (const float4*)(v + ((size_t)c*NRES + j)*192 + h*16);
        #pragma unroll
        for (int e4 = 0; e4 < 4; ++e4) {
            const float4 w = vr[e4];
            Bt[(e4*4+0)*ASTRB + j] = f2bf(w.x);
            Bt[(e4*4+1)*ASTRB + j] = f2bf(w.y);
            Bt[(e4*4+2)*ASTRB + j] = f2bf(w.z);
            Bt[(e4*4+3)*ASTRB + j] = f2bf(w.w);
        }
        const float4* vpr = (const float4*)(v_pts + ((size_t)c*NRES + j)*288 + h*24);
        #pragma unroll
        for (int e4 = 0; e4 < 6; ++e4) {
            const float4 w = vpr[e4];
            const float vals[4] = {w.x, w.y, w.z, w.w};
            #pragma unroll
            for (int cc = 0; cc < 4; ++cc) {
                const int e = e4*4 + cc;
                const float vp = vals[cc] - cen3[e % 3];
                const ushort_t hi = f2bf(vp);
                Bt[(16+e)*ASTRB + j] = hi;
                Bt[(40+e)*ASTRB + j] = f2bf(vp - bf2f(hi));
            }
        }
    }
    __syncthreads();

    const int wave = tid >> 6, lane = tid & 63;
    const int qd = lane >> 4, lr = lane & 15;
    const int m0 = wave*16;                     // local row base (block M=64)

    const float* arow = a + ((size_t)ch*NRES + i0 + m0 + lr)*NRES;

    f32x4 acc[4] = {{0,0,0,0},{0,0,0,0},{0,0,0,0},{0,0,0,0}};
    #pragma unroll
    for (int kk = 0; kk < 256; kk += 32) {
        const float4 a0 = *(const float4*)(arow + qd*8 + kk);
        const float4 a1 = *(const float4*)(arow + qd*8 + kk + 4);
        const float av[8] = {a0.x,a0.y,a0.z,a0.w,a1.x,a1.y,a1.z,a1.w};
        bf16x8 ahi, alo;
        #pragma unroll
        for (int e = 0; e < 8; ++e) {
            const ushort_t hi = f2bf(av[e]);
            ((ushort_t*)&ahi)[e] = hi;
            ((ushort_t*)&alo)[e] = f2bf(av[e] - bf2f(hi));
        }
        #pragma unroll
        for (int t = 0; t < 4; ++t) {
            const bf16x8 bf = *(const bf16x8*)&Bt[(t*16 + lr)*ASTRB + qd*8 + kk];
            acc[t] = __builtin_amdgcn_mfma_f32_16x16x32_bf16(ahi, bf, acc[t], 0, 0, 0);
            acc[t] = __builtin_amdgcn_mfma_f32_16x16x32_bf16(alo, bf, acc[t], 0, 0, 0);
        }
    }

    // scatter accumulators to LDS (within-wave ordering keeps += safe)
    #pragma unroll
    for (int reg = 0; reg < 4; ++reg) {
        const int row_l = m0 + qd*4 + reg;
        osh[row_l*17 + lr] = acc[0][reg];                 // o cols 0..15
        opt[row_l*25 + lr] = acc[1][reg];                 // vphi p=0..15
    }
    #pragma unroll
    for (int reg = 0; reg < 4; ++reg) {
        const int row_l = m0 + qd*4 + reg;
        if (lr < 8) opt[row_l*25 + 16 + lr] = acc[2][reg];        // vphi p=16..23
        else        opt[row_l*25 + (lr-8)] += acc[2][reg];        // vplo p=0..7
    }
    #pragma unroll
    for (int reg = 0; reg < 4; ++reg) {
        const int row_l = m0 + qd*4 + reg;
        opt[row_l*25 + 8 + lr] += acc[3][reg];                    // vplo p=8..23
    }
    __syncthreads();

    // epilogue: o slices
    #pragma unroll
    for (int it = 0; it < 4; ++it) {
        const int idx = it*256 + tid;        // 64 rows x 16 cols
        const int row_l = idx >> 4, e = idx & 15;
        const int grow = c*NRES + i0 + row_l;
        const float val = osh[row_l*17 + e];
        const ushort_t hi = f2bf(val);
        feat_hi[(size_t)grow*576 + h*16 + e] = hi;
        feat_lo[(size_t)grow*576 + h*16 + e] = f2bf(val - bf2f(hi));
    }
    // epilogue: points (64 rows x 8 pts)
    #pragma unroll
    for (int it = 0; it < 2; ++it) {
        const int idx = it*256 + tid;
        const int row_l = idx >> 3, p = idx & 7;
        const int grow = c*NRES + i0 + row_l;
        const float* R = rot + (size_t)grow*9;
        const float* T = trans + (size_t)grow*3;
        const float x = opt[row_l*25 + p*3+0] + cx - T[0];
        const float y = opt[row_l*25 + p*3+1] + cy - T[1];
        const float z = opt[row_l*25 + p*3+2] + cz - T[2];
        const float rx = R[0]*x + R[3]*y + R[6]*z;
        const float ry = R[1]*x + R[4]*y + R[7]*z;
        const float rz = R[2]*x + R[5]*y + R[8]*z;
        const float nm = sqrtf(rx*rx + ry*ry + rz*rz + 1e-8f);
        const float vals[4] = {rx, ry, rz, nm};
        #pragma unroll
        for (int sl = 0; sl < 4; ++sl) {
            const int col = 192 + sl*96 + h*8 + p;
            const ushort_t hi = f2bf(vals[sl]);
            feat_hi[(size_t)grow*576 + col] = hi;
            feat_lo[(size_t)grow*576 + col] = f2bf(vals[sl] - bf2f(hi));
        }
    }
}

// ===========================================================================
// Kernel 4b: out0 = feat @ wout + bout via MFMA (3-term hi/lo product).
// 2048x576 @ 576x384. Block 64x64, grid 32x6 = 192. Direct stores, no atomics.
// ===========================================================================
__global__ __launch_bounds__(256) void out_gemm_mfma_kernel(
    const ushort_t* __restrict__ feat_hi, const ushort_t* __restrict__ feat_lo,
    const ushort_t* __restrict__ wo_hi, const ushort_t* __restrict__ wo_lo,
    const float* __restrict__ bout, float* __restrict__ out0)
{
    const int blk = blockIdx.x;
    const int rt = blk / 6, ct = blk - rt*6;
    const int r0 = rt * 64, c0 = ct * 64;
    const int tid = threadIdx.x;
    const int wave = tid >> 6, lane = tid & 63;
    const int wrow = wave >> 1, wcol = wave & 1;
    const int m0 = r0 + wrow*32, n0 = c0 + wcol*32;
    const int qd = lane >> 4, lr = lane & 15;

    f32x4 acc[2][2] = {{{0,0,0,0},{0,0,0,0}},{{0,0,0,0},{0,0,0,0}}};

    const ushort_t* ah0 = feat_hi + (size_t)(m0 + lr)*576 + qd*8;
    const ushort_t* ah1 = ah0 + 16*576;
    const ushort_t* al0 = feat_lo + (size_t)(m0 + lr)*576 + qd*8;
    const ushort_t* al1 = al0 + 16*576;
    const ushort_t* bh0 = wo_hi + (size_t)(n0 + lr)*576 + qd*8;
    const ushort_t* bh1 = bh0 + 16*576;
    const ushort_t* bl0 = wo_lo + (size_t)(n0 + lr)*576 + qd*8;
    const ushort_t* bl1 = bl0 + 16*576;

    for (int kk = 0; kk < 576; kk += 32) {
        const bf16x8 fh0 = *(const bf16x8*)(ah0 + kk);
        const bf16x8 fh1 = *(const bf16x8*)(ah1 + kk);
        const bf16x8 fl0 = *(const bf16x8*)(al0 + kk);
        const bf16x8 fl1 = *(const bf16x8*)(al1 + kk);
        const bf16x8 wh0 = *(const bf16x8*)(bh0 + kk);
        const bf16x8 wh1 = *(const bf16x8*)(bh1 + kk);
        const bf16x8 wl0 = *(const bf16x8*)(bl0 + kk);
        const bf16x8 wl1 = *(const bf16x8*)(bl1 + kk);
        acc[0][0] = __builtin_amdgcn_mfma_f32_16x16x32_bf16(fh0, wh0, acc[0][0], 0, 0, 0);
        acc[0][1] = __builtin_amdgcn_mfma_f32_16x16x32_bf16(fh0, wh1, acc[0][1], 0, 0, 0);
        acc[1][0] = __builtin_amdgcn_mfma_f32_16x16x32_bf16(fh1, wh0, acc[1][0], 0, 0, 0);
        acc[1][1] = __builtin_amdgcn_mfma_f32_16x16x32_bf16(fh1, wh1, acc[1][1], 0, 0, 0);
        acc[0][0] = __builtin_amdgcn_mfma_f32_16x16x32_bf16(fl0, wh0, acc[0][0], 0, 0, 0);
        acc[0][1] = __builtin_amdgcn_mfma_f32_16x16x32_bf16(fl0, wh1, acc[0][1], 0, 0, 0);
        acc[1][0] = __builtin_amdgcn_mfma_f32_16x16x32_bf16(fl1, wh0, acc[1][0], 0, 0, 0);
        acc[1][1] = __builtin_amdgcn_mfma_f32_16x16x32_bf16(fl1, wh1, acc[1][1], 0, 0, 0);
        acc[0][0] = __builtin_amdgcn_mfma_f32_16x16x32_bf16(fh0, wl0, acc[0][0], 0, 0, 0);
        acc[0][1] = __builtin_amdgcn_mfma_f32_16x16x32_bf16(fh0, wl1, acc[0][1], 0, 0, 0);
        acc[1][0] = __builtin_amdgcn_mfma_f32_16x16x32_bf16(fh1, wl0, acc[1][0], 0, 0, 0);
        acc[1][1] = __builtin_amdgcn_mfma_f32_16x16x32_bf16(fh1, wl1, acc[1][1], 0, 0, 0);
    }

    #pragma unroll
    for (int mt = 0; mt < 2; ++mt) {
        #pragma unroll
        for (int nt = 0; nt < 2; ++nt) {
            const int col = n0 + nt*16 + lr;
            const float bb = bout[col];
            #pragma unroll
            for (int reg = 0; reg < 4; ++reg) {
                const int row = m0 + mt*16 + qd*4 + reg;
                out0[(size_t)row*CS + col] = acc[mt][nt][reg] + bb;
            }
        }
    }
}

// ===========================================================================
extern "C" void kernel_launch(void* const* d_in, const int* in_sizes, int n_in,
                              void* d_out, int out_size, void* d_ws, size_t ws_size,
                              hipStream_t stream)
{
    const float* s     = (const float*)d_in[0];
    const float* rot   = (const float*)d_in[2];
    const float* trans = (const float*)d_in[3];
    const float* mask  = (const float*)d_in[4];
    const float* wq    = (const float*)d_in[5];
    const float* bq    = (const float*)d_in[6];
    const float* wkv   = (const float*)d_in[7];
    const float* bkv   = (const float*)d_in[8];
    const float* g_gamma = (const float*)d_in[9];
    const float* g_beta  = (const float*)d_in[10];
    const float* wgq   = (const float*)d_in[11];
    const float* bgq   = (const float*)d_in[12];
    const float* wgk   = (const float*)d_in[13];
    const float* bgk   = (const float*)d_in[14];
    const float* wqp   = (const float*)d_in[15];
    const float* bqp   = (const float*)d_in[16];
    const float* wkvp  = (const float*)d_in[17];
    const float* bkvp  = (const float*)d_in[18];
    const float* head_weights = (const float*)d_in[19];
    const float* wdist = (const float*)d_in[20];
    const float* bdist = (const float*)d_in[21];
    const float* wout  = (const float*)d_in[22];
    const float* bout  = (const float*)d_in[23];

    float* ws      = (float*)d_ws;
    float* q_buf   = ws + 0;          // 393216
    float* qp_buf  = ws + 393216;     // 294912
    float* kp_buf  = ws + 688128;     // 294912
    float* gq_buf  = ws + 983040;     // 49152
    float* gk_buf  = ws + 1032192;    // 49152
    float* k_buf   = ws + 1081344;    // 393216
    float* v_buf   = ws + 1474560;    // 393216
    float* vp_buf  = ws + 1867776;    // 589824 (-> 2457600)
    ushort_t* sgn_bf  = (ushort_t*)(ws + 1867776); // overlays vp; dead before pt
    ushort_t* feat_hi = (ushort_t*)(ws + 2457600); // 1179648 bf16 (589824 f)
    ushort_t* feat_lo = (ushort_t*)(ws + 3047424); // 1179648 bf16
    ushort_t* wo_hi   = (ushort_t*)(ws + 3637248); // 221184 bf16 (110592 f)
    ushort_t* wo_lo   = (ushort_t*)(ws + 3747840); // 221184 bf16

    float* out0  = (float*)d_out;       // 786432
    float* a_out = out0 + 786432;       // 6291456
    // overlays inside a_out (dead before attn writes):
    float*    rawp   = a_out;                              // 1179648 floats
    ushort_t* s_bf   = (ushort_t*)(a_out + 1179648);       // 786432 bf16
    ushort_t* wt_bf  = (ushort_t*)(a_out + 1572864);       // 442368 bf16
    ushort_t* wtg_bf = (ushort_t*)(a_out + 1794048);       // 147456 bf16
    float*    pbias  = a_out + 1867776;                    // 1152
    float*    gbias  = a_out + 1868928;                    // 384

    convert_kernel<<<6246, 256, 0, stream>>>(s, wq, bq, wkv, bkv, wqp, bqp,
                                             wkvp, bkvp, wgq, bgq, wgk, bgk, wout,
                                             s_bf, wt_bf, wtg_bf, pbias, gbias,
                                             wo_hi, wo_lo);
    ln_kernel<<<256, 256, 0, stream>>>(s, g_gamma, g_beta, sgn_bf);
    proj_mfma_kernel<<<576, 256, 0, stream>>>(s_bf, wt_bf, pbias,
                                              q_buf, k_buf, v_buf, rawp);
    ggemm_mfma_kernel<<<24, 256, 0, stream>>>(sgn_bf, wtg_bf, gbias,
                                              gq_buf, gk_buf);
    pt_transform_kernel<<<1536, 256, 0, stream>>>(rawp, rot, trans,
                                                  qp_buf, kp_buf, vp_buf);
    attn_mfma_kernel<<<192, 256, 0, stream>>>(q_buf, k_buf, qp_buf, kp_buf,
                                              gq_buf, gk_buf, trans, mask,
                                              head_weights, wdist, bdist, a_out);
    out_feat_mfma_kernel<<<384, 256, 0, stream>>>(a_out, v_buf, vp_buf, rot, trans,
                                                  feat_hi, feat_lo);
    out_gemm_mfma_kernel<<<192, 256, 0, stream>>>(feat_hi, feat_lo, wo_hi, wo_lo,
                                                  bout, out0);
}

// Round 9
// 211.879 us; speedup vs baseline: 1.5846x; 1.0353x over previous
//
#include <hip/hip_runtime.h>
#include <math.h>

#define NRES 256
#define CDIM 8
#define HNUM 12
#define CS   384

typedef __attribute__((ext_vector_type(8))) short bf16x8;
typedef __attribute__((ext_vector_type(4))) float f32x4;
typedef unsigned short ushort_t;

static __device__ __forceinline__ unsigned short f2bf(float x) {
    unsigned int u = __float_as_uint(x);
    unsigned int r = (u + 0x7fffu + ((u >> 16) & 1u)) >> 16;
    return (unsigned short)r;
}
static __device__ __forceinline__ float bf2f(unsigned short h) {
    return __uint_as_float(((unsigned int)h) << 16);
}

// ===========================================================================
// Kernel 0: conversions + bias packing.
// ===========================================================================
__global__ __launch_bounds__(256) void convert_kernel(
    const float* __restrict__ s,
    const float* __restrict__ wq, const float* __restrict__ bq,
    const float* __restrict__ wkv, const float* __restrict__ bkv,
    const float* __restrict__ wqp, const float* __restrict__ bqp,
    const float* __restrict__ wkvp, const float* __restrict__ bkvp,
    const float* __restrict__ wgq, const float* __restrict__ bgq,
    const float* __restrict__ wgk, const float* __restrict__ bgk,
    const float* __restrict__ wout,
    ushort_t* __restrict__ s_bf, ushort_t* __restrict__ wt_bf,
    ushort_t* __restrict__ wtg_bf, float* __restrict__ pbias,
    float* __restrict__ gbias,
    ushort_t* __restrict__ wo_hi, ushort_t* __restrict__ wo_lo)
{
    const int idx = blockIdx.x*256 + threadIdx.x;
    const int NS   = 2048*384;
    const int NWT  = 384*1152;
    const int NWTG = 384*384;
    const int NWO  = 576*384;
    if (idx < NS) {
        s_bf[idx] = f2bf(s[idx]);
    } else if (idx < NS + NWT) {
        const int t = idx - NS;
        const int k = t / 1152, vc = t - k*1152;
        const float* w; int C, lc;
        if (vc < 192)      { w = wq;   C = 192; lc = vc; }
        else if (vc < 576) { w = wkv;  C = 384; lc = vc - 192; }
        else if (vc < 720) { w = wqp;  C = 144; lc = vc - 576; }
        else               { w = wkvp; C = 432; lc = vc - 720; }
        wt_bf[(size_t)vc*384 + k] = f2bf(w[(size_t)k*C + lc]);
    } else if (idx < NS + NWT + NWTG) {
        const int t = idx - NS - NWT;
        const int k = t / 384, vc = t - k*384;
        const float val = (vc < 192) ? wgq[(size_t)k*192 + vc]
                                     : wgk[(size_t)k*192 + vc - 192];
        wtg_bf[(size_t)vc*384 + k] = f2bf(val);
    } else if (idx < NS + NWT + NWTG + 1152) {
        const int i = idx - NS - NWT - NWTG;
        float b;
        if (i < 192)      b = bq[i];
        else if (i < 576) b = bkv[i - 192];
        else if (i < 720) b = bqp[i - 576];
        else              b = bkvp[i - 720];
        pbias[i] = b;
    } else if (idx < NS + NWT + NWTG + 1152 + 384) {
        const int i = idx - NS - NWT - NWTG - 1152;
        gbias[i] = (i < 192) ? bgq[i] : bgk[i - 192];
    } else if (idx < NS + NWT + NWTG + 1536 + NWO) {
        const int t = idx - NS - NWT - NWTG - 1536;
        const int k = t / 384, n = t - k*384;
        const float wv = wout[t];
        const unsigned int u = __float_as_uint(wv);
        const float hif = __uint_as_float(u & 0xFFFF0000u);
        wo_hi[(size_t)n*576 + k] = (ushort_t)(u >> 16);
        wo_lo[(size_t)n*576 + k] = (ushort_t)(__float_as_uint(wv - hif) >> 16);
    }
}

// ===========================================================================
// Kernel 1: unified projection GEMM via MFMA bf16.
// ===========================================================================
__global__ __launch_bounds__(256) void proj_mfma_kernel(
    const ushort_t* __restrict__ s_bf, const ushort_t* __restrict__ wt_bf,
    const float* __restrict__ pbias,
    float* __restrict__ qo, float* __restrict__ ko, float* __restrict__ vo,
    float* __restrict__ rawp)
{
    const int blk = blockIdx.x;
    const int rt = blk / 18, ct = blk - rt*18;
    const int r0 = rt * 64, c0 = ct * 64;
    const int tid = threadIdx.x;
    const int wave = tid >> 6, lane = tid & 63;
    const int wrow = wave >> 1, wcol = wave & 1;
    const int m0 = r0 + wrow*32, n0 = c0 + wcol*32;
    const int qd = lane >> 4, lr = lane & 15;

    f32x4 acc00 = {0,0,0,0}, acc01 = {0,0,0,0}, acc10 = {0,0,0,0}, acc11 = {0,0,0,0};

    const ushort_t* a0p = s_bf  + (size_t)(m0 + lr)*384 + qd*8;
    const ushort_t* a1p = a0p + 16*384;
    const ushort_t* b0p = wt_bf + (size_t)(n0 + lr)*384 + qd*8;
    const ushort_t* b1p = b0p + 16*384;

    #pragma unroll
    for (int kk = 0; kk < 384; kk += 32) {
        const bf16x8 a0 = *(const bf16x8*)(a0p + kk);
        const bf16x8 a1 = *(const bf16x8*)(a1p + kk);
        const bf16x8 b0 = *(const bf16x8*)(b0p + kk);
        const bf16x8 b1 = *(const bf16x8*)(b1p + kk);
        acc00 = __builtin_amdgcn_mfma_f32_16x16x32_bf16(a0, b0, acc00, 0, 0, 0);
        acc01 = __builtin_amdgcn_mfma_f32_16x16x32_bf16(a0, b1, acc01, 0, 0, 0);
        acc10 = __builtin_amdgcn_mfma_f32_16x16x32_bf16(a1, b0, acc10, 0, 0, 0);
        acc11 = __builtin_amdgcn_mfma_f32_16x16x32_bf16(a1, b1, acc11, 0, 0, 0);
    }

    #pragma unroll
    for (int mt = 0; mt < 2; ++mt) {
        #pragma unroll
        for (int nt = 0; nt < 2; ++nt) {
            const f32x4 av = (mt==0) ? (nt==0 ? acc00 : acc01)
                                     : (nt==0 ? acc10 : acc11);
            const int col = n0 + nt*16 + lr;
            const float bb = pbias[col];
            #pragma unroll
            for (int reg = 0; reg < 4; ++reg) {
                const int row = m0 + mt*16 + qd*4 + reg;
                const float val = av[reg] + bb;
                if (col < 192) {
                    qo[(size_t)row*192 + col] = val;
                } else if (col < 576) {
                    const int lc = col - 192, h = lc >> 5, rm = lc & 31;
                    if (rm < 16) ko[(size_t)row*192 + h*16 + rm] = val;
                    else         vo[(size_t)row*192 + h*16 + rm - 16] = val;
                } else {
                    rawp[(size_t)row*576 + col - 576] = val;
                }
            }
        }
    }
}

// ===========================================================================
// Kernel 1b: rigid transform of raw points -> q_pts / k_pts / v_pts
// ===========================================================================
__global__ __launch_bounds__(256) void pt_transform_kernel(
    const float* __restrict__ rawp, const float* __restrict__ rot,
    const float* __restrict__ trans,
    float* __restrict__ qpo, float* __restrict__ kpo, float* __restrict__ vpo)
{
    const int t = blockIdx.x*256 + threadIdx.x;
    const int row = t / 192;
    const int p = t - row*192;
    const float* R = rot + (size_t)row*9;
    const float* T = trans + (size_t)row*3;
    const float* base = rawp + (size_t)row*576;
    float x, y, z;
    if (p < 48) { x = base[p];       y = base[48+p];  z = base[96+p]; }
    else { const int pk = p-48; x = base[144+pk]; y = base[288+pk]; z = base[432+pk]; }
    const float px = R[0]*x + R[1]*y + R[2]*z + T[0];
    const float py = R[3]*x + R[4]*y + R[5]*z + T[1];
    const float pz = R[6]*x + R[7]*y + R[8]*z + T[2];
    if (p < 48) {
        float* o = qpo + (size_t)row*144 + p*3;
        o[0]=px; o[1]=py; o[2]=pz;
    } else {
        const int pk = p-48, h = pk/12, pp = pk - h*12;
        if (pp < 4) { float* o = kpo + (size_t)row*144 + (h*4+pp)*3;     o[0]=px; o[1]=py; o[2]=pz; }
        else        { float* o = vpo + (size_t)row*288 + (h*8+(pp-4))*3; o[0]=px; o[1]=py; o[2]=pz; }
    }
}

// ===========================================================================
// Kernel 2a: s_g = mean over C + LayerNorm -> sgn_bf (bf16)
// ===========================================================================
__global__ __launch_bounds__(256) void ln_kernel(
    const float* __restrict__ s, const float* __restrict__ g_gamma,
    const float* __restrict__ g_beta, ushort_t* __restrict__ sgn_bf)
{
    const int n = blockIdx.x;
    const int tid = threadIdx.x;
    __shared__ float sg[CS];
    __shared__ float red[256];

    for (int d = tid; d < CS; d += 256) {
        float acc = 0.f;
        for (int c = 0; c < CDIM; ++c) acc += s[((size_t)c*NRES+n)*CS + d];
        sg[d] = acc * (1.0f/CDIM);
    }
    __syncthreads();

    float lsum = 0.f;
    for (int d = tid; d < CS; d += 256) lsum += sg[d];
    red[tid] = lsum; __syncthreads();
    for (int st = 128; st > 0; st >>= 1) { if (tid < st) red[tid] += red[tid+st]; __syncthreads(); }
    const float mean = red[0] * (1.0f/CS);
    __syncthreads();

    float lvar = 0.f;
    for (int d = tid; d < CS; d += 256) { float df = sg[d]-mean; lvar += df*df; }
    red[tid] = lvar; __syncthreads();
    for (int st = 128; st > 0; st >>= 1) { if (tid < st) red[tid] += red[tid+st]; __syncthreads(); }
    const float var = red[0] * (1.0f/CS);
    __syncthreads();

    const float inv = rsqrtf(var + 1e-5f);
    for (int d = tid; d < CS; d += 256)
        sgn_bf[(size_t)n*CS + d] = f2bf((sg[d]-mean)*inv*g_gamma[d] + g_beta[d]);
}

// ===========================================================================
// Kernel 2b: g_q|g_k = sgn @ [wgq|wgk] via MFMA bf16.
// ===========================================================================
__global__ __launch_bounds__(256) void ggemm_mfma_kernel(
    const ushort_t* __restrict__ sgn_bf, const ushort_t* __restrict__ wtg_bf,
    const float* __restrict__ gbias,
    float* __restrict__ gqo, float* __restrict__ gko)
{
    const int blk = blockIdx.x;
    const int rt = blk / 6, ct = blk - rt*6;
    const int r0 = rt * 64, c0 = ct * 64;
    const int tid = threadIdx.x;
    const int wave = tid >> 6, lane = tid & 63;
    const int wrow = wave >> 1, wcol = wave & 1;
    const int m0 = r0 + wrow*32, n0 = c0 + wcol*32;
    const int qd = lane >> 4, lr = lane & 15;

    f32x4 acc00 = {0,0,0,0}, acc01 = {0,0,0,0}, acc10 = {0,0,0,0}, acc11 = {0,0,0,0};

    const ushort_t* a0p = sgn_bf + (size_t)(m0 + lr)*384 + qd*8;
    const ushort_t* a1p = a0p + 16*384;
    const ushort_t* b0p = wtg_bf + (size_t)(n0 + lr)*384 + qd*8;
    const ushort_t* b1p = b0p + 16*384;

    #pragma unroll
    for (int kk = 0; kk < 384; kk += 32) {
        const bf16x8 a0 = *(const bf16x8*)(a0p + kk);
        const bf16x8 a1 = *(const bf16x8*)(a1p + kk);
        const bf16x8 b0 = *(const bf16x8*)(b0p + kk);
        const bf16x8 b1 = *(const bf16x8*)(b1p + kk);
        acc00 = __builtin_amdgcn_mfma_f32_16x16x32_bf16(a0, b0, acc00, 0, 0, 0);
        acc01 = __builtin_amdgcn_mfma_f32_16x16x32_bf16(a0, b1, acc01, 0, 0, 0);
        acc10 = __builtin_amdgcn_mfma_f32_16x16x32_bf16(a1, b0, acc10, 0, 0, 0);
        acc11 = __builtin_amdgcn_mfma_f32_16x16x32_bf16(a1, b1, acc11, 0, 0, 0);
    }

    #pragma unroll
    for (int mt = 0; mt < 2; ++mt) {
        #pragma unroll
        for (int nt = 0; nt < 2; ++nt) {
            const f32x4 av = (mt==0) ? (nt==0 ? acc00 : acc01)
                                     : (nt==0 ? acc10 : acc11);
            const int col = n0 + nt*16 + lr;
            const float bb = gbias[col];
            #pragma unroll
            for (int reg = 0; reg < 4; ++reg) {
                const int row = m0 + mt*16 + qd*4 + reg;
                const float val = av[reg] + bb;
                if (col < 192) gqo[(size_t)row*192 + col]       = val;
                else           gko[(size_t)row*192 + col - 192] = val;
            }
        }
    }
}

// ===========================================================================
// Kernel 3: attention via MFMA, i-quarters (64 rows) -> 384 blocks.
// Row stride 104 ushorts (52 words: 2-way LDS access = free). LDS ~74.7 KB
// -> 2 blocks/CU, 8 waves/CU. No tsh (dist LUT reads trans from L2).
// ===========================================================================
#define BSTR 104
__global__ __launch_bounds__(256) void attn_mfma_kernel(
    const float* __restrict__ q, const float* __restrict__ k,
    const float* __restrict__ q_pts, const float* __restrict__ k_pts,
    const float* __restrict__ g_q, const float* __restrict__ g_k,
    const float* __restrict__ trans, const float* __restrict__ mask,
    const float* __restrict__ head_weights, const float* __restrict__ wdist,
    const float* __restrict__ bdist, float* __restrict__ a_out)
{
    const int blk  = blockIdx.x;
    const int qtr  = blk & 3;
    const int ch   = blk >> 2;
    const int h    = ch % HNUM;
    const int c    = ch / HNUM;
    const int i0   = qtr * 64;
    const int tid  = threadIdx.x;

    __shared__ ushort_t Bsh[256*BSTR];   // 53.2 KB
    __shared__ ushort_t Ash[64*BSTR];    // 13.3 KB
    __shared__ float dsh[7*256];         // 7 KB
    __shared__ float msh[256];
    __shared__ float kn_sh[256];
    __shared__ float qn_sh[64];
    __shared__ float wdsh[12], bdsh[12];
    __shared__ float cpart[96];
    __shared__ float censh[3];

    msh[tid] = mask[c*NRES + tid];
    if (tid < 12) { wdsh[tid] = wdist[tid]; bdsh[tid] = bdist[tid]; }

    // centroid of trans chain c (straight from L2)
    if (tid < 96) {
        const int coord = tid % 3, chunk = tid / 3;
        float sv = 0.f;
        for (int e = 0; e < 8; ++e)
            sv += trans[((size_t)c*NRES + chunk*8 + e)*3 + coord];
        cpart[tid] = sv;
    }
    __syncthreads();
    if (tid < 3) {
        float sv = 0.f;
        for (int e = 0; e < 32; ++e) sv += cpart[e*3 + tid];
        censh[tid] = sv * (1.0f/256.0f);
    }
    __syncthreads();

    const float s54   = 0.13608276348795434f;  // sqrt(1/54)
    const float scale = 0.14433756729740643f;  // sqrt(1/48)
    const float hwv = 0.5f * logf(1.0f + expf(head_weights[h])) * s54;
    const float sh  = sqrtf(2.0f * hwv);
    const float cx = censh[0], cy = censh[1], cz = censh[2];
    const float cen3[3] = {cx, cy, cz};

    // --- build B rows (all 256 threads, one j each), vectorized loads ---
    {
        const int j = tid;
        const float4* kr4 = (const float4*)(k    + ((size_t)c*NRES + j)*192 + h*16);
        const float4* gk4 = (const float4*)(g_k  + (size_t)j*192 + h*16);
        const float4* kp4 = (const float4*)(k_pts+ ((size_t)c*NRES + j)*144 + h*12);
        ushort_t* br = &Bsh[j*BSTR];
        #pragma unroll
        for (int e4 = 0; e4 < 4; ++e4) {
            const float4 w = kr4[e4];
            br[e4*4+0] = f2bf(w.x); br[e4*4+1] = f2bf(w.y);
            br[e4*4+2] = f2bf(w.z); br[e4*4+3] = f2bf(w.w);
        }
        #pragma unroll
        for (int e4 = 0; e4 < 4; ++e4) {
            const float4 w = gk4[e4];
            br[16+e4*4+0] = f2bf(w.x); br[16+e4*4+1] = f2bf(w.y);
            br[16+e4*4+2] = f2bf(w.z); br[16+e4*4+3] = f2bf(w.w);
        }
        float kp_a[12];
        #pragma unroll
        for (int e4 = 0; e4 < 3; ++e4) {
            const float4 w = kp4[e4];
            kp_a[e4*4+0]=w.x; kp_a[e4*4+1]=w.y; kp_a[e4*4+2]=w.z; kp_a[e4*4+3]=w.w;
        }
        float kn = 0.f;
        #pragma unroll
        for (int e = 0; e < 12; ++e) {
            const float kp = kp_a[e] - cen3[e % 3];
            kn += kp*kp;
            const float sp = sh * kp;
            const unsigned int u = __float_as_uint(sp);
            const float hif = __uint_as_float(u & 0xFFFF0000u);
            const ushort_t hi = (ushort_t)(u >> 16);
            br[32+e] = hi;
            br[44+e] = (ushort_t)(__float_as_uint(sp - hif) >> 16);
            br[56+e] = hi;
        }
        #pragma unroll
        for (int e = 68; e < 96; ++e) br[e] = 0;
        kn_sh[j] = hwv * kn;
    }

    // --- build A rows (threads 0..63, one i each) ---
    if (tid < 64) {
        const int il = i0 + tid;
        const float4* qr4 = (const float4*)(q    + ((size_t)c*NRES + il)*192 + h*16);
        const float4* gq4 = (const float4*)(g_q  + (size_t)il*192 + h*16);
        const float4* qp4 = (const float4*)(q_pts+ ((size_t)c*NRES + il)*144 + h*12);
        ushort_t* ar = &Ash[tid*BSTR];
        #pragma unroll
        for (int e4 = 0; e4 < 4; ++e4) {
            const float4 w = qr4[e4];
            ar[e4*4+0] = f2bf(scale*w.x); ar[e4*4+1] = f2bf(scale*w.y);
            ar[e4*4+2] = f2bf(scale*w.z); ar[e4*4+3] = f2bf(scale*w.w);
        }
        #pragma unroll
        for (int e4 = 0; e4 < 4; ++e4) {
            const float4 w = gq4[e4];
            ar[16+e4*4+0] = f2bf(scale*w.x); ar[16+e4*4+1] = f2bf(scale*w.y);
            ar[16+e4*4+2] = f2bf(scale*w.z); ar[16+e4*4+3] = f2bf(scale*w.w);
        }
        float qp_a[12];
        #pragma unroll
        for (int e4 = 0; e4 < 3; ++e4) {
            const float4 w = qp4[e4];
            qp_a[e4*4+0]=w.x; qp_a[e4*4+1]=w.y; qp_a[e4*4+2]=w.z; qp_a[e4*4+3]=w.w;
        }
        float qn = 0.f;
        #pragma unroll
        for (int e = 0; e < 12; ++e) {
            const float qp = qp_a[e] - cen3[e % 3];
            qn += qp*qp;
            const float sp = sh * qp;
            const unsigned int u = __float_as_uint(sp);
            const float hif = __uint_as_float(u & 0xFFFF0000u);
            const ushort_t hi = (ushort_t)(u >> 16);
            ar[32+e] = hi;
            ar[44+e] = hi;
            ar[56+e] = (ushort_t)(__float_as_uint(sp - hif) >> 16);
        }
        #pragma unroll
        for (int e = 68; e < 96; ++e) ar[e] = 0;
        qn_sh[tid] = hwv * qn;
    }

    // --- dist LUT for this (h, i-quarter): NI <= 7 ii values ---
    const int Fmin = h*65536 + i0*256;
    const int iibase = Fmin / 3072;
    const int NI = (Fmin + 63*256 + 255)/3072 - iibase + 1;
    const float* tch = trans + (size_t)c*768;
    for (int idx = tid; idx < NI*256; idx += 256) {
        const int e = idx >> 8, jj = idx & 255;
        const int ia = iibase + e;
        const float dx = tch[ia*3+0] - tch[jj*3+0];
        const float dy = tch[ia*3+1] - tch[jj*3+1];
        const float dz = tch[ia*3+2] - tch[jj*3+2];
        dsh[idx] = sqrtf(dx*dx + dy*dy + dz*dz);
    }
    __syncthreads();

    // --- main: wave handles 16 rows ---
    const int wave = tid >> 6, lane = tid & 63;
    const int qd = lane >> 4, lr = lane & 15;
    const int m0 = wave*16;

    const ushort_t* ap = &Ash[(m0 + lr)*BSTR + qd*8];
    const bf16x8 af0 = *(const bf16x8*)(ap);
    const bf16x8 af1 = *(const bf16x8*)(ap + 32);
    const bf16x8 af2 = *(const bf16x8*)(ap + 64);

    f32x4 acc[16];
    #pragma unroll
    for (int t = 0; t < 16; ++t) {
        const ushort_t* bp = &Bsh[(t*16 + lr)*BSTR + qd*8];
        f32x4 a = {0.f,0.f,0.f,0.f};
        a = __builtin_amdgcn_mfma_f32_16x16x32_bf16(af0, *(const bf16x8*)(bp),      a, 0, 0, 0);
        a = __builtin_amdgcn_mfma_f32_16x16x32_bf16(af1, *(const bf16x8*)(bp + 32), a, 0, 0, 0);
        a = __builtin_amdgcn_mfma_f32_16x16x32_bf16(af2, *(const bf16x8*)(bp + 64), a, 0, 0, 0);
        acc[t] = a;
    }

    const int ibase = m0 + qd*4;           // local row (0..63)
    float qn_r[4], mb_r[4];
    int F0_[4];
    #pragma unroll
    for (int r = 0; r < 4; ++r) {
        const int il = i0 + ibase + r;
        qn_r[r] = qn_sh[ibase + r];
        mb_r[r] = 100000.0f * msh[il];
        F0_[r]  = h*65536 + il*256;
    }

    float mx[4] = {-1e30f,-1e30f,-1e30f,-1e30f};
    #pragma unroll
    for (int t = 0; t < 16; ++t) {
        const int j = t*16 + lr;
        const float knj = kn_sh[j];
        const float mj  = msh[j];
        #pragma unroll
        for (int r = 0; r < 4; ++r) {
            const unsigned int f = (unsigned int)(F0_[r] + j);
            const unsigned int p = f / 12u;
            const int ho = (int)(f - p*12u);
            const int ii = (int)(p >> 8);
            const int jj = (int)(p & 255u);
            const float dist = dsh[(ii - iibase)*256 + jj];
            const float db = dist*wdsh[ho] + bdsh[ho];
            const float lv = acc[t][r] - qn_r[r] - knj
                           + (mb_r[r]*mj - 100000.0f) + db;
            acc[t][r] = lv;
            mx[r] = fmaxf(mx[r], lv);
        }
    }
    #pragma unroll
    for (int r = 0; r < 4; ++r) {
        #pragma unroll
        for (int off = 1; off < 16; off <<= 1)
            mx[r] = fmaxf(mx[r], __shfl_xor(mx[r], off));
    }
    float sm[4] = {0.f,0.f,0.f,0.f};
    #pragma unroll
    for (int t = 0; t < 16; ++t) {
        #pragma unroll
        for (int r = 0; r < 4; ++r) {
            const float e = __expf(acc[t][r] - mx[r]);
            acc[t][r] = e;
            sm[r] += e;
        }
    }
    #pragma unroll
    for (int r = 0; r < 4; ++r) {
        #pragma unroll
        for (int off = 1; off < 16; off <<= 1)
            sm[r] += __shfl_xor(sm[r], off);
        sm[r] = 1.0f / sm[r];
    }
    float* dst = a_out + ((size_t)ch*NRES + (i0 + ibase))*NRES;
    #pragma unroll
    for (int t = 0; t < 16; ++t) {
        #pragma unroll
        for (int r = 0; r < 4; ++r)
            dst[(size_t)r*NRES + t*16 + lr] = acc[t][r]*sm[r];
    }
}

// ===========================================================================
// Kernel 4a: o / o_pt via MFMA (truncation-based hi/lo splits).
// ===========================================================================
#define ASTRB 264
__global__ __launch_bounds__(256) void out_feat_mfma_kernel(
    const float* __restrict__ a, const float* __restrict__ v,
    const float* __restrict__ v_pts, const float* __restrict__ rot,
    const float* __restrict__ trans,
    ushort_t* __restrict__ feat_hi, ushort_t* __restrict__ feat_lo)
{
    const int blk = blockIdx.x;
    const int qtr = blk & 3;
    const int ch  = blk >> 2;
    const int h   = ch % HNUM;
    const int c   = ch / HNUM;
    const int i0  = qtr * 64;
    const int tid = threadIdx.x;

    __shared__ ushort_t Bt[64*ASTRB];
    __shared__ float opt[64*25];
    __shared__ float osh[64*17];
    __shared__ float cpart[96];
    __shared__ float censh[3];

    if (tid < 96) {
        const int coord = tid % 3, chunk = tid / 3;
        float sv = 0.f;
        for (int e = 0; e < 8; ++e)
            sv += trans[((size_t)c*NRES + chunk*8 + e)*3 + coord];
        cpart[tid] = sv;
    }
    __syncthreads();
    if (tid < 3) {
        float sv = 0.f;
        for (int e = 0; e < 32; ++e) sv += cpart[e*3 + tid];
        censh[tid] = sv * (1.0f/256.0f);
    }
    __syncthreads();
    const float cx = censh[0], cy = censh[1], cz = censh[2];
    const float cen3[3] = {cx, cy, cz};

    {
        const int j = tid;
        const float4* vr = (const float4*)(v + ((size_t)c*NRES + j)*192 + h*16);
        #pragma unroll
        for (int e4 = 0; e4 < 4; ++e4) {
            const float4 w = vr[e4];
            Bt[(e4*4+0)*ASTRB + j] = f2bf(w.x);
            Bt[(e4*4+1)*ASTRB + j] = f2bf(w.y);
            Bt[(e4*4+2)*ASTRB + j] = f2bf(w.z);
            Bt[(e4*4+3)*ASTRB + j] = f2bf(w.w);
        }
        const float4* vpr = (const float4*)(v_pts + ((size_t)c*NRES + j)*288 + h*24);
        #pragma unroll
        for (int e4 = 0; e4 < 6; ++e4) {
            const float4 w = vpr[e4];
            const float vals[4] = {w.x, w.y, w.z, w.w};
            #pragma unroll
            for (int cc = 0; cc < 4; ++cc) {
                const int e = e4*4 + cc;
                const float vp = vals[cc] - cen3[e % 3];
                const unsigned int u = __float_as_uint(vp);
                const float hif = __uint_as_float(u & 0xFFFF0000u);
                Bt[(16+e)*ASTRB + j] = (ushort_t)(u >> 16);
                Bt[(40+e)*ASTRB + j] = (ushort_t)(__float_as_uint(vp - hif) >> 16);
            }
        }
    }
    __syncthreads();

    const int wave = tid >> 6, lane = tid & 63;
    const int qd = lane >> 4, lr = lane & 15;
    const int m0 = wave*16;

    const float* arow = a + ((size_t)ch*NRES + i0 + m0 + lr)*NRES;

    f32x4 acc[4] = {{0,0,0,0},{0,0,0,0},{0,0,0,0},{0,0,0,0}};
    #pragma unroll
    for (int kk = 0; kk < 256; kk += 32) {
        const float4 a0 = *(const float4*)(arow + qd*8 + kk);
        const float4 a1 = *(const float4*)(arow + qd*8 + kk + 4);
        const float av[8] = {a0.x,a0.y,a0.z,a0.w,a1.x,a1.y,a1.z,a1.w};
        bf16x8 ahi, alo;
        #pragma unroll
        for (int e = 0; e < 8; ++e) {
            const unsigned int u = __float_as_uint(av[e]);
            const float hif = __uint_as_float(u & 0xFFFF0000u);
            ((ushort_t*)&ahi)[e] = (ushort_t)(u >> 16);
            ((ushort_t*)&alo)[e] = (ushort_t)(__float_as_uint(av[e] - hif) >> 16);
        }
        #pragma unroll
        for (int t = 0; t < 4; ++t) {
            const bf16x8 bf = *(const bf16x8*)&Bt[(t*16 + lr)*ASTRB + qd*8 + kk];
            acc[t] = __builtin_amdgcn_mfma_f32_16x16x32_bf16(ahi, bf, acc[t], 0, 0, 0);
            acc[t] = __builtin_amdgcn_mfma_f32_16x16x32_bf16(alo, bf, acc[t], 0, 0, 0);
        }
    }

    #pragma unroll
    for (int reg = 0; reg < 4; ++reg) {
        const int row_l = m0 + qd*4 + reg;
        osh[row_l*17 + lr] = acc[0][reg];
        opt[row_l*25 + lr] = acc[1][reg];
    }
    #pragma unroll
    for (int reg = 0; reg < 4; ++reg) {
        const int row_l = m0 + qd*4 + reg;
        if (lr < 8) opt[row_l*25 + 16 + lr] = acc[2][reg];
        else        opt[row_l*25 + (lr-8)] += acc[2][reg];
    }
    #pragma unroll
    for (int reg = 0; reg < 4; ++reg) {
        const int row_l = m0 + qd*4 + reg;
        opt[row_l*25 + 8 + lr] += acc[3][reg];
    }
    __syncthreads();

    #pragma unroll
    for (int it = 0; it < 4; ++it) {
        const int idx = it*256 + tid;
        const int row_l = idx >> 4, e = idx & 15;
        const int grow = c*NRES + i0 + row_l;
        const float val = osh[row_l*17 + e];
        const unsigned int u = __float_as_uint(val);
        const float hif = __uint_as_float(u & 0xFFFF0000u);
        feat_hi[(size_t)grow*576 + h*16 + e] = (ushort_t)(u >> 16);
        feat_lo[(size_t)grow*576 + h*16 + e] = (ushort_t)(__float_as_uint(val - hif) >> 16);
    }
    #pragma unroll
    for (int it = 0; it < 2; ++it) {
        const int idx = it*256 + tid;
        const int row_l = idx >> 3, p = idx & 7;
        const int grow = c*NRES + i0 + row_l;
        const float* R = rot + (size_t)grow*9;
        const float* T = trans + (size_t)grow*3;
        const float x = opt[row_l*25 + p*3+0] + cx - T[0];
        const float y = opt[row_l*25 + p*3+1] + cy - T[1];
        const float z = opt[row_l*25 + p*3+2] + cz - T[2];
        const float rx = R[0]*x + R[3]*y + R[6]*z;
        const float ry = R[1]*x + R[4]*y + R[7]*z;
        const float rz = R[2]*x + R[5]*y + R[8]*z;
        const float nm = sqrtf(rx*rx + ry*ry + rz*rz + 1e-8f);
        const float vals[4] = {rx, ry, rz, nm};
        #pragma unroll
        for (int sl = 0; sl < 4; ++sl) {
            const int col = 192 + sl*96 + h*8 + p;
            const float vv = vals[sl];
            const unsigned int u = __float_as_uint(vv);
            const float hif = __uint_as_float(u & 0xFFFF0000u);
            feat_hi[(size_t)grow*576 + col] = (ushort_t)(u >> 16);
            feat_lo[(size_t)grow*576 + col] = (ushort_t)(__float_as_uint(vv - hif) >> 16);
        }
    }
}

// ===========================================================================
// Kernel 4b: out0 = feat @ wout + bout via MFMA (3-term hi/lo product).
// ===========================================================================
__global__ __launch_bounds__(256) void out_gemm_mfma_kernel(
    const ushort_t* __restrict__ feat_hi, const ushort_t* __restrict__ feat_lo,
    const ushort_t* __restrict__ wo_hi, const ushort_t* __restrict__ wo_lo,
    const float* __restrict__ bout, float* __restrict__ out0)
{
    const int blk = blockIdx.x;
    const int rt = blk / 6, ct = blk - rt*6;
    const int r0 = rt * 64, c0 = ct * 64;
    const int tid = threadIdx.x;
    const int wave = tid >> 6, lane = tid & 63;
    const int wrow = wave >> 1, wcol = wave & 1;
    const int m0 = r0 + wrow*32, n0 = c0 + wcol*32;
    const int qd = lane >> 4, lr = lane & 15;

    f32x4 acc[2][2] = {{{0,0,0,0},{0,0,0,0}},{{0,0,0,0},{0,0,0,0}}};

    const ushort_t* ah0 = feat_hi + (size_t)(m0 + lr)*576 + qd*8;
    const ushort_t* ah1 = ah0 + 16*576;
    const ushort_t* al0 = feat_lo + (size_t)(m0 + lr)*576 + qd*8;
    const ushort_t* al1 = al0 + 16*576;
    const ushort_t* bh0 = wo_hi + (size_t)(n0 + lr)*576 + qd*8;
    const ushort_t* bh1 = bh0 + 16*576;
    const ushort_t* bl0 = wo_lo + (size_t)(n0 + lr)*576 + qd*8;
    const ushort_t* bl1 = bl0 + 16*576;

    for (int kk = 0; kk < 576; kk += 32) {
        const bf16x8 fh0 = *(const bf16x8*)(ah0 + kk);
        const bf16x8 fh1 = *(const bf16x8*)(ah1 + kk);
        const bf16x8 fl0 = *(const bf16x8*)(al0 + kk);
        const bf16x8 fl1 = *(const bf16x8*)(al1 + kk);
        const bf16x8 wh0 = *(const bf16x8*)(bh0 + kk);
        const bf16x8 wh1 = *(const bf16x8*)(bh1 + kk);
        const bf16x8 wl0 = *(const bf16x8*)(bl0 + kk);
        const bf16x8 wl1 = *(const bf16x8*)(bl1 + kk);
        acc[0][0] = __builtin_amdgcn_mfma_f32_16x16x32_bf16(fh0, wh0, acc[0][0], 0, 0, 0);
        acc[0][1] = __builtin_amdgcn_mfma_f32_16x16x32_bf16(fh0, wh1, acc[0][1], 0, 0, 0);
        acc[1][0] = __builtin_amdgcn_mfma_f32_16x16x32_bf16(fh1, wh0, acc[1][0], 0, 0, 0);
        acc[1][1] = __builtin_amdgcn_mfma_f32_16x16x32_bf16(fh1, wh1, acc[1][1], 0, 0, 0);
        acc[0][0] = __builtin_amdgcn_mfma_f32_16x16x32_bf16(fl0, wh0, acc[0][0], 0, 0, 0);
        acc[0][1] = __builtin_amdgcn_mfma_f32_16x16x32_bf16(fl0, wh1, acc[0][1], 0, 0, 0);
        acc[1][0] = __builtin_amdgcn_mfma_f32_16x16x32_bf16(fl1, wh0, acc[1][0], 0, 0, 0);
        acc[1][1] = __builtin_amdgcn_mfma_f32_16x16x32_bf16(fl1, wh1, acc[1][1], 0, 0, 0);
        acc[0][0] = __builtin_amdgcn_mfma_f32_16x16x32_bf16(fh0, wl0, acc[0][0], 0, 0, 0);
        acc[0][1] = __builtin_amdgcn_mfma_f32_16x16x32_bf16(fh0, wl1, acc[0][1], 0, 0, 0);
        acc[1][0] = __builtin_amdgcn_mfma_f32_16x16x32_bf16(fh1, wl0, acc[1][0], 0, 0, 0);
        acc[1][1] = __builtin_amdgcn_mfma_f32_16x16x32_bf16(fh1, wl1, acc[1][1], 0, 0, 0);
    }

    #pragma unroll
    for (int mt = 0; mt < 2; ++mt) {
        #pragma unroll
        for (int nt = 0; nt < 2; ++nt) {
            const int col = n0 + nt*16 + lr;
            const float bb = bout[col];
            #pragma unroll
            for (int reg = 0; reg < 4; ++reg) {
                const int row = m0 + mt*16 + qd*4 + reg;
                out0[(size_t)row*CS + col] = acc[mt][nt][reg] + bb;
            }
        }
    }
}

// ===========================================================================
extern "C" void kernel_launch(void* const* d_in, const int* in_sizes, int n_in,
                              void* d_out, int out_size, void* d_ws, size_t ws_size,
                              hipStream_t stream)
{
    const float* s     = (const float*)d_in[0];
    const float* rot   = (const float*)d_in[2];
    const float* trans = (const float*)d_in[3];
    const float* mask  = (const float*)d_in[4];
    const float* wq    = (const float*)d_in[5];
    const float* bq    = (const float*)d_in[6];
    const float* wkv   = (const float*)d_in[7];
    const float* bkv   = (const float*)d_in[8];
    const float* g_gamma = (const float*)d_in[9];
    const float* g_beta  = (const float*)d_in[10];
    const float* wgq   = (const float*)d_in[11];
    const float* bgq   = (const float*)d_in[12];
    const float* wgk   = (const float*)d_in[13];
    const float* bgk   = (const float*)d_in[14];
    const float* wqp   = (const float*)d_in[15];
    const float* bqp   = (const float*)d_in[16];
    const float* wkvp  = (const float*)d_in[17];
    const float* bkvp  = (const float*)d_in[18];
    const float* head_weights = (const float*)d_in[19];
    const float* wdist = (const float*)d_in[20];
    const float* bdist = (const float*)d_in[21];
    const float* wout  = (const float*)d_in[22];
    const float* bout  = (const float*)d_in[23];

    float* ws      = (float*)d_ws;
    float* q_buf   = ws + 0;          // 393216
    float* qp_buf  = ws + 393216;     // 294912
    float* kp_buf  = ws + 688128;     // 294912
    float* gq_buf  = ws + 983040;     // 49152
    float* gk_buf  = ws + 1032192;    // 49152
    float* k_buf   = ws + 1081344;    // 393216
    float* v_buf   = ws + 1474560;    // 393216
    float* vp_buf  = ws + 1867776;    // 589824 (-> 2457600)
    ushort_t* sgn_bf  = (ushort_t*)(ws + 1867776); // overlays vp; dead before pt
    ushort_t* feat_hi = (ushort_t*)(ws + 2457600); // 1179648 bf16
    ushort_t* feat_lo = (ushort_t*)(ws + 3047424); // 1179648 bf16
    ushort_t* wo_hi   = (ushort_t*)(ws + 3637248); // 221184 bf16
    ushort_t* wo_lo   = (ushort_t*)(ws + 3747840); // 221184 bf16

    float* out0  = (float*)d_out;       // 786432
    float* a_out = out0 + 786432;       // 6291456
    // overlays inside a_out (dead before attn writes):
    float*    rawp   = a_out;                              // 1179648 floats
    ushort_t* s_bf   = (ushort_t*)(a_out + 1179648);       // 786432 bf16
    ushort_t* wt_bf  = (ushort_t*)(a_out + 1572864);       // 442368 bf16
    ushort_t* wtg_bf = (ushort_t*)(a_out + 1794048);       // 147456 bf16
    float*    pbias  = a_out + 1867776;                    // 1152
    float*    gbias  = a_out + 1868928;                    // 384

    convert_kernel<<<6246, 256, 0, stream>>>(s, wq, bq, wkv, bkv, wqp, bqp,
                                             wkvp, bkvp, wgq, bgq, wgk, bgk, wout,
                                             s_bf, wt_bf, wtg_bf, pbias, gbias,
                                             wo_hi, wo_lo);
    ln_kernel<<<256, 256, 0, stream>>>(s, g_gamma, g_beta, sgn_bf);
    proj_mfma_kernel<<<576, 256, 0, stream>>>(s_bf, wt_bf, pbias,
                                              q_buf, k_buf, v_buf, rawp);
    ggemm_mfma_kernel<<<24, 256, 0, stream>>>(sgn_bf, wtg_bf, gbias,
                                              gq_buf, gk_buf);
    pt_transform_kernel<<<1536, 256, 0, stream>>>(rawp, rot, trans,
                                                  qp_buf, kp_buf, vp_buf);
    attn_mfma_kernel<<<384, 256, 0, stream>>>(q_buf, k_buf, qp_buf, kp_buf,
                                              gq_buf, gk_buf, trans, mask,
                                              head_weights, wdist, bdist, a_out);
    out_feat_mfma_kernel<<<384, 256, 0, stream>>>(a_out, v_buf, vp_buf, rot, trans,
                                                  feat_hi, feat_lo);
    out_gemm_mfma_kernel<<<192, 256, 0, stream>>>(feat_hi, feat_lo, wo_hi, wo_lo,
                                                  bout, out0);
}

// Round 10
// 200.434 us; speedup vs baseline: 1.6751x; 1.0571x over previous
//
#include <hip/hip_runtime.h>
#include <math.h>

#define NRES 256
#define CDIM 8
#define HNUM 12
#define CS   384

typedef __attribute__((ext_vector_type(8))) short bf16x8;
typedef __attribute__((ext_vector_type(4))) float f32x4;
typedef unsigned short ushort_t;

static __device__ __forceinline__ unsigned short f2bf(float x) {
    unsigned int u = __float_as_uint(x);
    unsigned int r = (u + 0x7fffu + ((u >> 16) & 1u)) >> 16;
    return (unsigned short)r;
}

// ===========================================================================
// Kernel 0: conversions + bias packing + LayerNorm (fused; branch on block).
// ===========================================================================
__global__ __launch_bounds__(256) void convert_ln_kernel(
    const float* __restrict__ s,
    const float* __restrict__ wq, const float* __restrict__ bq,
    const float* __restrict__ wkv, const float* __restrict__ bkv,
    const float* __restrict__ wqp, const float* __restrict__ bqp,
    const float* __restrict__ wkvp, const float* __restrict__ bkvp,
    const float* __restrict__ wgq, const float* __restrict__ bgq,
    const float* __restrict__ wgk, const float* __restrict__ bgk,
    const float* __restrict__ wout,
    const float* __restrict__ g_gamma, const float* __restrict__ g_beta,
    ushort_t* __restrict__ s_bf, ushort_t* __restrict__ wt_bf,
    ushort_t* __restrict__ wtg_bf, float* __restrict__ pbias,
    float* __restrict__ gbias,
    ushort_t* __restrict__ wo_hi, ushort_t* __restrict__ wo_lo,
    ushort_t* __restrict__ sgn_bf)
{
    __shared__ float sg[CS];
    __shared__ float red[256];
    const int tid = threadIdx.x;
    const int NS   = 2048*384;
    const int NWT  = 384*1152;
    const int NWTG = 384*384;
    const int NWO  = 576*384;
    const int NB_CONV = 6246;   // (NS+NWT+NWTG+1536+NWO)/256

    if (blockIdx.x < NB_CONV) {
        const int idx = blockIdx.x*256 + tid;
        if (idx < NS) {
            s_bf[idx] = f2bf(s[idx]);
        } else if (idx < NS + NWT) {
            const int t = idx - NS;
            const int k = t / 1152, vc = t - k*1152;
            const float* w; int C, lc;
            if (vc < 192)      { w = wq;   C = 192; lc = vc; }
            else if (vc < 576) { w = wkv;  C = 384; lc = vc - 192; }
            else if (vc < 720) { w = wqp;  C = 144; lc = vc - 576; }
            else               { w = wkvp; C = 432; lc = vc - 720; }
            wt_bf[(size_t)vc*384 + k] = f2bf(w[(size_t)k*C + lc]);
        } else if (idx < NS + NWT + NWTG) {
            const int t = idx - NS - NWT;
            const int k = t / 384, vc = t - k*384;
            const float val = (vc < 192) ? wgq[(size_t)k*192 + vc]
                                         : wgk[(size_t)k*192 + vc - 192];
            wtg_bf[(size_t)vc*384 + k] = f2bf(val);
        } else if (idx < NS + NWT + NWTG + 1152) {
            const int i = idx - NS - NWT - NWTG;
            float b;
            if (i < 192)      b = bq[i];
            else if (i < 576) b = bkv[i - 192];
            else if (i < 720) b = bqp[i - 576];
            else              b = bkvp[i - 720];
            pbias[i] = b;
        } else if (idx < NS + NWT + NWTG + 1152 + 384) {
            const int i = idx - NS - NWT - NWTG - 1152;
            gbias[i] = (i < 192) ? bgq[i] : bgk[i - 192];
        } else if (idx < NS + NWT + NWTG + 1536 + NWO) {
            const int t = idx - NS - NWT - NWTG - 1536;
            const int k = t / 384, n = t - k*384;
            const float wv = wout[t];
            const unsigned int u = __float_as_uint(wv);
            const float hif = __uint_as_float(u & 0xFFFF0000u);
            wo_hi[(size_t)n*576 + k] = (ushort_t)(u >> 16);
            wo_lo[(size_t)n*576 + k] = (ushort_t)(__float_as_uint(wv - hif) >> 16);
        }
        return;
    }

    // ---- LayerNorm branch: one block per n ----
    const int n = blockIdx.x - NB_CONV;
    for (int d = tid; d < CS; d += 256) {
        float acc = 0.f;
        for (int c = 0; c < CDIM; ++c) acc += s[((size_t)c*NRES+n)*CS + d];
        sg[d] = acc * (1.0f/CDIM);
    }
    __syncthreads();

    float lsum = 0.f;
    for (int d = tid; d < CS; d += 256) lsum += sg[d];
    red[tid] = lsum; __syncthreads();
    for (int st = 128; st > 0; st >>= 1) { if (tid < st) red[tid] += red[tid+st]; __syncthreads(); }
    const float mean = red[0] * (1.0f/CS);
    __syncthreads();

    float lvar = 0.f;
    for (int d = tid; d < CS; d += 256) { float df = sg[d]-mean; lvar += df*df; }
    red[tid] = lvar; __syncthreads();
    for (int st = 128; st > 0; st >>= 1) { if (tid < st) red[tid] += red[tid+st]; __syncthreads(); }
    const float var = red[0] * (1.0f/CS);
    __syncthreads();

    const float inv = rsqrtf(var + 1e-5f);
    for (int d = tid; d < CS; d += 256)
        sgn_bf[(size_t)n*CS + d] = f2bf((sg[d]-mean)*inv*g_gamma[d] + g_beta[d]);
}

// ===========================================================================
// Kernel 1: projection GEMM + g-projection GEMM fused (branch on block).
// blocks [0,576): proj C[2048][1152]; blocks [576,600): ggemm 256x384.
// ===========================================================================
__global__ __launch_bounds__(256) void proj_ggemm_kernel(
    const ushort_t* __restrict__ s_bf, const ushort_t* __restrict__ wt_bf,
    const float* __restrict__ pbias,
    const ushort_t* __restrict__ sgn_bf, const ushort_t* __restrict__ wtg_bf,
    const float* __restrict__ gbias,
    float* __restrict__ qo, float* __restrict__ ko, float* __restrict__ vo,
    float* __restrict__ rawp, float* __restrict__ gqo, float* __restrict__ gko)
{
    const int tid = threadIdx.x;
    const int wave = tid >> 6, lane = tid & 63;
    const int wrow = wave >> 1, wcol = wave & 1;
    const int qd = lane >> 4, lr = lane & 15;

    if (blockIdx.x < 576) {
        const int blk = blockIdx.x;
        const int rt = blk / 18, ct = blk - rt*18;
        const int r0 = rt * 64, c0 = ct * 64;
        const int m0 = r0 + wrow*32, n0 = c0 + wcol*32;

        f32x4 acc00 = {0,0,0,0}, acc01 = {0,0,0,0}, acc10 = {0,0,0,0}, acc11 = {0,0,0,0};

        const ushort_t* a0p = s_bf  + (size_t)(m0 + lr)*384 + qd*8;
        const ushort_t* a1p = a0p + 16*384;
        const ushort_t* b0p = wt_bf + (size_t)(n0 + lr)*384 + qd*8;
        const ushort_t* b1p = b0p + 16*384;

        #pragma unroll
        for (int kk = 0; kk < 384; kk += 32) {
            const bf16x8 a0 = *(const bf16x8*)(a0p + kk);
            const bf16x8 a1 = *(const bf16x8*)(a1p + kk);
            const bf16x8 b0 = *(const bf16x8*)(b0p + kk);
            const bf16x8 b1 = *(const bf16x8*)(b1p + kk);
            acc00 = __builtin_amdgcn_mfma_f32_16x16x32_bf16(a0, b0, acc00, 0, 0, 0);
            acc01 = __builtin_amdgcn_mfma_f32_16x16x32_bf16(a0, b1, acc01, 0, 0, 0);
            acc10 = __builtin_amdgcn_mfma_f32_16x16x32_bf16(a1, b0, acc10, 0, 0, 0);
            acc11 = __builtin_amdgcn_mfma_f32_16x16x32_bf16(a1, b1, acc11, 0, 0, 0);
        }

        #pragma unroll
        for (int mt = 0; mt < 2; ++mt) {
            #pragma unroll
            for (int nt = 0; nt < 2; ++nt) {
                const f32x4 av = (mt==0) ? (nt==0 ? acc00 : acc01)
                                         : (nt==0 ? acc10 : acc11);
                const int col = n0 + nt*16 + lr;
                const float bb = pbias[col];
                #pragma unroll
                for (int reg = 0; reg < 4; ++reg) {
                    const int row = m0 + mt*16 + qd*4 + reg;
                    const float val = av[reg] + bb;
                    if (col < 192) {
                        qo[(size_t)row*192 + col] = val;
                    } else if (col < 576) {
                        const int lc = col - 192, h = lc >> 5, rm = lc & 31;
                        if (rm < 16) ko[(size_t)row*192 + h*16 + rm] = val;
                        else         vo[(size_t)row*192 + h*16 + rm - 16] = val;
                    } else {
                        rawp[(size_t)row*576 + col - 576] = val;
                    }
                }
            }
        }
        return;
    }

    // ---- ggemm branch ----
    const int blk = blockIdx.x - 576;
    const int rt = blk / 6, ct = blk - rt*6;
    const int r0 = rt * 64, c0 = ct * 64;
    const int m0 = r0 + wrow*32, n0 = c0 + wcol*32;

    f32x4 acc00 = {0,0,0,0}, acc01 = {0,0,0,0}, acc10 = {0,0,0,0}, acc11 = {0,0,0,0};

    const ushort_t* a0p = sgn_bf + (size_t)(m0 + lr)*384 + qd*8;
    const ushort_t* a1p = a0p + 16*384;
    const ushort_t* b0p = wtg_bf + (size_t)(n0 + lr)*384 + qd*8;
    const ushort_t* b1p = b0p + 16*384;

    #pragma unroll
    for (int kk = 0; kk < 384; kk += 32) {
        const bf16x8 a0 = *(const bf16x8*)(a0p + kk);
        const bf16x8 a1 = *(const bf16x8*)(a1p + kk);
        const bf16x8 b0 = *(const bf16x8*)(b0p + kk);
        const bf16x8 b1 = *(const bf16x8*)(b1p + kk);
        acc00 = __builtin_amdgcn_mfma_f32_16x16x32_bf16(a0, b0, acc00, 0, 0, 0);
        acc01 = __builtin_amdgcn_mfma_f32_16x16x32_bf16(a0, b1, acc01, 0, 0, 0);
        acc10 = __builtin_amdgcn_mfma_f32_16x16x32_bf16(a1, b0, acc10, 0, 0, 0);
        acc11 = __builtin_amdgcn_mfma_f32_16x16x32_bf16(a1, b1, acc11, 0, 0, 0);
    }

    #pragma unroll
    for (int mt = 0; mt < 2; ++mt) {
        #pragma unroll
        for (int nt = 0; nt < 2; ++nt) {
            const f32x4 av = (mt==0) ? (nt==0 ? acc00 : acc01)
                                     : (nt==0 ? acc10 : acc11);
            const int col = n0 + nt*16 + lr;
            const float bb = gbias[col];
            #pragma unroll
            for (int reg = 0; reg < 4; ++reg) {
                const int row = m0 + mt*16 + qd*4 + reg;
                const float val = av[reg] + bb;
                if (col < 192) gqo[(size_t)row*192 + col]       = val;
                else           gko[(size_t)row*192 + col - 192] = val;
            }
        }
    }
}

// ===========================================================================
// Kernel 2: attention via MFMA; rigid transform of q/k points applied INLINE
// from rawp (pt_transform kernel eliminated).
// ===========================================================================
#define BSTR 104
__global__ __launch_bounds__(256) void attn_mfma_kernel(
    const float* __restrict__ q, const float* __restrict__ k,
    const float* __restrict__ rawp, const float* __restrict__ rot,
    const float* __restrict__ g_q, const float* __restrict__ g_k,
    const float* __restrict__ trans, const float* __restrict__ mask,
    const float* __restrict__ head_weights, const float* __restrict__ wdist,
    const float* __restrict__ bdist, float* __restrict__ a_out)
{
    const int blk  = blockIdx.x;
    const int qtr  = blk & 3;
    const int ch   = blk >> 2;
    const int h    = ch % HNUM;
    const int c    = ch / HNUM;
    const int i0   = qtr * 64;
    const int tid  = threadIdx.x;

    __shared__ ushort_t Bsh[256*BSTR];   // 53.2 KB
    __shared__ ushort_t Ash[64*BSTR];    // 13.3 KB
    __shared__ float dsh[7*256];         // 7 KB
    __shared__ float msh[256];
    __shared__ float kn_sh[256];
    __shared__ float qn_sh[64];
    __shared__ float wdsh[12], bdsh[12];
    __shared__ float cpart[96];
    __shared__ float censh[3];

    msh[tid] = mask[c*NRES + tid];
    if (tid < 12) { wdsh[tid] = wdist[tid]; bdsh[tid] = bdist[tid]; }

    if (tid < 96) {
        const int coord = tid % 3, chunk = tid / 3;
        float sv = 0.f;
        for (int e = 0; e < 8; ++e)
            sv += trans[((size_t)c*NRES + chunk*8 + e)*3 + coord];
        cpart[tid] = sv;
    }
    __syncthreads();
    if (tid < 3) {
        float sv = 0.f;
        for (int e = 0; e < 32; ++e) sv += cpart[e*3 + tid];
        censh[tid] = sv * (1.0f/256.0f);
    }
    __syncthreads();

    const float s54   = 0.13608276348795434f;  // sqrt(1/54)
    const float scale = 0.14433756729740643f;  // sqrt(1/48)
    const float hwv = 0.5f * logf(1.0f + expf(head_weights[h])) * s54;
    const float sh  = sqrtf(2.0f * hwv);
    const float cx = censh[0], cy = censh[1], cz = censh[2];

    // --- build B rows (one j per thread) with inline k-point transform ---
    {
        const int j = tid;
        const int grow = c*NRES + j;
        const float4* kr4 = (const float4*)(k   + (size_t)grow*192 + h*16);
        const float4* gk4 = (const float4*)(g_k + (size_t)j*192 + h*16);
        ushort_t* br = &Bsh[j*BSTR];
        #pragma unroll
        for (int e4 = 0; e4 < 4; ++e4) {
            const float4 w = kr4[e4];
            br[e4*4+0] = f2bf(w.x); br[e4*4+1] = f2bf(w.y);
            br[e4*4+2] = f2bf(w.z); br[e4*4+3] = f2bf(w.w);
        }
        #pragma unroll
        for (int e4 = 0; e4 < 4; ++e4) {
            const float4 w = gk4[e4];
            br[16+e4*4+0] = f2bf(w.x); br[16+e4*4+1] = f2bf(w.y);
            br[16+e4*4+2] = f2bf(w.z); br[16+e4*4+3] = f2bf(w.w);
        }
        // k_pts: rawp kvp block, pp=0..3 of head h
        const float* base = rawp + (size_t)grow*576;
        const float4 rx = *(const float4*)(base + 144 + h*12);
        const float4 ry = *(const float4*)(base + 288 + h*12);
        const float4 rz = *(const float4*)(base + 432 + h*12);
        const float* R = rot + (size_t)grow*9;
        const float* T = trans + (size_t)grow*3;
        const float R0=R[0],R1=R[1],R2=R[2],R3=R[3],R4=R[4],R5=R[5],R6=R[6],R7=R[7],R8=R[8];
        const float Tx=T[0]-cx, Ty=T[1]-cy, Tz=T[2]-cz;
        const float xs[4] = {rx.x, rx.y, rx.z, rx.w};
        const float ys[4] = {ry.x, ry.y, ry.z, ry.w};
        const float zs[4] = {rz.x, rz.y, rz.z, rz.w};
        float kn = 0.f;
        #pragma unroll
        for (int pp = 0; pp < 4; ++pp) {
            const float x = xs[pp], y = ys[pp], z = zs[pp];
            const float pv[3] = { R0*x + R1*y + R2*z + Tx,
                                  R3*x + R4*y + R5*z + Ty,
                                  R6*x + R7*y + R8*z + Tz };
            #pragma unroll
            for (int cc = 0; cc < 3; ++cc) {
                const int e = pp*3 + cc;
                kn += pv[cc]*pv[cc];
                const float sp = sh * pv[cc];
                const unsigned int u = __float_as_uint(sp);
                const float hif = __uint_as_float(u & 0xFFFF0000u);
                const ushort_t hi = (ushort_t)(u >> 16);
                br[32+e] = hi;
                br[44+e] = (ushort_t)(__float_as_uint(sp - hif) >> 16);
                br[56+e] = hi;
            }
        }
        #pragma unroll
        for (int e = 68; e < 96; ++e) br[e] = 0;
        kn_sh[j] = hwv * kn;
    }

    // --- build A rows (threads 0..63) with inline q-point transform ---
    if (tid < 64) {
        const int il = i0 + tid;
        const int grow = c*NRES + il;
        const float4* qr4 = (const float4*)(q   + (size_t)grow*192 + h*16);
        const float4* gq4 = (const float4*)(g_q + (size_t)il*192 + h*16);
        ushort_t* ar = &Ash[tid*BSTR];
        #pragma unroll
        for (int e4 = 0; e4 < 4; ++e4) {
            const float4 w = qr4[e4];
            ar[e4*4+0] = f2bf(scale*w.x); ar[e4*4+1] = f2bf(scale*w.y);
            ar[e4*4+2] = f2bf(scale*w.z); ar[e4*4+3] = f2bf(scale*w.w);
        }
        #pragma unroll
        for (int e4 = 0; e4 < 4; ++e4) {
            const float4 w = gq4[e4];
            ar[16+e4*4+0] = f2bf(scale*w.x); ar[16+e4*4+1] = f2bf(scale*w.y);
            ar[16+e4*4+2] = f2bf(scale*w.z); ar[16+e4*4+3] = f2bf(scale*w.w);
        }
        // q_pts: rawp qp block, pp=0..3 of head h
        const float* base = rawp + (size_t)grow*576;
        const float4 rx = *(const float4*)(base + h*4);
        const float4 ry = *(const float4*)(base + 48 + h*4);
        const float4 rz = *(const float4*)(base + 96 + h*4);
        const float* R = rot + (size_t)grow*9;
        const float* T = trans + (size_t)grow*3;
        const float R0=R[0],R1=R[1],R2=R[2],R3=R[3],R4=R[4],R5=R[5],R6=R[6],R7=R[7],R8=R[8];
        const float Tx=T[0]-cx, Ty=T[1]-cy, Tz=T[2]-cz;
        const float xs[4] = {rx.x, rx.y, rx.z, rx.w};
        const float ys[4] = {ry.x, ry.y, ry.z, ry.w};
        const float zs[4] = {rz.x, rz.y, rz.z, rz.w};
        float qn = 0.f;
        #pragma unroll
        for (int pp = 0; pp < 4; ++pp) {
            const float x = xs[pp], y = ys[pp], z = zs[pp];
            const float pv[3] = { R0*x + R1*y + R2*z + Tx,
                                  R3*x + R4*y + R5*z + Ty,
                                  R6*x + R7*y + R8*z + Tz };
            #pragma unroll
            for (int cc = 0; cc < 3; ++cc) {
                const int e = pp*3 + cc;
                qn += pv[cc]*pv[cc];
                const float sp = sh * pv[cc];
                const unsigned int u = __float_as_uint(sp);
                const float hif = __uint_as_float(u & 0xFFFF0000u);
                const ushort_t hi = (ushort_t)(u >> 16);
                ar[32+e] = hi;
                ar[44+e] = hi;
                ar[56+e] = (ushort_t)(__float_as_uint(sp - hif) >> 16);
            }
        }
        #pragma unroll
        for (int e = 68; e < 96; ++e) ar[e] = 0;
        qn_sh[tid] = hwv * qn;
    }

    // --- dist LUT for this (h, i-quarter): NI <= 7 ---
    const int Fmin = h*65536 + i0*256;
    const int iibase = Fmin / 3072;
    const int NI = (Fmin + 63*256 + 255)/3072 - iibase + 1;
    const float* tch = trans + (size_t)c*768;
    for (int idx = tid; idx < NI*256; idx += 256) {
        const int e = idx >> 8, jj = idx & 255;
        const int ia = iibase + e;
        const float dx = tch[ia*3+0] - tch[jj*3+0];
        const float dy = tch[ia*3+1] - tch[jj*3+1];
        const float dz = tch[ia*3+2] - tch[jj*3+2];
        dsh[idx] = sqrtf(dx*dx + dy*dy + dz*dz);
    }
    __syncthreads();

    // --- main: wave handles 16 rows ---
    const int wave = tid >> 6, lane = tid & 63;
    const int qd = lane >> 4, lr = lane & 15;
    const int m0 = wave*16;

    const ushort_t* ap = &Ash[(m0 + lr)*BSTR + qd*8];
    const bf16x8 af0 = *(const bf16x8*)(ap);
    const bf16x8 af1 = *(const bf16x8*)(ap + 32);
    const bf16x8 af2 = *(const bf16x8*)(ap + 64);

    f32x4 acc[16];
    #pragma unroll
    for (int t = 0; t < 16; ++t) {
        const ushort_t* bp = &Bsh[(t*16 + lr)*BSTR + qd*8];
        f32x4 a = {0.f,0.f,0.f,0.f};
        a = __builtin_amdgcn_mfma_f32_16x16x32_bf16(af0, *(const bf16x8*)(bp),      a, 0, 0, 0);
        a = __builtin_amdgcn_mfma_f32_16x16x32_bf16(af1, *(const bf16x8*)(bp + 32), a, 0, 0, 0);
        a = __builtin_amdgcn_mfma_f32_16x16x32_bf16(af2, *(const bf16x8*)(bp + 64), a, 0, 0, 0);
        acc[t] = a;
    }

    const int ibase = m0 + qd*4;
    float qn_r[4], mb_r[4];
    int F0_[4];
    #pragma unroll
    for (int r = 0; r < 4; ++r) {
        const int il = i0 + ibase + r;
        qn_r[r] = qn_sh[ibase + r];
        mb_r[r] = 100000.0f * msh[il];
        F0_[r]  = h*65536 + il*256;
    }

    float mx[4] = {-1e30f,-1e30f,-1e30f,-1e30f};
    #pragma unroll
    for (int t = 0; t < 16; ++t) {
        const int j = t*16 + lr;
        const float knj = kn_sh[j];
        const float mj  = msh[j];
        #pragma unroll
        for (int r = 0; r < 4; ++r) {
            const unsigned int f = (unsigned int)(F0_[r] + j);
            const unsigned int p = f / 12u;
            const int ho = (int)(f - p*12u);
            const int ii = (int)(p >> 8);
            const int jj = (int)(p & 255u);
            const float dist = dsh[(ii - iibase)*256 + jj];
            const float db = dist*wdsh[ho] + bdsh[ho];
            const float lv = acc[t][r] - qn_r[r] - knj
                           + (mb_r[r]*mj - 100000.0f) + db;
            acc[t][r] = lv;
            mx[r] = fmaxf(mx[r], lv);
        }
    }
    #pragma unroll
    for (int r = 0; r < 4; ++r) {
        #pragma unroll
        for (int off = 1; off < 16; off <<= 1)
            mx[r] = fmaxf(mx[r], __shfl_xor(mx[r], off));
    }
    float sm[4] = {0.f,0.f,0.f,0.f};
    #pragma unroll
    for (int t = 0; t < 16; ++t) {
        #pragma unroll
        for (int r = 0; r < 4; ++r) {
            const float e = __expf(acc[t][r] - mx[r]);
            acc[t][r] = e;
            sm[r] += e;
        }
    }
    #pragma unroll
    for (int r = 0; r < 4; ++r) {
        #pragma unroll
        for (int off = 1; off < 16; off <<= 1)
            sm[r] += __shfl_xor(sm[r], off);
        sm[r] = 1.0f / sm[r];
    }
    float* dst = a_out + ((size_t)ch*NRES + (i0 + ibase))*NRES;
    #pragma unroll
    for (int t = 0; t < 16; ++t) {
        #pragma unroll
        for (int r = 0; r < 4; ++r)
            dst[(size_t)r*NRES + t*16 + lr] = acc[t][r]*sm[r];
    }
}

// ===========================================================================
// Kernel 3: o / o_pt via MFMA; v-point rigid transform applied INLINE.
// ===========================================================================
#define ASTRB 264
__global__ __launch_bounds__(256) void out_feat_mfma_kernel(
    const float* __restrict__ a, const float* __restrict__ v,
    const float* __restrict__ rawp, const float* __restrict__ rot,
    const float* __restrict__ trans,
    ushort_t* __restrict__ feat_hi, ushort_t* __restrict__ feat_lo)
{
    const int blk = blockIdx.x;
    const int qtr = blk & 3;
    const int ch  = blk >> 2;
    const int h   = ch % HNUM;
    const int c   = ch / HNUM;
    const int i0  = qtr * 64;
    const int tid = threadIdx.x;

    __shared__ ushort_t Bt[64*ASTRB];
    __shared__ float opt[64*25];
    __shared__ float osh[64*17];
    __shared__ float cpart[96];
    __shared__ float censh[3];

    if (tid < 96) {
        const int coord = tid % 3, chunk = tid / 3;
        float sv = 0.f;
        for (int e = 0; e < 8; ++e)
            sv += trans[((size_t)c*NRES + chunk*8 + e)*3 + coord];
        cpart[tid] = sv;
    }
    __syncthreads();
    if (tid < 3) {
        float sv = 0.f;
        for (int e = 0; e < 32; ++e) sv += cpart[e*3 + tid];
        censh[tid] = sv * (1.0f/256.0f);
    }
    __syncthreads();
    const float cx = censh[0], cy = censh[1], cz = censh[2];

    // stage B: thread j builds column j (v + inline-transformed v_pts hi/lo)
    {
        const int j = tid;
        const int grow = c*NRES + j;
        const float4* vr = (const float4*)(v + (size_t)grow*192 + h*16);
        #pragma unroll
        for (int e4 = 0; e4 < 4; ++e4) {
            const float4 w = vr[e4];
            Bt[(e4*4+0)*ASTRB + j] = f2bf(w.x);
            Bt[(e4*4+1)*ASTRB + j] = f2bf(w.y);
            Bt[(e4*4+2)*ASTRB + j] = f2bf(w.z);
            Bt[(e4*4+3)*ASTRB + j] = f2bf(w.w);
        }
        // v_pts: rawp kvp block, pp=4..11 of head h
        const float* base = rawp + (size_t)grow*576;
        const float4 rx0 = *(const float4*)(base + 144 + h*12 + 4);
        const float4 rx1 = *(const float4*)(base + 144 + h*12 + 8);
        const float4 ry0 = *(const float4*)(base + 288 + h*12 + 4);
        const float4 ry1 = *(const float4*)(base + 288 + h*12 + 8);
        const float4 rz0 = *(const float4*)(base + 432 + h*12 + 4);
        const float4 rz1 = *(const float4*)(base + 432 + h*12 + 8);
        const float* R = rot + (size_t)grow*9;
        const float* T = trans + (size_t)grow*3;
        const float R0=R[0],R1=R[1],R2=R[2],R3=R[3],R4=R[4],R5=R[5],R6=R[6],R7=R[7],R8=R[8];
        const float Tx=T[0]-cx, Ty=T[1]-cy, Tz=T[2]-cz;
        const float xs[8] = {rx0.x,rx0.y,rx0.z,rx0.w, rx1.x,rx1.y,rx1.z,rx1.w};
        const float ys[8] = {ry0.x,ry0.y,ry0.z,ry0.w, ry1.x,ry1.y,ry1.z,ry1.w};
        const float zs[8] = {rz0.x,rz0.y,rz0.z,rz0.w, rz1.x,rz1.y,rz1.z,rz1.w};
        #pragma unroll
        for (int pp = 0; pp < 8; ++pp) {
            const float x = xs[pp], y = ys[pp], z = zs[pp];
            const float pv[3] = { R0*x + R1*y + R2*z + Tx,
                                  R3*x + R4*y + R5*z + Ty,
                                  R6*x + R7*y + R8*z + Tz };
            #pragma unroll
            for (int cc = 0; cc < 3; ++cc) {
                const int e = pp*3 + cc;
                const float vp = pv[cc];
                const unsigned int u = __float_as_uint(vp);
                const float hif = __uint_as_float(u & 0xFFFF0000u);
                Bt[(16+e)*ASTRB + j] = (ushort_t)(u >> 16);
                Bt[(40+e)*ASTRB + j] = (ushort_t)(__float_as_uint(vp - hif) >> 16);
            }
        }
    }
    __syncthreads();

    const int wave = tid >> 6, lane = tid & 63;
    const int qd = lane >> 4, lr = lane & 15;
    const int m0 = wave*16;

    const float* arow = a + ((size_t)ch*NRES + i0 + m0 + lr)*NRES;

    f32x4 acc[4] = {{0,0,0,0},{0,0,0,0},{0,0,0,0},{0,0,0,0}};
    #pragma unroll
    for (int kk = 0; kk < 256; kk += 32) {
        const float4 a0 = *(const float4*)(arow + qd*8 + kk);
        const float4 a1 = *(const float4*)(arow + qd*8 + kk + 4);
        const float av[8] = {a0.x,a0.y,a0.z,a0.w,a1.x,a1.y,a1.z,a1.w};
        bf16x8 ahi, alo;
        #pragma unroll
        for (int e = 0; e < 8; ++e) {
            const unsigned int u = __float_as_uint(av[e]);
            const float hif = __uint_as_float(u & 0xFFFF0000u);
            ((ushort_t*)&ahi)[e] = (ushort_t)(u >> 16);
            ((ushort_t*)&alo)[e] = (ushort_t)(__float_as_uint(av[e] - hif) >> 16);
        }
        #pragma unroll
        for (int t = 0; t < 4; ++t) {
            const bf16x8 bf = *(const bf16x8*)&Bt[(t*16 + lr)*ASTRB + qd*8 + kk];
            acc[t] = __builtin_amdgcn_mfma_f32_16x16x32_bf16(ahi, bf, acc[t], 0, 0, 0);
            acc[t] = __builtin_amdgcn_mfma_f32_16x16x32_bf16(alo, bf, acc[t], 0, 0, 0);
        }
    }

    #pragma unroll
    for (int reg = 0; reg < 4; ++reg) {
        const int row_l = m0 + qd*4 + reg;
        osh[row_l*17 + lr] = acc[0][reg];
        opt[row_l*25 + lr] = acc[1][reg];
    }
    #pragma unroll
    for (int reg = 0; reg < 4; ++reg) {
        const int row_l = m0 + qd*4 + reg;
        if (lr < 8) opt[row_l*25 + 16 + lr] = acc[2][reg];
        else        opt[row_l*25 + (lr-8)] += acc[2][reg];
    }
    #pragma unroll
    for (int reg = 0; reg < 4; ++reg) {
        const int row_l = m0 + qd*4 + reg;
        opt[row_l*25 + 8 + lr] += acc[3][reg];
    }
    __syncthreads();

    #pragma unroll
    for (int it = 0; it < 4; ++it) {
        const int idx = it*256 + tid;
        const int row_l = idx >> 4, e = idx & 15;
        const int grow = c*NRES + i0 + row_l;
        const float val = osh[row_l*17 + e];
        const unsigned int u = __float_as_uint(val);
        const float hif = __uint_as_float(u & 0xFFFF0000u);
        feat_hi[(size_t)grow*576 + h*16 + e] = (ushort_t)(u >> 16);
        feat_lo[(size_t)grow*576 + h*16 + e] = (ushort_t)(__float_as_uint(val - hif) >> 16);
    }
    #pragma unroll
    for (int it = 0; it < 2; ++it) {
        const int idx = it*256 + tid;
        const int row_l = idx >> 3, p = idx & 7;
        const int grow = c*NRES + i0 + row_l;
        const float* R = rot + (size_t)grow*9;
        const float* T = trans + (size_t)grow*3;
        const float x = opt[row_l*25 + p*3+0] + cx - T[0];
        const float y = opt[row_l*25 + p*3+1] + cy - T[1];
        const float z = opt[row_l*25 + p*3+2] + cz - T[2];
        const float rx = R[0]*x + R[3]*y + R[6]*z;
        const float ry = R[1]*x + R[4]*y + R[7]*z;
        const float rz = R[2]*x + R[5]*y + R[8]*z;
        const float nm = sqrtf(rx*rx + ry*ry + rz*rz + 1e-8f);
        const float vals[4] = {rx, ry, rz, nm};
        #pragma unroll
        for (int sl = 0; sl < 4; ++sl) {
            const int col = 192 + sl*96 + h*8 + p;
            const float vv = vals[sl];
            const unsigned int u = __float_as_uint(vv);
            const float hif = __uint_as_float(u & 0xFFFF0000u);
            feat_hi[(size_t)grow*576 + col] = (ushort_t)(u >> 16);
            feat_lo[(size_t)grow*576 + col] = (ushort_t)(__float_as_uint(vv - hif) >> 16);
        }
    }
}

// ===========================================================================
// Kernel 4: out0 = feat @ wout + bout via MFMA (3-term hi/lo product).
// ===========================================================================
__global__ __launch_bounds__(256) void out_gemm_mfma_kernel(
    const ushort_t* __restrict__ feat_hi, const ushort_t* __restrict__ feat_lo,
    const ushort_t* __restrict__ wo_hi, const ushort_t* __restrict__ wo_lo,
    const float* __restrict__ bout, float* __restrict__ out0)
{
    const int blk = blockIdx.x;
    const int rt = blk / 6, ct = blk - rt*6;
    const int r0 = rt * 64, c0 = ct * 64;
    const int tid = threadIdx.x;
    const int wave = tid >> 6, lane = tid & 63;
    const int wrow = wave >> 1, wcol = wave & 1;
    const int m0 = r0 + wrow*32, n0 = c0 + wcol*32;
    const int qd = lane >> 4, lr = lane & 15;

    f32x4 acc[2][2] = {{{0,0,0,0},{0,0,0,0}},{{0,0,0,0},{0,0,0,0}}};

    const ushort_t* ah0 = feat_hi + (size_t)(m0 + lr)*576 + qd*8;
    const ushort_t* ah1 = ah0 + 16*576;
    const ushort_t* al0 = feat_lo + (size_t)(m0 + lr)*576 + qd*8;
    const ushort_t* al1 = al0 + 16*576;
    const ushort_t* bh0 = wo_hi + (size_t)(n0 + lr)*576 + qd*8;
    const ushort_t* bh1 = bh0 + 16*576;
    const ushort_t* bl0 = wo_lo + (size_t)(n0 + lr)*576 + qd*8;
    const ushort_t* bl1 = bl0 + 16*576;

    for (int kk = 0; kk < 576; kk += 32) {
        const bf16x8 fh0 = *(const bf16x8*)(ah0 + kk);
        const bf16x8 fh1 = *(const bf16x8*)(ah1 + kk);
        const bf16x8 fl0 = *(const bf16x8*)(al0 + kk);
        const bf16x8 fl1 = *(const bf16x8*)(al1 + kk);
        const bf16x8 wh0 = *(const bf16x8*)(bh0 + kk);
        const bf16x8 wh1 = *(const bf16x8*)(bh1 + kk);
        const bf16x8 wl0 = *(const bf16x8*)(bl0 + kk);
        const bf16x8 wl1 = *(const bf16x8*)(bl1 + kk);
        acc[0][0] = __builtin_amdgcn_mfma_f32_16x16x32_bf16(fh0, wh0, acc[0][0], 0, 0, 0);
        acc[0][1] = __builtin_amdgcn_mfma_f32_16x16x32_bf16(fh0, wh1, acc[0][1], 0, 0, 0);
        acc[1][0] = __builtin_amdgcn_mfma_f32_16x16x32_bf16(fh1, wh0, acc[1][0], 0, 0, 0);
        acc[1][1] = __builtin_amdgcn_mfma_f32_16x16x32_bf16(fh1, wh1, acc[1][1], 0, 0, 0);
        acc[0][0] = __builtin_amdgcn_mfma_f32_16x16x32_bf16(fl0, wh0, acc[0][0], 0, 0, 0);
        acc[0][1] = __builtin_amdgcn_mfma_f32_16x16x32_bf16(fl0, wh1, acc[0][1], 0, 0, 0);
        acc[1][0] = __builtin_amdgcn_mfma_f32_16x16x32_bf16(fl1, wh0, acc[1][0], 0, 0, 0);
        acc[1][1] = __builtin_amdgcn_mfma_f32_16x16x32_bf16(fl1, wh1, acc[1][1], 0, 0, 0);
        acc[0][0] = __builtin_amdgcn_mfma_f32_16x16x32_bf16(fh0, wl0, acc[0][0], 0, 0, 0);
        acc[0][1] = __builtin_amdgcn_mfma_f32_16x16x32_bf16(fh0, wl1, acc[0][1], 0, 0, 0);
        acc[1][0] = __builtin_amdgcn_mfma_f32_16x16x32_bf16(fh1, wl0, acc[1][0], 0, 0, 0);
        acc[1][1] = __builtin_amdgcn_mfma_f32_16x16x32_bf16(fh1, wl1, acc[1][1], 0, 0, 0);
    }

    #pragma unroll
    for (int mt = 0; mt < 2; ++mt) {
        #pragma unroll
        for (int nt = 0; nt < 2; ++nt) {
            const int col = n0 + nt*16 + lr;
            const float bb = bout[col];
            #pragma unroll
            for (int reg = 0; reg < 4; ++reg) {
                const int row = m0 + mt*16 + qd*4 + reg;
                out0[(size_t)row*CS + col] = acc[mt][nt][reg] + bb;
            }
        }
    }
}

// ===========================================================================
extern "C" void kernel_launch(void* const* d_in, const int* in_sizes, int n_in,
                              void* d_out, int out_size, void* d_ws, size_t ws_size,
                              hipStream_t stream)
{
    const float* s     = (const float*)d_in[0];
    const float* rot   = (const float*)d_in[2];
    const float* trans = (const float*)d_in[3];
    const float* mask  = (const float*)d_in[4];
    const float* wq    = (const float*)d_in[5];
    const float* bq    = (const float*)d_in[6];
    const float* wkv   = (const float*)d_in[7];
    const float* bkv   = (const float*)d_in[8];
    const float* g_gamma = (const float*)d_in[9];
    const float* g_beta  = (const float*)d_in[10];
    const float* wgq   = (const float*)d_in[11];
    const float* bgq   = (const float*)d_in[12];
    const float* wgk   = (const float*)d_in[13];
    const float* bgk   = (const float*)d_in[14];
    const float* wqp   = (const float*)d_in[15];
    const float* bqp   = (const float*)d_in[16];
    const float* wkvp  = (const float*)d_in[17];
    const float* bkvp  = (const float*)d_in[18];
    const float* head_weights = (const float*)d_in[19];
    const float* wdist = (const float*)d_in[20];
    const float* bdist = (const float*)d_in[21];
    const float* wout  = (const float*)d_in[22];
    const float* bout  = (const float*)d_in[23];

    float* ws      = (float*)d_ws;
    float* q_buf   = ws + 0;          // 393216
    float* gq_buf  = ws + 983040;     // 49152
    float* gk_buf  = ws + 1032192;    // 49152
    float* k_buf   = ws + 1081344;    // 393216
    float* v_buf   = ws + 1474560;    // 393216
    ushort_t* sgn_bf  = (ushort_t*)(ws + 1867776); // 98304 bf16
    ushort_t* feat_hi = (ushort_t*)(ws + 2457600); // 1179648 bf16
    ushort_t* feat_lo = (ushort_t*)(ws + 3047424); // 1179648 bf16
    ushort_t* wo_hi   = (ushort_t*)(ws + 3637248); // 221184 bf16
    ushort_t* wo_lo   = (ushort_t*)(ws + 3747840); // 221184 bf16
    float*    rawp    = ws + 4194304;              // 1179648 floats (private)

    float* out0  = (float*)d_out;       // 786432
    float* a_out = out0 + 786432;       // 6291456
    // overlays inside a_out (dead before attn writes):
    ushort_t* s_bf   = (ushort_t*)(a_out);                 // 786432 bf16
    ushort_t* wt_bf  = (ushort_t*)(a_out + 393216);        // 442368 bf16
    ushort_t* wtg_bf = (ushort_t*)(a_out + 614400);        // 147456 bf16
    float*    pbias  = a_out + 688128;                     // 1152
    float*    gbias  = a_out + 689280;                     // 384

    convert_ln_kernel<<<6502, 256, 0, stream>>>(s, wq, bq, wkv, bkv, wqp, bqp,
                                                wkvp, bkvp, wgq, bgq, wgk, bgk,
                                                wout, g_gamma, g_beta,
                                                s_bf, wt_bf, wtg_bf, pbias, gbias,
                                                wo_hi, wo_lo, sgn_bf);
    proj_ggemm_kernel<<<600, 256, 0, stream>>>(s_bf, wt_bf, pbias,
                                               sgn_bf, wtg_bf, gbias,
                                               q_buf, k_buf, v_buf, rawp,
                                               gq_buf, gk_buf);
    attn_mfma_kernel<<<384, 256, 0, stream>>>(q_buf, k_buf, rawp, rot,
                                              gq_buf, gk_buf, trans, mask,
                                              head_weights, wdist, bdist, a_out);
    out_feat_mfma_kernel<<<384, 256, 0, stream>>>(a_out, v_buf, rawp, rot, trans,
                                                  feat_hi, feat_lo);
    out_gemm_mfma_kernel<<<192, 256, 0, stream>>>(feat_hi, feat_lo, wo_hi, wo_lo,
                                                  bout, out0);
}

// Round 11
// 197.762 us; speedup vs baseline: 1.6977x; 1.0135x over previous
//
#include <hip/hip_runtime.h>
#include <math.h>

#define NRES 256
#define CDIM 8
#define HNUM 12
#define CS   384

typedef __attribute__((ext_vector_type(8))) short bf16x8;
typedef __attribute__((ext_vector_type(4))) float f32x4;
typedef unsigned short ushort_t;

static __device__ __forceinline__ unsigned short f2bf(float x) {
    unsigned int u = __float_as_uint(x);
    unsigned int r = (u + 0x7fffu + ((u >> 16) & 1u)) >> 16;
    return (unsigned short)r;
}

// ===========================================================================
// Kernel 0: conversions (LDS-tiled transposes) + bias packing + LayerNorm.
// Block map: [0,768) s->bf16 | [768,876) wt tiles | [876,912) wtg tiles |
//            [912,966) wo hi/lo tiles | [966] biases | [967,1223) LN rows
// ===========================================================================
#define TSTR 66   // ushort tile stride (33 words: conflict-free on write)
#define FSTR 65   // float tile stride (conflict-free on read-out)
__global__ __launch_bounds__(256) void convert_ln_kernel(
    const float* __restrict__ s,
    const float* __restrict__ wq, const float* __restrict__ bq,
    const float* __restrict__ wkv, const float* __restrict__ bkv,
    const float* __restrict__ wqp, const float* __restrict__ bqp,
    const float* __restrict__ wkvp, const float* __restrict__ bkvp,
    const float* __restrict__ wgq, const float* __restrict__ bgq,
    const float* __restrict__ wgk, const float* __restrict__ bgk,
    const float* __restrict__ wout,
    const float* __restrict__ g_gamma, const float* __restrict__ g_beta,
    ushort_t* __restrict__ s_bf, ushort_t* __restrict__ wt_bf,
    ushort_t* __restrict__ wtg_bf, float* __restrict__ pbias,
    float* __restrict__ gbias,
    ushort_t* __restrict__ wo_hi, ushort_t* __restrict__ wo_lo,
    ushort_t* __restrict__ sgn_bf)
{
    __shared__ ushort_t tile[64*TSTR];   // 8.4 KB
    __shared__ float ftile[64*FSTR];     // 16.6 KB
    __shared__ float sg[CS];
    __shared__ float red[256];
    const int tid = threadIdx.x;
    const int b = blockIdx.x;

    if (b < 768) {
        // ---- s -> bf16, vectorized ----
        const int idx = b*256 + tid;
        const float4 v = ((const float4*)s)[idx];
        unsigned int p0 = (unsigned int)f2bf(v.x) | ((unsigned int)f2bf(v.y) << 16);
        unsigned int p1 = (unsigned int)f2bf(v.z) | ((unsigned int)f2bf(v.w) << 16);
        uint2 pk; pk.x = p0; pk.y = p1;
        *(uint2*)&s_bf[(size_t)idx*4] = pk;
        return;
    }
    if (b < 876) {
        // ---- wt transpose: out wt_bf[vc][k], 64x64 tile ----
        const int t = b - 768;
        const int vt = t / 6, kt = t - vt*6;
        const int vc0 = vt*64, k0 = kt*64;
        #pragma unroll
        for (int it = 0; it < 16; ++it) {
            const int kk = it*4 + (tid >> 6);
            const int vv = tid & 63;
            const int vc = vc0 + vv;
            const float* w; int C, lc;
            if (vc < 192)      { w = wq;   C = 192; lc = vc; }
            else if (vc < 576) { w = wkv;  C = 384; lc = vc - 192; }
            else if (vc < 720) { w = wqp;  C = 144; lc = vc - 576; }
            else               { w = wkvp; C = 432; lc = vc - 720; }
            tile[vv*TSTR + kk] = f2bf(w[(size_t)(k0+kk)*C + lc]);
        }
        __syncthreads();
        #pragma unroll
        for (int it = 0; it < 16; ++it) {
            const int vv = it*4 + (tid >> 6);
            const int kk = tid & 63;
            wt_bf[(size_t)(vc0+vv)*384 + k0 + kk] = tile[vv*TSTR + kk];
        }
        return;
    }
    if (b < 912) {
        // ---- wtg transpose: out wtg_bf[vc][k] (vc<192 wgq else wgk) ----
        const int t = b - 876;
        const int vt = t / 6, kt = t - vt*6;
        const int vc0 = vt*64, k0 = kt*64;
        #pragma unroll
        for (int it = 0; it < 16; ++it) {
            const int kk = it*4 + (tid >> 6);
            const int vv = tid & 63;
            const int vc = vc0 + vv;
            const float val = (vc < 192) ? wgq[(size_t)(k0+kk)*192 + vc]
                                         : wgk[(size_t)(k0+kk)*192 + vc - 192];
            tile[vv*TSTR + kk] = f2bf(val);
        }
        __syncthreads();
        #pragma unroll
        for (int it = 0; it < 16; ++it) {
            const int vv = it*4 + (tid >> 6);
            const int kk = tid & 63;
            wtg_bf[(size_t)(vc0+vv)*384 + k0 + kk] = tile[vv*TSTR + kk];
        }
        return;
    }
    if (b < 966) {
        // ---- wout transpose hi/lo: out [n][k], src wout[k*384+n], K=576 ----
        const int t = b - 912;
        const int nt = t / 9, kt = t - nt*9;
        const int n0 = nt*64, k0 = kt*64;
        #pragma unroll
        for (int it = 0; it < 16; ++it) {
            const int kk = it*4 + (tid >> 6);
            const int nn = tid & 63;
            ftile[nn*FSTR + kk] = wout[(size_t)(k0+kk)*384 + n0 + nn];
        }
        __syncthreads();
        #pragma unroll
        for (int it = 0; it < 16; ++it) {
            const int nn = it*4 + (tid >> 6);
            const int kk = tid & 63;
            const float wv = ftile[nn*FSTR + kk];
            const unsigned int u = __float_as_uint(wv);
            const float hif = __uint_as_float(u & 0xFFFF0000u);
            wo_hi[(size_t)(n0+nn)*576 + k0 + kk] = (ushort_t)(u >> 16);
            wo_lo[(size_t)(n0+nn)*576 + k0 + kk] =
                (ushort_t)(__float_as_uint(wv - hif) >> 16);
        }
        return;
    }
    if (b == 966) {
        // ---- biases ----
        for (int i = tid; i < 1536; i += 256) {
            if (i < 1152) {
                float bb;
                if (i < 192)      bb = bq[i];
                else if (i < 576) bb = bkv[i - 192];
                else if (i < 720) bb = bqp[i - 576];
                else              bb = bkvp[i - 720];
                pbias[i] = bb;
            } else {
                const int g = i - 1152;
                gbias[g] = (g < 192) ? bgq[g] : bgk[g - 192];
            }
        }
        return;
    }

    // ---- LayerNorm branch: one block per n ----
    const int n = b - 967;
    for (int d = tid; d < CS; d += 256) {
        float acc = 0.f;
        for (int c = 0; c < CDIM; ++c) acc += s[((size_t)c*NRES+n)*CS + d];
        sg[d] = acc * (1.0f/CDIM);
    }
    __syncthreads();

    float lsum = 0.f;
    for (int d = tid; d < CS; d += 256) lsum += sg[d];
    red[tid] = lsum; __syncthreads();
    for (int st = 128; st > 0; st >>= 1) { if (tid < st) red[tid] += red[tid+st]; __syncthreads(); }
    const float mean = red[0] * (1.0f/CS);
    __syncthreads();

    float lvar = 0.f;
    for (int d = tid; d < CS; d += 256) { float df = sg[d]-mean; lvar += df*df; }
    red[tid] = lvar; __syncthreads();
    for (int st = 128; st > 0; st >>= 1) { if (tid < st) red[tid] += red[tid+st]; __syncthreads(); }
    const float var = red[0] * (1.0f/CS);
    __syncthreads();

    const float inv = rsqrtf(var + 1e-5f);
    for (int d = tid; d < CS; d += 256)
        sgn_bf[(size_t)n*CS + d] = f2bf((sg[d]-mean)*inv*g_gamma[d] + g_beta[d]);
}

// ===========================================================================
// Kernel 1: projection GEMM + g-projection GEMM fused (branch on block).
// ===========================================================================
__global__ __launch_bounds__(256) void proj_ggemm_kernel(
    const ushort_t* __restrict__ s_bf, const ushort_t* __restrict__ wt_bf,
    const float* __restrict__ pbias,
    const ushort_t* __restrict__ sgn_bf, const ushort_t* __restrict__ wtg_bf,
    const float* __restrict__ gbias,
    float* __restrict__ qo, float* __restrict__ ko, float* __restrict__ vo,
    float* __restrict__ rawp, float* __restrict__ gqo, float* __restrict__ gko)
{
    const int tid = threadIdx.x;
    const int wave = tid >> 6, lane = tid & 63;
    const int wrow = wave >> 1, wcol = wave & 1;
    const int qd = lane >> 4, lr = lane & 15;

    if (blockIdx.x < 576) {
        const int blk = blockIdx.x;
        const int rt = blk / 18, ct = blk - rt*18;
        const int r0 = rt * 64, c0 = ct * 64;
        const int m0 = r0 + wrow*32, n0 = c0 + wcol*32;

        f32x4 acc00 = {0,0,0,0}, acc01 = {0,0,0,0}, acc10 = {0,0,0,0}, acc11 = {0,0,0,0};

        const ushort_t* a0p = s_bf  + (size_t)(m0 + lr)*384 + qd*8;
        const ushort_t* a1p = a0p + 16*384;
        const ushort_t* b0p = wt_bf + (size_t)(n0 + lr)*384 + qd*8;
        const ushort_t* b1p = b0p + 16*384;

        #pragma unroll
        for (int kk = 0; kk < 384; kk += 32) {
            const bf16x8 a0 = *(const bf16x8*)(a0p + kk);
            const bf16x8 a1 = *(const bf16x8*)(a1p + kk);
            const bf16x8 b0 = *(const bf16x8*)(b0p + kk);
            const bf16x8 b1 = *(const bf16x8*)(b1p + kk);
            acc00 = __builtin_amdgcn_mfma_f32_16x16x32_bf16(a0, b0, acc00, 0, 0, 0);
            acc01 = __builtin_amdgcn_mfma_f32_16x16x32_bf16(a0, b1, acc01, 0, 0, 0);
            acc10 = __builtin_amdgcn_mfma_f32_16x16x32_bf16(a1, b0, acc10, 0, 0, 0);
            acc11 = __builtin_amdgcn_mfma_f32_16x16x32_bf16(a1, b1, acc11, 0, 0, 0);
        }

        #pragma unroll
        for (int mt = 0; mt < 2; ++mt) {
            #pragma unroll
            for (int nt = 0; nt < 2; ++nt) {
                const f32x4 av = (mt==0) ? (nt==0 ? acc00 : acc01)
                                         : (nt==0 ? acc10 : acc11);
                const int col = n0 + nt*16 + lr;
                const float bb = pbias[col];
                #pragma unroll
                for (int reg = 0; reg < 4; ++reg) {
                    const int row = m0 + mt*16 + qd*4 + reg;
                    const float val = av[reg] + bb;
                    if (col < 192) {
                        qo[(size_t)row*192 + col] = val;
                    } else if (col < 576) {
                        const int lc = col - 192, h = lc >> 5, rm = lc & 31;
                        if (rm < 16) ko[(size_t)row*192 + h*16 + rm] = val;
                        else         vo[(size_t)row*192 + h*16 + rm - 16] = val;
                    } else {
                        rawp[(size_t)row*576 + col - 576] = val;
                    }
                }
            }
        }
        return;
    }

    // ---- ggemm branch ----
    const int blk = blockIdx.x - 576;
    const int rt = blk / 6, ct = blk - rt*6;
    const int r0 = rt * 64, c0 = ct * 64;
    const int m0 = r0 + wrow*32, n0 = c0 + wcol*32;

    f32x4 acc00 = {0,0,0,0}, acc01 = {0,0,0,0}, acc10 = {0,0,0,0}, acc11 = {0,0,0,0};

    const ushort_t* a0p = sgn_bf + (size_t)(m0 + lr)*384 + qd*8;
    const ushort_t* a1p = a0p + 16*384;
    const ushort_t* b0p = wtg_bf + (size_t)(n0 + lr)*384 + qd*8;
    const ushort_t* b1p = b0p + 16*384;

    #pragma unroll
    for (int kk = 0; kk < 384; kk += 32) {
        const bf16x8 a0 = *(const bf16x8*)(a0p + kk);
        const bf16x8 a1 = *(const bf16x8*)(a1p + kk);
        const bf16x8 b0 = *(const bf16x8*)(b0p + kk);
        const bf16x8 b1 = *(const bf16x8*)(b1p + kk);
        acc00 = __builtin_amdgcn_mfma_f32_16x16x32_bf16(a0, b0, acc00, 0, 0, 0);
        acc01 = __builtin_amdgcn_mfma_f32_16x16x32_bf16(a0, b1, acc01, 0, 0, 0);
        acc10 = __builtin_amdgcn_mfma_f32_16x16x32_bf16(a1, b0, acc10, 0, 0, 0);
        acc11 = __builtin_amdgcn_mfma_f32_16x16x32_bf16(a1, b1, acc11, 0, 0, 0);
    }

    #pragma unroll
    for (int mt = 0; mt < 2; ++mt) {
        #pragma unroll
        for (int nt = 0; nt < 2; ++nt) {
            const f32x4 av = (mt==0) ? (nt==0 ? acc00 : acc01)
                                     : (nt==0 ? acc10 : acc11);
            const int col = n0 + nt*16 + lr;
            const float bb = gbias[col];
            #pragma unroll
            for (int reg = 0; reg < 4; ++reg) {
                const int row = m0 + mt*16 + qd*4 + reg;
                const float val = av[reg] + bb;
                if (col < 192) gqo[(size_t)row*192 + col]       = val;
                else           gko[(size_t)row*192 + col - 192] = val;
            }
        }
    }
}

// ===========================================================================
// Kernel 2: attention via MFMA; q/k point transforms inline; A/B rows built
// in registers then stored as 12x ds_write_b128 (row base j*208B is 16B-aligned).
// ===========================================================================
#define BSTR 104
__global__ __launch_bounds__(256) void attn_mfma_kernel(
    const float* __restrict__ q, const float* __restrict__ k,
    const float* __restrict__ rawp, const float* __restrict__ rot,
    const float* __restrict__ g_q, const float* __restrict__ g_k,
    const float* __restrict__ trans, const float* __restrict__ mask,
    const float* __restrict__ head_weights, const float* __restrict__ wdist,
    const float* __restrict__ bdist, float* __restrict__ a_out)
{
    const int blk  = blockIdx.x;
    const int qtr  = blk & 3;
    const int ch   = blk >> 2;
    const int h    = ch % HNUM;
    const int c    = ch / HNUM;
    const int i0   = qtr * 64;
    const int tid  = threadIdx.x;

    __shared__ ushort_t Bsh[256*BSTR];   // 53.2 KB
    __shared__ ushort_t Ash[64*BSTR];    // 13.3 KB
    __shared__ float dsh[7*256];         // 7 KB
    __shared__ float msh[256];
    __shared__ float kn_sh[256];
    __shared__ float qn_sh[64];
    __shared__ float wdsh[12], bdsh[12];
    __shared__ float cpart[96];
    __shared__ float censh[3];

    msh[tid] = mask[c*NRES + tid];
    if (tid < 12) { wdsh[tid] = wdist[tid]; bdsh[tid] = bdist[tid]; }

    if (tid < 96) {
        const int coord = tid % 3, chunk = tid / 3;
        float sv = 0.f;
        for (int e = 0; e < 8; ++e)
            sv += trans[((size_t)c*NRES + chunk*8 + e)*3 + coord];
        cpart[tid] = sv;
    }
    __syncthreads();
    if (tid < 3) {
        float sv = 0.f;
        for (int e = 0; e < 32; ++e) sv += cpart[e*3 + tid];
        censh[tid] = sv * (1.0f/256.0f);
    }
    __syncthreads();

    const float s54   = 0.13608276348795434f;  // sqrt(1/54)
    const float scale = 0.14433756729740643f;  // sqrt(1/48)
    const float hwv = 0.5f * logf(1.0f + expf(head_weights[h])) * s54;
    const float sh  = sqrtf(2.0f * hwv);
    const float cx = censh[0], cy = censh[1], cz = censh[2];

    // --- build B rows in registers, vector-store to LDS ---
    {
        const int j = tid;
        const int grow = c*NRES + j;
        ushort_t rowv[96];
        const float4* kr4 = (const float4*)(k   + (size_t)grow*192 + h*16);
        const float4* gk4 = (const float4*)(g_k + (size_t)j*192 + h*16);
        #pragma unroll
        for (int e4 = 0; e4 < 4; ++e4) {
            const float4 w = kr4[e4];
            rowv[e4*4+0] = f2bf(w.x); rowv[e4*4+1] = f2bf(w.y);
            rowv[e4*4+2] = f2bf(w.z); rowv[e4*4+3] = f2bf(w.w);
        }
        #pragma unroll
        for (int e4 = 0; e4 < 4; ++e4) {
            const float4 w = gk4[e4];
            rowv[16+e4*4+0] = f2bf(w.x); rowv[16+e4*4+1] = f2bf(w.y);
            rowv[16+e4*4+2] = f2bf(w.z); rowv[16+e4*4+3] = f2bf(w.w);
        }
        const float* base = rawp + (size_t)grow*576;
        const float4 rx = *(const float4*)(base + 144 + h*12);
        const float4 ry = *(const float4*)(base + 288 + h*12);
        const float4 rz = *(const float4*)(base + 432 + h*12);
        const float* R = rot + (size_t)grow*9;
        const float* T = trans + (size_t)grow*3;
        const float R0=R[0],R1=R[1],R2=R[2],R3=R[3],R4=R[4],R5=R[5],R6=R[6],R7=R[7],R8=R[8];
        const float Tx=T[0]-cx, Ty=T[1]-cy, Tz=T[2]-cz;
        const float xs[4] = {rx.x, rx.y, rx.z, rx.w};
        const float ys[4] = {ry.x, ry.y, ry.z, ry.w};
        const float zs[4] = {rz.x, rz.y, rz.z, rz.w};
        float kn = 0.f;
        #pragma unroll
        for (int pp = 0; pp < 4; ++pp) {
            const float x = xs[pp], y = ys[pp], z = zs[pp];
            const float pv[3] = { R0*x + R1*y + R2*z + Tx,
                                  R3*x + R4*y + R5*z + Ty,
                                  R6*x + R7*y + R8*z + Tz };
            #pragma unroll
            for (int cc = 0; cc < 3; ++cc) {
                const int e = pp*3 + cc;
                kn += pv[cc]*pv[cc];
                const float sp = sh * pv[cc];
                const unsigned int u = __float_as_uint(sp);
                const float hif = __uint_as_float(u & 0xFFFF0000u);
                const ushort_t hi = (ushort_t)(u >> 16);
                rowv[32+e] = hi;
                rowv[44+e] = (ushort_t)(__float_as_uint(sp - hif) >> 16);
                rowv[56+e] = hi;
            }
        }
        #pragma unroll
        for (int e = 68; e < 96; ++e) rowv[e] = 0;
        ushort_t* br = &Bsh[j*BSTR];
        #pragma unroll
        for (int e8 = 0; e8 < 12; ++e8)
            *(bf16x8*)(br + e8*8) = *(const bf16x8*)(rowv + e8*8);
        kn_sh[j] = hwv * kn;
    }

    // --- build A rows (threads 0..63) in registers, vector-store to LDS ---
    if (tid < 64) {
        const int il = i0 + tid;
        const int grow = c*NRES + il;
        ushort_t rowv[96];
        const float4* qr4 = (const float4*)(q   + (size_t)grow*192 + h*16);
        const float4* gq4 = (const float4*)(g_q + (size_t)il*192 + h*16);
        #pragma unroll
        for (int e4 = 0; e4 < 4; ++e4) {
            const float4 w = qr4[e4];
            rowv[e4*4+0] = f2bf(scale*w.x); rowv[e4*4+1] = f2bf(scale*w.y);
            rowv[e4*4+2] = f2bf(scale*w.z); rowv[e4*4+3] = f2bf(scale*w.w);
        }
        #pragma unroll
        for (int e4 = 0; e4 < 4; ++e4) {
            const float4 w = gq4[e4];
            rowv[16+e4*4+0] = f2bf(scale*w.x); rowv[16+e4*4+1] = f2bf(scale*w.y);
            rowv[16+e4*4+2] = f2bf(scale*w.z); rowv[16+e4*4+3] = f2bf(scale*w.w);
        }
        const float* base = rawp + (size_t)grow*576;
        const float4 rx = *(const float4*)(base + h*4);
        const float4 ry = *(const float4*)(base + 48 + h*4);
        const float4 rz = *(const float4*)(base + 96 + h*4);
        const float* R = rot + (size_t)grow*9;
        const float* T = trans + (size_t)grow*3;
        const float R0=R[0],R1=R[1],R2=R[2],R3=R[3],R4=R[4],R5=R[5],R6=R[6],R7=R[7],R8=R[8];
        const float Tx=T[0]-cx, Ty=T[1]-cy, Tz=T[2]-cz;
        const float xs[4] = {rx.x, rx.y, rx.z, rx.w};
        const float ys[4] = {ry.x, ry.y, ry.z, ry.w};
        const float zs[4] = {rz.x, rz.y, rz.z, rz.w};
        float qn = 0.f;
        #pragma unroll
        for (int pp = 0; pp < 4; ++pp) {
            const float x = xs[pp], y = ys[pp], z = zs[pp];
            const float pv[3] = { R0*x + R1*y + R2*z + Tx,
                                  R3*x + R4*y + R5*z + Ty,
                                  R6*x + R7*y + R8*z + Tz };
            #pragma unroll
            for (int cc = 0; cc < 3; ++cc) {
                const int e = pp*3 + cc;
                qn += pv[cc]*pv[cc];
                const float sp = sh * pv[cc];
                const unsigned int u = __float_as_uint(sp);
                const float hif = __uint_as_float(u & 0xFFFF0000u);
                const ushort_t hi = (ushort_t)(u >> 16);
                rowv[32+e] = hi;
                rowv[44+e] = hi;
                rowv[56+e] = (ushort_t)(__float_as_uint(sp - hif) >> 16);
            }
        }
        #pragma unroll
        for (int e = 68; e < 96; ++e) rowv[e] = 0;
        ushort_t* ar = &Ash[tid*BSTR];
        #pragma unroll
        for (int e8 = 0; e8 < 12; ++e8)
            *(bf16x8*)(ar + e8*8) = *(const bf16x8*)(rowv + e8*8);
        qn_sh[tid] = hwv * qn;
    }

    // --- dist LUT for this (h, i-quarter): NI <= 7 ---
    const int Fmin = h*65536 + i0*256;
    const int iibase = Fmin / 3072;
    const int NI = (Fmin + 63*256 + 255)/3072 - iibase + 1;
    const float* tch = trans + (size_t)c*768;
    for (int idx = tid; idx < NI*256; idx += 256) {
        const int e = idx >> 8, jj = idx & 255;
        const int ia = iibase + e;
        const float dx = tch[ia*3+0] - tch[jj*3+0];
        const float dy = tch[ia*3+1] - tch[jj*3+1];
        const float dz = tch[ia*3+2] - tch[jj*3+2];
        dsh[idx] = sqrtf(dx*dx + dy*dy + dz*dz);
    }
    __syncthreads();

    // --- main: wave handles 16 rows ---
    const int wave = tid >> 6, lane = tid & 63;
    const int qd = lane >> 4, lr = lane & 15;
    const int m0 = wave*16;

    const ushort_t* ap = &Ash[(m0 + lr)*BSTR + qd*8];
    const bf16x8 af0 = *(const bf16x8*)(ap);
    const bf16x8 af1 = *(const bf16x8*)(ap + 32);
    const bf16x8 af2 = *(const bf16x8*)(ap + 64);

    f32x4 acc[16];
    #pragma unroll
    for (int t = 0; t < 16; ++t) {
        const ushort_t* bp = &Bsh[(t*16 + lr)*BSTR + qd*8];
        f32x4 a = {0.f,0.f,0.f,0.f};
        a = __builtin_amdgcn_mfma_f32_16x16x32_bf16(af0, *(const bf16x8*)(bp),      a, 0, 0, 0);
        a = __builtin_amdgcn_mfma_f32_16x16x32_bf16(af1, *(const bf16x8*)(bp + 32), a, 0, 0, 0);
        a = __builtin_amdgcn_mfma_f32_16x16x32_bf16(af2, *(const bf16x8*)(bp + 64), a, 0, 0, 0);
        acc[t] = a;
    }

    const int ibase = m0 + qd*4;
    float qn_r[4], mb_r[4];
    int F0_[4];
    #pragma unroll
    for (int r = 0; r < 4; ++r) {
        const int il = i0 + ibase + r;
        qn_r[r] = qn_sh[ibase + r];
        mb_r[r] = 100000.0f * msh[il];
        F0_[r]  = h*65536 + il*256;
    }

    float mx[4] = {-1e30f,-1e30f,-1e30f,-1e30f};
    #pragma unroll
    for (int t = 0; t < 16; ++t) {
        const int j = t*16 + lr;
        const float knj = kn_sh[j];
        const float mj  = msh[j];
        #pragma unroll
        for (int r = 0; r < 4; ++r) {
            const unsigned int f = (unsigned int)(F0_[r] + j);
            const unsigned int p = f / 12u;
            const int ho = (int)(f - p*12u);
            const int ii = (int)(p >> 8);
            const int jj = (int)(p & 255u);
            const float dist = dsh[(ii - iibase)*256 + jj];
            const float db = dist*wdsh[ho] + bdsh[ho];
            const float lv = acc[t][r] - qn_r[r] - knj
                           + (mb_r[r]*mj - 100000.0f) + db;
            acc[t][r] = lv;
            mx[r] = fmaxf(mx[r], lv);
        }
    }
    #pragma unroll
    for (int r = 0; r < 4; ++r) {
        #pragma unroll
        for (int off = 1; off < 16; off <<= 1)
            mx[r] = fmaxf(mx[r], __shfl_xor(mx[r], off));
    }
    float sm[4] = {0.f,0.f,0.f,0.f};
    #pragma unroll
    for (int t = 0; t < 16; ++t) {
        #pragma unroll
        for (int r = 0; r < 4; ++r) {
            const float e = __expf(acc[t][r] - mx[r]);
            acc[t][r] = e;
            sm[r] += e;
        }
    }
    #pragma unroll
    for (int r = 0; r < 4; ++r) {
        #pragma unroll
        for (int off = 1; off < 16; off <<= 1)
            sm[r] += __shfl_xor(sm[r], off);
        sm[r] = 1.0f / sm[r];
    }
    float* dst = a_out + ((size_t)ch*NRES + (i0 + ibase))*NRES;
    #pragma unroll
    for (int t = 0; t < 16; ++t) {
        #pragma unroll
        for (int r = 0; r < 4; ++r)
            dst[(size_t)r*NRES + t*16 + lr] = acc[t][r]*sm[r];
    }
}

// ===========================================================================
// Kernel 3: o / o_pt via MFMA; v-point rigid transform applied INLINE.
// ===========================================================================
#define ASTRB 264
__global__ __launch_bounds__(256) void out_feat_mfma_kernel(
    const float* __restrict__ a, const float* __restrict__ v,
    const float* __restrict__ rawp, const float* __restrict__ rot,
    const float* __restrict__ trans,
    ushort_t* __restrict__ feat_hi, ushort_t* __restrict__ feat_lo)
{
    const int blk = blockIdx.x;
    const int qtr = blk & 3;
    const int ch  = blk >> 2;
    const int h   = ch % HNUM;
    const int c   = ch / HNUM;
    const int i0  = qtr * 64;
    const int tid = threadIdx.x;

    __shared__ ushort_t Bt[64*ASTRB];
    __shared__ float opt[64*25];
    __shared__ float osh[64*17];
    __shared__ float cpart[96];
    __shared__ float censh[3];

    if (tid < 96) {
        const int coord = tid % 3, chunk = tid / 3;
        float sv = 0.f;
        for (int e = 0; e < 8; ++e)
            sv += trans[((size_t)c*NRES + chunk*8 + e)*3 + coord];
        cpart[tid] = sv;
    }
    __syncthreads();
    if (tid < 3) {
        float sv = 0.f;
        for (int e = 0; e < 32; ++e) sv += cpart[e*3 + tid];
        censh[tid] = sv * (1.0f/256.0f);
    }
    __syncthreads();
    const float cx = censh[0], cy = censh[1], cz = censh[2];

    // stage B: thread j builds column j (v + inline-transformed v_pts hi/lo)
    {
        const int j = tid;
        const int grow = c*NRES + j;
        const float4* vr = (const float4*)(v + (size_t)grow*192 + h*16);
        #pragma unroll
        for (int e4 = 0; e4 < 4; ++e4) {
            const float4 w = vr[e4];
            Bt[(e4*4+0)*ASTRB + j] = f2bf(w.x);
            Bt[(e4*4+1)*ASTRB + j] = f2bf(w.y);
            Bt[(e4*4+2)*ASTRB + j] = f2bf(w.z);
            Bt[(e4*4+3)*ASTRB + j] = f2bf(w.w);
        }
        const float* base = rawp + (size_t)grow*576;
        const float4 rx0 = *(const float4*)(base + 144 + h*12 + 4);
        const float4 rx1 = *(const float4*)(base + 144 + h*12 + 8);
        const float4 ry0 = *(const float4*)(base + 288 + h*12 + 4);
        const float4 ry1 = *(const float4*)(base + 288 + h*12 + 8);
        const float4 rz0 = *(const float4*)(base + 432 + h*12 + 4);
        const float4 rz1 = *(const float4*)(base + 432 + h*12 + 8);
        const float* R = rot + (size_t)grow*9;
        const float* T = trans + (size_t)grow*3;
        const float R0=R[0],R1=R[1],R2=R[2],R3=R[3],R4=R[4],R5=R[5],R6=R[6],R7=R[7],R8=R[8];
        const float Tx=T[0]-cx, Ty=T[1]-cy, Tz=T[2]-cz;
        const float xs[8] = {rx0.x,rx0.y,rx0.z,rx0.w, rx1.x,rx1.y,rx1.z,rx1.w};
        const float ys[8] = {ry0.x,ry0.y,ry0.z,ry0.w, ry1.x,ry1.y,ry1.z,ry1.w};
        const float zs[8] = {rz0.x,rz0.y,rz0.z,rz0.w, rz1.x,rz1.y,rz1.z,rz1.w};
        #pragma unroll
        for (int pp = 0; pp < 8; ++pp) {
            const float x = xs[pp], y = ys[pp], z = zs[pp];
            const float pv[3] = { R0*x + R1*y + R2*z + Tx,
                                  R3*x + R4*y + R5*z + Ty,
                                  R6*x + R7*y + R8*z + Tz };
            #pragma unroll
            for (int cc = 0; cc < 3; ++cc) {
                const int e = pp*3 + cc;
                const float vp = pv[cc];
                const unsigned int u = __float_as_uint(vp);
                const float hif = __uint_as_float(u & 0xFFFF0000u);
                Bt[(16+e)*ASTRB + j] = (ushort_t)(u >> 16);
                Bt[(40+e)*ASTRB + j] = (ushort_t)(__float_as_uint(vp - hif) >> 16);
            }
        }
    }
    __syncthreads();

    const int wave = tid >> 6, lane = tid & 63;
    const int qd = lane >> 4, lr = lane & 15;
    const int m0 = wave*16;

    const float* arow = a + ((size_t)ch*NRES + i0 + m0 + lr)*NRES;

    f32x4 acc[4] = {{0,0,0,0},{0,0,0,0},{0,0,0,0},{0,0,0,0}};
    #pragma unroll
    for (int kk = 0; kk < 256; kk += 32) {
        const float4 a0 = *(const float4*)(arow + qd*8 + kk);
        const float4 a1 = *(const float4*)(arow + qd*8 + kk + 4);
        const float av[8] = {a0.x,a0.y,a0.z,a0.w,a1.x,a1.y,a1.z,a1.w};
        bf16x8 ahi, alo;
        #pragma unroll
        for (int e = 0; e < 8; ++e) {
            const unsigned int u = __float_as_uint(av[e]);
            const float hif = __uint_as_float(u & 0xFFFF0000u);
            ((ushort_t*)&ahi)[e] = (ushort_t)(u >> 16);
            ((ushort_t*)&alo)[e] = (ushort_t)(__float_as_uint(av[e] - hif) >> 16);
        }
        #pragma unroll
        for (int t = 0; t < 4; ++t) {
            const bf16x8 bf = *(const bf16x8*)&Bt[(t*16 + lr)*ASTRB + qd*8 + kk];
            acc[t] = __builtin_amdgcn_mfma_f32_16x16x32_bf16(ahi, bf, acc[t], 0, 0, 0);
            acc[t] = __builtin_amdgcn_mfma_f32_16x16x32_bf16(alo, bf, acc[t], 0, 0, 0);
        }
    }

    #pragma unroll
    for (int reg = 0; reg < 4; ++reg) {
        const int row_l = m0 + qd*4 + reg;
        osh[row_l*17 + lr] = acc[0][reg];
        opt[row_l*25 + lr] = acc[1][reg];
    }
    #pragma unroll
    for (int reg = 0; reg < 4; ++reg) {
        const int row_l = m0 + qd*4 + reg;
        if (lr < 8) opt[row_l*25 + 16 + lr] = acc[2][reg];
        else        opt[row_l*25 + (lr-8)] += acc[2][reg];
    }
    #pragma unroll
    for (int reg = 0; reg < 4; ++reg) {
        const int row_l = m0 + qd*4 + reg;
        opt[row_l*25 + 8 + lr] += acc[3][reg];
    }
    __syncthreads();

    #pragma unroll
    for (int it = 0; it < 4; ++it) {
        const int idx = it*256 + tid;
        const int row_l = idx >> 4, e = idx & 15;
        const int grow = c*NRES + i0 + row_l;
        const float val = osh[row_l*17 + e];
        const unsigned int u = __float_as_uint(val);
        const float hif = __uint_as_float(u & 0xFFFF0000u);
        feat_hi[(size_t)grow*576 + h*16 + e] = (ushort_t)(u >> 16);
        feat_lo[(size_t)grow*576 + h*16 + e] = (ushort_t)(__float_as_uint(val - hif) >> 16);
    }
    #pragma unroll
    for (int it = 0; it < 2; ++it) {
        const int idx = it*256 + tid;
        const int row_l = idx >> 3, p = idx & 7;
        const int grow = c*NRES + i0 + row_l;
        const float* R = rot + (size_t)grow*9;
        const float* T = trans + (size_t)grow*3;
        const float x = opt[row_l*25 + p*3+0] + cx - T[0];
        const float y = opt[row_l*25 + p*3+1] + cy - T[1];
        const float z = opt[row_l*25 + p*3+2] + cz - T[2];
        const float rx = R[0]*x + R[3]*y + R[6]*z;
        const float ry = R[1]*x + R[4]*y + R[7]*z;
        const float rz = R[2]*x + R[5]*y + R[8]*z;
        const float nm = sqrtf(rx*rx + ry*ry + rz*rz + 1e-8f);
        const float vals[4] = {rx, ry, rz, nm};
        #pragma unroll
        for (int sl = 0; sl < 4; ++sl) {
            const int col = 192 + sl*96 + h*8 + p;
            const float vv = vals[sl];
            const unsigned int u = __float_as_uint(vv);
            const float hif = __uint_as_float(u & 0xFFFF0000u);
            feat_hi[(size_t)grow*576 + col] = (ushort_t)(u >> 16);
            feat_lo[(size_t)grow*576 + col] = (ushort_t)(__float_as_uint(vv - hif) >> 16);
        }
    }
}

// ===========================================================================
// Kernel 4: out0 = feat @ wout + bout via MFMA (3-term hi/lo product).
// ===========================================================================
__global__ __launch_bounds__(256) void out_gemm_mfma_kernel(
    const ushort_t* __restrict__ feat_hi, const ushort_t* __restrict__ feat_lo,
    const ushort_t* __restrict__ wo_hi, const ushort_t* __restrict__ wo_lo,
    const float* __restrict__ bout, float* __restrict__ out0)
{
    const int blk = blockIdx.x;
    const int rt = blk / 6, ct = blk - rt*6;
    const int r0 = rt * 64, c0 = ct * 64;
    const int tid = threadIdx.x;
    const int wave = tid >> 6, lane = tid & 63;
    const int wrow = wave >> 1, wcol = wave & 1;
    const int m0 = r0 + wrow*32, n0 = c0 + wcol*32;
    const int qd = lane >> 4, lr = lane & 15;

    f32x4 acc[2][2] = {{{0,0,0,0},{0,0,0,0}},{{0,0,0,0},{0,0,0,0}}};

    const ushort_t* ah0 = feat_hi + (size_t)(m0 + lr)*576 + qd*8;
    const ushort_t* ah1 = ah0 + 16*576;
    const ushort_t* al0 = feat_lo + (size_t)(m0 + lr)*576 + qd*8;
    const ushort_t* al1 = al0 + 16*576;
    const ushort_t* bh0 = wo_hi + (size_t)(n0 + lr)*576 + qd*8;
    const ushort_t* bh1 = bh0 + 16*576;
    const ushort_t* bl0 = wo_lo + (size_t)(n0 + lr)*576 + qd*8;
    const ushort_t* bl1 = bl0 + 16*576;

    for (int kk = 0; kk < 576; kk += 32) {
        const bf16x8 fh0 = *(const bf16x8*)(ah0 + kk);
        const bf16x8 fh1 = *(const bf16x8*)(ah1 + kk);
        const bf16x8 fl0 = *(const bf16x8*)(al0 + kk);
        const bf16x8 fl1 = *(const bf16x8*)(al1 + kk);
        const bf16x8 wh0 = *(const bf16x8*)(bh0 + kk);
        const bf16x8 wh1 = *(const bf16x8*)(bh1 + kk);
        const bf16x8 wl0 = *(const bf16x8*)(bl0 + kk);
        const bf16x8 wl1 = *(const bf16x8*)(bl1 + kk);
        acc[0][0] = __builtin_amdgcn_mfma_f32_16x16x32_bf16(fh0, wh0, acc[0][0], 0, 0, 0);
        acc[0][1] = __builtin_amdgcn_mfma_f32_16x16x32_bf16(fh0, wh1, acc[0][1], 0, 0, 0);
        acc[1][0] = __builtin_amdgcn_mfma_f32_16x16x32_bf16(fh1, wh0, acc[1][0], 0, 0, 0);
        acc[1][1] = __builtin_amdgcn_mfma_f32_16x16x32_bf16(fh1, wh1, acc[1][1], 0, 0, 0);
        acc[0][0] = __builtin_amdgcn_mfma_f32_16x16x32_bf16(fl0, wh0, acc[0][0], 0, 0, 0);
        acc[0][1] = __builtin_amdgcn_mfma_f32_16x16x32_bf16(fl0, wh1, acc[0][1], 0, 0, 0);
        acc[1][0] = __builtin_amdgcn_mfma_f32_16x16x32_bf16(fl1, wh0, acc[1][0], 0, 0, 0);
        acc[1][1] = __builtin_amdgcn_mfma_f32_16x16x32_bf16(fl1, wh1, acc[1][1], 0, 0, 0);
        acc[0][0] = __builtin_amdgcn_mfma_f32_16x16x32_bf16(fh0, wl0, acc[0][0], 0, 0, 0);
        acc[0][1] = __builtin_amdgcn_mfma_f32_16x16x32_bf16(fh0, wl1, acc[0][1], 0, 0, 0);
        acc[1][0] = __builtin_amdgcn_mfma_f32_16x16x32_bf16(fh1, wl0, acc[1][0], 0, 0, 0);
        acc[1][1] = __builtin_amdgcn_mfma_f32_16x16x32_bf16(fh1, wl1, acc[1][1], 0, 0, 0);
    }

    #pragma unroll
    for (int mt = 0; mt < 2; ++mt) {
        #pragma unroll
        for (int nt = 0; nt < 2; ++nt) {
            const int col = n0 + nt*16 + lr;
            const float bb = bout[col];
            #pragma unroll
            for (int reg = 0; reg < 4; ++reg) {
                const int row = m0 + mt*16 + qd*4 + reg;
                out0[(size_t)row*CS + col] = acc[mt][nt][reg] + bb;
            }
        }
    }
}

// ===========================================================================
extern "C" void kernel_launch(void* const* d_in, const int* in_sizes, int n_in,
                              void* d_out, int out_size, void* d_ws, size_t ws_size,
                              hipStream_t stream)
{
    const float* s     = (const float*)d_in[0];
    const float* rot   = (const float*)d_in[2];
    const float* trans = (const float*)d_in[3];
    const float* mask  = (const float*)d_in[4];
    const float* wq    = (const float*)d_in[5];
    const float* bq    = (const float*)d_in[6];
    const float* wkv   = (const float*)d_in[7];
    const float* bkv   = (const float*)d_in[8];
    const float* g_gamma = (const float*)d_in[9];
    const float* g_beta  = (const float*)d_in[10];
    const float* wgq   = (const float*)d_in[11];
    const float* bgq   = (const float*)d_in[12];
    const float* wgk   = (const float*)d_in[13];
    const float* bgk   = (const float*)d_in[14];
    const float* wqp   = (const float*)d_in[15];
    const float* bqp   = (const float*)d_in[16];
    const float* wkvp  = (const float*)d_in[17];
    const float* bkvp  = (const float*)d_in[18];
    const float* head_weights = (const float*)d_in[19];
    const float* wdist = (const float*)d_in[20];
    const float* bdist = (const float*)d_in[21];
    const float* wout  = (const float*)d_in[22];
    const float* bout  = (const float*)d_in[23];

    float* ws      = (float*)d_ws;
    float* q_buf   = ws + 0;          // 393216
    float* gq_buf  = ws + 983040;     // 49152
    float* gk_buf  = ws + 1032192;    // 49152
    float* k_buf   = ws + 1081344;    // 393216
    float* v_buf   = ws + 1474560;    // 393216
    ushort_t* sgn_bf  = (ushort_t*)(ws + 1867776); // 98304 bf16
    ushort_t* feat_hi = (ushort_t*)(ws + 2457600); // 1179648 bf16
    ushort_t* feat_lo = (ushort_t*)(ws + 3047424); // 1179648 bf16
    ushort_t* wo_hi   = (ushort_t*)(ws + 3637248); // 221184 bf16
    ushort_t* wo_lo   = (ushort_t*)(ws + 3747840); // 221184 bf16
    float*    rawp    = ws + 4194304;              // 1179648 floats (private)

    float* out0  = (float*)d_out;       // 786432
    float* a_out = out0 + 786432;       // 6291456
    // overlays inside a_out (dead before attn writes):
    ushort_t* s_bf   = (ushort_t*)(a_out);                 // 786432 bf16
    ushort_t* wt_bf  = (ushort_t*)(a_out + 393216);        // 442368 bf16
    ushort_t* wtg_bf = (ushort_t*)(a_out + 614400);        // 147456 bf16
    float*    pbias  = a_out + 688128;                     // 1152
    float*    gbias  = a_out + 689280;                     // 384

    convert_ln_kernel<<<1223, 256, 0, stream>>>(s, wq, bq, wkv, bkv, wqp, bqp,
                                                wkvp, bkvp, wgq, bgq, wgk, bgk,
                                                wout, g_gamma, g_beta,
                                                s_bf, wt_bf, wtg_bf, pbias, gbias,
                                                wo_hi, wo_lo, sgn_bf);
    proj_ggemm_kernel<<<600, 256, 0, stream>>>(s_bf, wt_bf, pbias,
                                               sgn_bf, wtg_bf, gbias,
                                               q_buf, k_buf, v_buf, rawp,
                                               gq_buf, gk_buf);
    attn_mfma_kernel<<<384, 256, 0, stream>>>(q_buf, k_buf, rawp, rot,
                                              gq_buf, gk_buf, trans, mask,
                                              head_weights, wdist, bdist, a_out);
    out_feat_mfma_kernel<<<384, 256, 0, stream>>>(a_out, v_buf, rawp, rot, trans,
                                                  feat_hi, feat_lo);
    out_gemm_mfma_kernel<<<192, 256, 0, stream>>>(feat_hi, feat_lo, wo_hi, wo_lo,
                                                  bout, out0);
}